// Round 14
// baseline (1273.386 us; speedup 1.0000x reference)
//
#include <hip/hip_runtime.h>
#include <math.h>

namespace {
constexpr int kB = 2, kS = 2048, kDH = 2048, kH = 16, kDN = 128, kDR = 64, kDV = 128;
constexpr int kKvLora = 512, kQLora = 1024, kHI = 8, kDI = 128, kTopK = 1024;
constexpr int kNTok = kB * kS;             // 4096
constexpr float kNeg = -1e30f;

// ---- fixed region (bytes) ----
constexpr size_t OFF_SC    = 0;                          // 784 f32 scales
constexpr size_t OFF_SEL_B = 4096;                       // 1 MB
constexpr size_t OFF_WGT_B = OFF_SEL_B + 1048576;        // 128 KB
constexpr size_t OFF_KRH_B = OFF_WGT_B + 131072;         // 512 KB
constexpr size_t OFF_KRL_B = OFF_KRH_B + 524288;         // 512 KB
constexpr size_t OFF_WOB_B = OFF_KRL_B + 524288;         // 8 MB  (Wo bf16)
constexpr size_t POOL      = OFF_WOB_B + 8388608;        // 10,620,928
// ---- phase B core ----
constexpr size_t B_HIDQ = POOL;                 // 16 MB bf16
constexpr size_t B_WQA  = POOL + 16777216;      // 4 MB
constexpr size_t B_WQB  = POOL + 20971520;      // 6 MB
constexpr size_t B_WKVA = POOL + 27262976;      // 2.5 MB
constexpr size_t B_WKVB = POOL + 29884416;      // 4 MB
constexpr size_t B_QAF  = POOL + 34078720;      // 16 MB f32
constexpr size_t B_QAB  = POOL + 50855936;      // 8 MB bf16
constexpr size_t B_KVA  = POOL + 59244544;      // 9.4 MB f32
constexpr size_t B_CKV  = POOL + 68681728;      // 4 MB bf16
constexpr size_t B_QH   = POOL + 72876032;      // 24 MB bf16
constexpr size_t B_QL   = POOL + 98041856;      // 24 MB bf16
constexpr size_t B_KNH  = POOL + 123207680;     // 16 MB
constexpr size_t B_KNL  = POOL + 139984896;     // 16 MB
constexpr size_t B_VTH  = POOL;                 // 16 MB (over dead hidq)
constexpr size_t B_VTL  = POOL + 34078720;      // 16 MB (over dead qa_f)
constexpr size_t B_CTXB = POOL + 50855936;      // 16 MB (over dead qa_b + kva)
// ---- phase A (indexer) ----
constexpr size_t A_HHI  = POOL + 16777216;      // 16 MB bf16
constexpr size_t A_HLO  = POOL + 33554432;      // 16 MB bf16
constexpr size_t A_WQKH = POOL + 50331648;      // 4,718,592
constexpr size_t A_WQKL = POOL + 55050240;      // 4,718,592
constexpr size_t A_QIKH = POOL + 59768832;      // 9,437,184 bf16 [4096][1152]
constexpr size_t A_QIKL = POOL + 69206016;      // 9,437,184
constexpr size_t A_ISC  = POOL + 78643200;      // 33,554,432 f32 [4096][2048]
constexpr size_t WS_NEED = POOL + 156762112;    // 167,383,040 B (known-good)
} // namespace

typedef __attribute__((ext_vector_type(4))) float f32x4;
typedef __attribute__((ext_vector_type(8))) short bf16x8;
typedef __attribute__((address_space(1))) const void gvoid;
typedef __attribute__((address_space(3))) void lvoid;

// Exact e4m3fn round-to-nearest-even quant-dequant for |x| <= 448 (incl. subnormals).
__device__ __forceinline__ float fp8_e4m3_qdq(float x) {
  float ax = fabsf(x);
  int e;
  (void)frexpf(ax, &e);
  int ee = e - 1;
  if (ee < -6) ee = -6;
  float q = ldexpf(1.0f, ee - 3);
  float y = rintf(ax / q) * q;
  return (x < 0.0f) ? -y : y;
}

__device__ __forceinline__ float act_scale_from_amax(float amax) {
  float t = amax / 448.0f;
  unsigned u = __float_as_uint(t);
  int e = (int)((u >> 23) & 255u) - 127;
  if (u & 0x7fffffu) e += 1;
  return __uint_as_float((unsigned)(e + 127) << 23);
}

__device__ __forceinline__ float clamp448(float v) {
  return fminf(fmaxf(v, -448.0f), 448.0f);
}

__device__ __forceinline__ unsigned short f32_to_bf16(float f) {
  unsigned u = __float_as_uint(f);
  unsigned r = (u + 0x7FFFu + ((u >> 16) & 1u)) >> 16;
  return (unsigned short)r;
}
__device__ __forceinline__ float bf16_to_f32(unsigned short h) {
  return __uint_as_float((unsigned)h << 16);
}

__global__ __launch_bounds__(256) void fill_kernel(float* p, int n, float v) {
  int i = blockIdx.x * 256 + threadIdx.x;
  if (i < n) p[i] = v;
}

// ---------------- fused hidden prep: hi/lo split + fp8-qdq -> bf16 (one read) ----------------
__global__ __launch_bounds__(256) void hidden_prep_kernel(const float* __restrict__ X,
                                                          unsigned short* __restrict__ HI,
                                                          unsigned short* __restrict__ LO,
                                                          unsigned short* __restrict__ QB) {
  int wid = blockIdx.x * 4 + (threadIdx.x >> 6);
  int lane = threadIdx.x & 63;
  const float* x = X + (size_t)wid * 128;
  float v0 = x[lane], v1 = x[lane + 64];
  size_t o0 = (size_t)wid * 128 + lane, o1 = o0 + 64;
  unsigned short h0 = f32_to_bf16(v0);
  HI[o0] = h0; LO[o0] = f32_to_bf16(v0 - bf16_to_f32(h0));
  unsigned short h1 = f32_to_bf16(v1);
  HI[o1] = h1; LO[o1] = f32_to_bf16(v1 - bf16_to_f32(h1));
  float am = fmaxf(fabsf(v0), fabsf(v1));
#pragma unroll
  for (int m = 32; m >= 1; m >>= 1) am = fmaxf(am, __shfl_xor(am, m, 64));
  am = fmaxf(am, 1e-4f);
  float s = act_scale_from_amax(am);
  QB[o0] = f32_to_bf16(fp8_e4m3_qdq(clamp448(v0 / s)) * s);
  QB[o1] = f32_to_bf16(fp8_e4m3_qdq(clamp448(v1 / s)) * s);
}

// ---------------- fused weight 128x128-block scale + bf16 quantized values ----------------
__global__ __launch_bounds__(256) void fused_weight_kernel(const float* __restrict__ W,
                                                           float* __restrict__ SC,
                                                           unsigned short* __restrict__ WB,
                                                           int O, int I) {
  int kb = blockIdx.x, ob = blockIdx.y;
  int bo = ob * 128, bi = kb * 128;
  int tid = threadIdx.x;
  __shared__ float red[256];
  __shared__ float s_scale;
  float am = 0.0f;
  for (int idx = tid; idx < 128 * 128; idx += 256) {
    int r = bo + (idx >> 7), c = bi + (idx & 127);
    if (r < O) am = fmaxf(am, fabsf(W[(size_t)r * I + c]));
  }
  red[tid] = am; __syncthreads();
  for (int s = 128; s >= 1; s >>= 1) {
    if (tid < s) red[tid] = fmaxf(red[tid], red[tid + s]);
    __syncthreads();
  }
  if (tid == 0) {
    float sc = fmaxf(red[0], 1e-4f) / 448.0f;
    SC[(size_t)ob * gridDim.x + kb] = sc;
    s_scale = sc;
  }
  __syncthreads();
  float sc = s_scale;
  for (int idx = tid; idx < 128 * 128; idx += 256) {
    int r = bo + (idx >> 7), c = bi + (idx & 127);
    unsigned short v = 0;
    if (r < O) v = f32_to_bf16(fp8_e4m3_qdq(clamp448(W[(size_t)r * I + c] / sc)));
    WB[(size_t)r * I + c] = v;
  }
}

// ---------------- f32 -> bf16 hi/lo split ----------------
__global__ __launch_bounds__(256) void split_bf16x2_kernel(const float* __restrict__ X,
                                                           unsigned short* __restrict__ HI,
                                                           unsigned short* __restrict__ LO,
                                                           size_t n) {
  size_t i = (size_t)blockIdx.x * 256 + threadIdx.x;
  if (i >= n) return;
  float x = X[i];
  unsigned short h = f32_to_bf16(x);
  HI[i] = h;
  LO[i] = f32_to_bf16(x - bf16_to_f32(h));
}

// ---------------- fused RMSNorm + activation qdq -> bf16 (per row) ----------------
__global__ __launch_bounds__(256) void rms_qdq_kernel(const float* __restrict__ X,
                                                      const float* __restrict__ G,
                                                      unsigned short* __restrict__ Y,
                                                      int C, int xs, int ys) {
  int row = blockIdx.x, tid = threadIdx.x;
  __shared__ float xr[1024];
  __shared__ float red[256];
  const float* x = X + (size_t)row * xs;
  float ssq = 0.0f;
  for (int i = tid; i < C; i += 256) { float v = x[i]; xr[i] = v; ssq += v * v; }
  red[tid] = ssq; __syncthreads();
  for (int s = 128; s >= 1; s >>= 1) { if (tid < s) red[tid] += red[tid + s]; __syncthreads(); }
  float inv = 1.0f / sqrtf(red[0] / (float)C + 1e-6f);
  __syncthreads();
  int wv = tid >> 6, lane = tid & 63;
  for (int blk = wv; blk < C / 128; blk += 4) {
    int i0 = blk * 128 + lane, i1 = i0 + 64;
    float y0 = xr[i0] * inv * G[i0];
    float y1 = xr[i1] * inv * G[i1];
    float am = fmaxf(fabsf(y0), fabsf(y1));
#pragma unroll
    for (int m = 32; m >= 1; m >>= 1) am = fmaxf(am, __shfl_xor(am, m, 64));
    am = fmaxf(am, 1e-4f);
    float s = act_scale_from_amax(am);
    Y[(size_t)row * ys + i0] = f32_to_bf16(fp8_e4m3_qdq(clamp448(y0 / s)) * s);
    Y[(size_t)row * ys + i1] = f32_to_bf16(fp8_e4m3_qdq(clamp448(y1 / s)) * s);
  }
}

// ---------------- bf16 MFMA GEMM, templated epilogue ----------------
template <int OMODE, bool SCALED>
__global__ __launch_bounds__(256) void mfma_gemm_kernel(const unsigned short* __restrict__ A,
                                                        const unsigned short* __restrict__ B,
                                                        const float* __restrict__ Bsc,
                                                        float* __restrict__ C,
                                                        unsigned short* __restrict__ O1,
                                                        unsigned short* __restrict__ O2,
                                                        unsigned short* __restrict__ O3,
                                                        unsigned short* __restrict__ O4,
                                                        int N, int K, int ldc) {
  __shared__ unsigned short lA[128 * 64];
  __shared__ unsigned short lB[128 * 64];
  const int tid = threadIdx.x;
  const int wave = tid >> 6, lane = tid & 63;
  const int wr = (wave >> 1) * 64, wc = (wave & 1) * 64;
  const int m0 = blockIdx.y * 128, n0 = blockIdx.x * 128;
  const int KB = K >> 7;
  const int frow = lane & 15, fk = (lane >> 4) * 8;

  f32x4 mainAcc[4][4];
  f32x4 part[4][4];
  const f32x4 vzero = {0.f, 0.f, 0.f, 0.f};
#pragma unroll
  for (int i = 0; i < 4; ++i)
#pragma unroll
    for (int j = 0; j < 4; ++j) { mainAcc[i][j] = vzero; part[i][j] = vzero; }

  const int nkt = K >> 6;
  for (int kt = 0; kt < nkt; ++kt) {
    const int k0 = kt << 6;
    __syncthreads();
#pragma unroll
    for (int it = 0; it < 4; ++it) {
      int o = it * 4096 + wave * 1024 + lane * 16;
      int row = o >> 7;
      int kb = o & 127;
      const char* ga = (const char*)(A + (size_t)(m0 + row) * K + k0) + kb;
      const char* gb = (const char*)(B + (size_t)(n0 + row) * K + k0) + kb;
      __builtin_amdgcn_global_load_lds((gvoid*)ga, (lvoid*)((char*)lA + o), 16, 0, 0);
      __builtin_amdgcn_global_load_lds((gvoid*)gb, (lvoid*)((char*)lB + o), 16, 0, 0);
    }
    __syncthreads();
#pragma unroll
    for (int ks = 0; ks < 2; ++ks) {
      bf16x8 af[4], bfr[4];
#pragma unroll
      for (int i = 0; i < 4; ++i)
        af[i] = *(const bf16x8*)&lA[(wr + i * 16 + frow) * 64 + ks * 32 + fk];
#pragma unroll
      for (int j = 0; j < 4; ++j)
        bfr[j] = *(const bf16x8*)&lB[(wc + j * 16 + frow) * 64 + ks * 32 + fk];
#pragma unroll
      for (int i = 0; i < 4; ++i)
#pragma unroll
        for (int j = 0; j < 4; ++j)
          part[i][j] = __builtin_amdgcn_mfma_f32_16x16x32_bf16(af[i], bfr[j], part[i][j], 0, 0, 0);
    }
    if (SCALED) {
      float bs = Bsc[(size_t)(n0 >> 7) * KB + (k0 >> 7)];
#pragma unroll
      for (int i = 0; i < 4; ++i)
#pragma unroll
        for (int j = 0; j < 4; ++j) {
          mainAcc[i][j] += part[i][j] * bs;
          part[i][j] = vzero;
        }
    }
  }
  const int crow0 = (lane >> 4) * 4;
  const int ccol = lane & 15;
#pragma unroll
  for (int i = 0; i < 4; ++i) {
#pragma unroll
    for (int j = 0; j < 4; ++j) {
      f32x4 v = SCALED ? mainAcc[i][j] : part[i][j];
      int col = n0 + wc + j * 16 + ccol;
      if (col < N) {
#pragma unroll
        for (int r = 0; r < 4; ++r) {
          int m = m0 + wr + i * 16 + crow0 + r;
          float val = v[r];
          if (OMODE == 0) {
            C[(size_t)m * ldc + col] = val;
          } else if (OMODE == 1) {
            int hh = col / 192, d = col - hh * 192;
            int bb = m >> 11, s = m & 2047;
            size_t off = ((size_t)((bb * 16 + hh) * 2048 + s)) * 192 + d;
            unsigned short hi = f32_to_bf16(val);
            O1[off] = hi;
            O2[off] = f32_to_bf16(val - bf16_to_f32(hi));
          } else {
            int hh = col >> 8, d = col & 255;
            int bb = m >> 11, s = m & 2047;
            if (d < 128) {
              size_t off = ((size_t)((bb * 16 + hh) * 2048 + s)) * 128 + d;
              unsigned short hi = f32_to_bf16(val);
              O1[off] = hi;
              O2[off] = f32_to_bf16(val - bf16_to_f32(hi));
            } else {
              size_t off = ((size_t)((bb * 16 + hh) * 128 + (d - 128))) * 2048 + s;
              unsigned short hi = f32_to_bf16(val);
              O3[off] = hi;
              O4[off] = f32_to_bf16(val - bf16_to_f32(hi));
            }
          }
        }
      }
    }
  }
}

// ---------------- 3-product split GEMM -> bf16 hi/lo output [4096][1152] ----------------
__global__ __launch_bounds__(256) void mfma_gemm3_kernel(const unsigned short* __restrict__ Ah,
                                                         const unsigned short* __restrict__ Al,
                                                         const unsigned short* __restrict__ Bh,
                                                         const unsigned short* __restrict__ Bl,
                                                         unsigned short* __restrict__ OH,
                                                         unsigned short* __restrict__ OL,
                                                         int K, int ldc) {
  if (blockIdx.x < 8 && !(blockIdx.y & 8)) return;   // qi rows q<1024 never used
  __shared__ unsigned short lAh[128 * 64], lAl[128 * 64];
  __shared__ unsigned short lBh[128 * 64], lBl[128 * 64];
  const int tid = threadIdx.x;
  const int wave = tid >> 6, lane = tid & 63;
  const int wr = (wave >> 1) * 64, wc = (wave & 1) * 64;
  const int m0 = blockIdx.y * 128, n0 = blockIdx.x * 128;
  const int frow = lane & 15, fk = (lane >> 4) * 8;

  f32x4 part[4][4];
  const f32x4 vzero = {0.f, 0.f, 0.f, 0.f};
#pragma unroll
  for (int i = 0; i < 4; ++i)
#pragma unroll
    for (int j = 0; j < 4; ++j) part[i][j] = vzero;

  const int nkt = K >> 6;
  for (int kt = 0; kt < nkt; ++kt) {
    const int k0 = kt << 6;
    __syncthreads();
#pragma unroll
    for (int it = 0; it < 4; ++it) {
      int o = it * 4096 + wave * 1024 + lane * 16;
      int row = o >> 7;
      int kb = o & 127;
      size_t ga = (size_t)(m0 + row) * K + k0;
      size_t gb = (size_t)(n0 + row) * K + k0;
      __builtin_amdgcn_global_load_lds((gvoid*)((const char*)(Ah + ga) + kb), (lvoid*)((char*)lAh + o), 16, 0, 0);
      __builtin_amdgcn_global_load_lds((gvoid*)((const char*)(Al + ga) + kb), (lvoid*)((char*)lAl + o), 16, 0, 0);
      __builtin_amdgcn_global_load_lds((gvoid*)((const char*)(Bh + gb) + kb), (lvoid*)((char*)lBh + o), 16, 0, 0);
      __builtin_amdgcn_global_load_lds((gvoid*)((const char*)(Bl + gb) + kb), (lvoid*)((char*)lBl + o), 16, 0, 0);
    }
    __syncthreads();
#pragma unroll
    for (int ks = 0; ks < 2; ++ks) {
      bf16x8 ah[4], al[4], bh[4], bl[4];
#pragma unroll
      for (int i = 0; i < 4; ++i) {
        ah[i] = *(const bf16x8*)&lAh[(wr + i * 16 + frow) * 64 + ks * 32 + fk];
        al[i] = *(const bf16x8*)&lAl[(wr + i * 16 + frow) * 64 + ks * 32 + fk];
      }
#pragma unroll
      for (int j = 0; j < 4; ++j) {
        bh[j] = *(const bf16x8*)&lBh[(wc + j * 16 + frow) * 64 + ks * 32 + fk];
        bl[j] = *(const bf16x8*)&lBl[(wc + j * 16 + frow) * 64 + ks * 32 + fk];
      }
#pragma unroll
      for (int i = 0; i < 4; ++i)
#pragma unroll
        for (int j = 0; j < 4; ++j) {
          part[i][j] = __builtin_amdgcn_mfma_f32_16x16x32_bf16(ah[i], bh[j], part[i][j], 0, 0, 0);
          part[i][j] = __builtin_amdgcn_mfma_f32_16x16x32_bf16(ah[i], bl[j], part[i][j], 0, 0, 0);
          part[i][j] = __builtin_amdgcn_mfma_f32_16x16x32_bf16(al[i], bh[j], part[i][j], 0, 0, 0);
        }
    }
  }
  const int crow0 = (lane >> 4) * 4;
  const int ccol = lane & 15;
#pragma unroll
  for (int i = 0; i < 4; ++i)
#pragma unroll
    for (int j = 0; j < 4; ++j) {
      int col = n0 + wc + j * 16 + ccol;
#pragma unroll
      for (int r = 0; r < 4; ++r) {
        float val = part[i][j][r];
        size_t off = (size_t)(m0 + wr + i * 16 + crow0 + r) * ldc + col;
        unsigned short hi = f32_to_bf16(val);
        OH[off] = hi;
        OL[off] = f32_to_bf16(val - bf16_to_f32(hi));
      }
    }
}

// ---------------- f32 GEMM (tiny Wig only); rowskip: skip tiles with (y & rowskip)==0 ----------------
__global__ __launch_bounds__(256) void gemm_f32_kernel(const float* __restrict__ A,
                                                       const float* __restrict__ Bw,
                                                       float* __restrict__ C,
                                                       int N, int K, float alpha, int rowskip) {
  if (rowskip && !(blockIdx.y & rowskip)) return;
  __shared__ __align__(16) float As[16][68];
  __shared__ __align__(16) float Bs[16][68];
  int n0 = blockIdx.x * 64;
  int m0 = blockIdx.y * 64;
  int tid = threadIdx.x;
  int tx = tid & 15, ty = tid >> 4;
  float acc[4][4] = {};
  for (int k0 = 0; k0 < K; k0 += 16) {
#pragma unroll
    for (int t = 0; t < 4; ++t) {
      int idx = tid + t * 256;
      int rr = idx >> 4;
      int kk = idx & 15;
      As[kk][rr] = A[(size_t)(m0 + rr) * K + (k0 + kk)];
      Bs[kk][rr] = (n0 + rr < N) ? Bw[(size_t)(n0 + rr) * K + (k0 + kk)] : 0.0f;
    }
    __syncthreads();
#pragma unroll
    for (int kk = 0; kk < 16; ++kk) {
      float4 a = *(const float4*)&As[kk][ty * 4];
      float4 b = *(const float4*)&Bs[kk][tx * 4];
      float av[4] = {a.x, a.y, a.z, a.w};
      float bv[4] = {b.x, b.y, b.z, b.w};
#pragma unroll
      for (int i = 0; i < 4; ++i)
#pragma unroll
        for (int j = 0; j < 4; ++j) acc[i][j] += av[i] * bv[j];
    }
    __syncthreads();
  }
#pragma unroll
  for (int i = 0; i < 4; ++i) {
    int m = m0 + ty * 4 + i;
#pragma unroll
    for (int j = 0; j < 4; ++j) {
      int n = n0 + tx * 4 + j;
      if (n < N) C[(size_t)m * N + n] = alpha * acc[i][j];
    }
  }
}

// ---------------- RoPE on split Q (in place, [b,h,s,192]) + k_rope -> Krh/Krl ----------------
__global__ __launch_bounds__(64) void rope_split_kernel(unsigned short* __restrict__ Qh,
                                                        unsigned short* __restrict__ Ql,
                                                        const float* __restrict__ KVA,
                                                        unsigned short* __restrict__ Krh,
                                                        unsigned short* __restrict__ Krl,
                                                        const int* __restrict__ POS) {
  int t = blockIdx.x;  // b*S + s
  int tid = threadIdx.x;
  int b = t >> 11, s = t & 2047;
  __shared__ float cs[32], sn[32];
  if (tid < 32) {
    int pos = POS[t];
    double inv = pow(10000.0, -((double)(2 * tid) / 64.0));
    float ang = (float)pos * (float)inv;
    cs[tid] = cosf(ang);
    sn[tid] = sinf(ang);
  }
  __syncthreads();
  if (tid < 32) {
    const float* kr = KVA + (size_t)t * (kKvLora + kDR) + kKvLora;
    float x1 = kr[tid], x2 = kr[32 + tid];
    float y1 = x1 * cs[tid] - x2 * sn[tid];
    float y2 = x2 * cs[tid] + x1 * sn[tid];
    unsigned short h1 = f32_to_bf16(y1);
    Krh[(size_t)t * 64 + tid] = h1;
    Krl[(size_t)t * 64 + tid] = f32_to_bf16(y1 - bf16_to_f32(h1));
    unsigned short h2 = f32_to_bf16(y2);
    Krh[(size_t)t * 64 + 32 + tid] = h2;
    Krl[(size_t)t * 64 + 32 + tid] = f32_to_bf16(y2 - bf16_to_f32(h2));
  }
  for (int it = tid; it < kH * 32; it += 64) {
    int h = it >> 5, i = it & 31;
    size_t base = ((size_t)((b * 16 + h) * 2048 + s)) * 192 + 128;
    float x1 = bf16_to_f32(Qh[base + i]) + bf16_to_f32(Ql[base + i]);
    float x2 = bf16_to_f32(Qh[base + 32 + i]) + bf16_to_f32(Ql[base + 32 + i]);
    float y1 = x1 * cs[i] - x2 * sn[i];
    float y2 = x2 * cs[i] + x1 * sn[i];
    unsigned short h1 = f32_to_bf16(y1);
    Qh[base + i] = h1;
    Ql[base + i] = f32_to_bf16(y1 - bf16_to_f32(h1));
    unsigned short h2 = f32_to_bf16(y2);
    Qh[base + 32 + i] = h2;
    Ql[base + 32 + i] = f32_to_bf16(y2 - bf16_to_f32(h2));
  }
}

// ---------------- MFMA indexer scores: one 64x64 tile per block (rows q>=1024 only) ----------------
__global__ __launch_bounds__(256) void isc_mfma_kernel(const unsigned short* __restrict__ QIKH,
                                                       const unsigned short* __restrict__ QIKL,
                                                       const float* __restrict__ WGT,
                                                       float* __restrict__ ISC) {
  const int qt = blockIdx.y + 16;
  const int kt = blockIdx.x;
  if (kt > qt) return;
  const int b = blockIdx.z;
  const int q0 = qt * 64, k0 = kt * 64;
  const int tid = threadIdx.x, wave = tid >> 6, lane = tid & 63;
  const int fr = lane & 15, fg = lane >> 4;

  __shared__ unsigned short KiH[4 * 64 * 40], KiL[4 * 64 * 40];
  __shared__ float wgs[64 * 8];

  {
    int key = tid >> 2, sub = (tid & 3) * 8;
    size_t rb = (size_t)(b * kS + k0 + key) * 1152 + 1024;
#pragma unroll
    for (int kc = 0; kc < 4; ++kc) {
      *(bf16x8*)&KiH[kc * 2560 + key * 40 + sub] = *(const bf16x8*)&QIKH[rb + kc * 32 + sub];
      *(bf16x8*)&KiL[kc * 2560 + key * 40 + sub] = *(const bf16x8*)&QIKL[rb + kc * 32 + sub];
    }
#pragma unroll
    for (int t = 0; t < 2; ++t) {
      int i = t * 256 + tid;
      wgs[i] = WGT[(size_t)(b * kS + q0 + (i >> 3)) * kHI + (i & 7)];
    }
  }
  const size_t qrow = (size_t)(b * kS + q0 + wave * 16 + fr) * 1152;
  f32x4 sacc[4];
  const f32x4 vzero = {0.f, 0.f, 0.f, 0.f};
#pragma unroll
  for (int j = 0; j < 4; ++j) sacc[j] = vzero;

  bf16x8 qAh[4], qAl[4], qBh[4], qBl[4];
#define LOADQ(DH_, DL_, H_)                                                     \
  _Pragma("unroll") for (int kc = 0; kc < 4; ++kc) {                            \
    DH_[kc] = *(const bf16x8*)&QIKH[qrow + (H_)*128 + kc * 32 + fg * 8];        \
    DL_[kc] = *(const bf16x8*)&QIKL[qrow + (H_)*128 + kc * 32 + fg * 8];        \
  }
  LOADQ(qAh, qAl, 0)
  __syncthreads();
#define MFMA_HEAD(QH_, QL_, H_)                                                 \
  {                                                                             \
    f32x4 acc[4];                                                               \
    _Pragma("unroll") for (int j = 0; j < 4; ++j) acc[j] = vzero;               \
    _Pragma("unroll") for (int kc = 0; kc < 4; ++kc) {                          \
      _Pragma("unroll") for (int j = 0; j < 4; ++j) {                           \
        bf16x8 kh = *(const bf16x8*)&KiH[kc * 2560 + (j * 16 + fr) * 40 + fg * 8]; \
        bf16x8 kl = *(const bf16x8*)&KiL[kc * 2560 + (j * 16 + fr) * 40 + fg * 8]; \
        acc[j] = __builtin_amdgcn_mfma_f32_16x16x32_bf16(QH_[kc], kh, acc[j], 0, 0, 0); \
        acc[j] = __builtin_amdgcn_mfma_f32_16x16x32_bf16(QH_[kc], kl, acc[j], 0, 0, 0); \
        acc[j] = __builtin_amdgcn_mfma_f32_16x16x32_bf16(QL_[kc], kh, acc[j], 0, 0, 0); \
      }                                                                         \
    }                                                                           \
    float wv[4];                                                                \
    _Pragma("unroll") for (int r = 0; r < 4; ++r)                               \
        wv[r] = wgs[(wave * 16 + fg * 4 + r) * 8 + (H_)];                       \
    _Pragma("unroll") for (int j = 0; j < 4; ++j)                               \
      _Pragma("unroll") for (int r = 0; r < 4; ++r)                             \
        sacc[j][r] += fmaxf(acc[j][r], 0.0f) * wv[r];                           \
  }
#pragma unroll
  for (int hp = 0; hp < 4; ++hp) {
    int h0 = hp * 2;
    LOADQ(qBh, qBl, h0 + 1)
    MFMA_HEAD(qAh, qAl, h0)
    if (hp < 3) LOADQ(qAh, qAl, h0 + 2)
    MFMA_HEAD(qBh, qBl, h0 + 1)
  }
#undef LOADQ
#undef MFMA_HEAD
#pragma unroll
  for (int r = 0; r < 4; ++r) {
    size_t ob = (size_t)(b * kS + q0 + wave * 16 + fg * 4 + r) * kS + k0;
#pragma unroll
    for (int j = 0; j < 4; ++j) ISC[ob + j * 16 + fr] = sacc[j][r];
  }
}

// ---------------- exact stable top-k from precomputed scores ----------------
__global__ __launch_bounds__(256) void topk_kernel(const float* __restrict__ ISC,
                                                   unsigned* __restrict__ SEL) {
  int row = blockIdx.x;
  int q = row & (kS - 1);
  int L = q + 1;
  unsigned* selrow = SEL + (size_t)row * (kS / 32);
  int tid = threadIdx.x;
  if (L <= kTopK) {
    if (tid < kS / 32) {
      int base = tid * 32;
      unsigned w;
      if (base + 32 <= L) w = 0xFFFFFFFFu;
      else if (base >= L) w = 0u;
      else w = (1u << (L - base)) - 1u;
      selrow[tid] = w;
    }
    return;
  }
  __shared__ unsigned keys[kS];
  __shared__ unsigned hist[256];
  __shared__ unsigned msk[kS / 32];
  __shared__ unsigned pick[2];
  if (tid < kS / 32) msk[tid] = 0u;
  const float* x = ISC + (size_t)row * kS;
  for (int k = tid; k < L; k += 256) {
    unsigned u = __float_as_uint(x[k]);
    keys[k] = (u & 0x80000000u) ? ~u : (u | 0x80000000u);
  }
  __syncthreads();
  unsigned prefix = 0u;
  int r = kTopK;
  for (int shift = 24; shift >= 0; shift -= 8) {
    hist[tid] = 0u;
    __syncthreads();
    unsigned hm = (shift == 24) ? 0u : (0xFFFFFFFFu << (shift + 8));
    for (int k = tid; k < L; k += 256) {
      unsigned key = keys[k];
      if ((key & hm) == (prefix & hm)) atomicAdd(&hist[(key >> shift) & 255u], 1u);
    }
    __syncthreads();
    if (tid == 0) {
      int rr = r, bsel = 0;
      for (int bb = 255; bb >= 0; --bb) {
        int c = (int)hist[bb];
        if (rr <= c) { bsel = bb; break; }
        rr -= c;
      }
      pick[0] = (unsigned)bsel;
      pick[1] = (unsigned)rr;
    }
    __syncthreads();
    prefix |= pick[0] << shift;
    r = (int)pick[1];
    __syncthreads();
  }
  unsigned T = prefix;
  int ties_take = r;
  int base = tid * 8;
  int cnt = 0;
#pragma unroll
  for (int j = 0; j < 8; ++j) {
    int k = base + j;
    if (k < L && keys[k] == T) ++cnt;
  }
  hist[tid] = (unsigned)cnt;
  __syncthreads();
  if (tid == 0) {
    unsigned run = 0;
    for (int t = 0; t < 256; ++t) { unsigned c = hist[t]; hist[t] = run; run += c; }
  }
  __syncthreads();
  int trank = (int)hist[tid];
  unsigned bits = 0u;
#pragma unroll
  for (int j = 0; j < 8; ++j) {
    int k = base + j;
    if (k < L) {
      unsigned key = keys[k];
      bool s;
      if (key > T) s = true;
      else if (key == T) { s = trank < ties_take; ++trank; }
      else s = false;
      if (s) bits |= (1u << j);
    }
  }
  atomicOr(&msk[tid >> 2], bits << ((tid & 3) * 8));
  __syncthreads();
  if (tid < kS / 32) selrow[tid] = msk[tid];
}

// ---------------- MFMA flash attention (round-11 structure; slim LDS pads -> 3 blocks/CU) ----------------
// grid.x = flattened (qt,h), global longest-first: qt = 31 - (x>>4), h = x&15; b = grid.y.
// QK^T: 3-pass hi/lo; K chunks LDS double-buffered (1 barrier/chunk) with reg prefetch.
// PV: (Ph+Pl)*Vh then Ph*Vl; V prefetched into regs early. No tile-skip (costs pipeline depth).
__global__ __launch_bounds__(256) void attn_mfma_kernel(const unsigned short* __restrict__ Qh,
                                                        const unsigned short* __restrict__ Ql,
                                                        const unsigned short* __restrict__ Knh,
                                                        const unsigned short* __restrict__ Knl,
                                                        const unsigned short* __restrict__ Krh,
                                                        const unsigned short* __restrict__ Krl,
                                                        const unsigned short* __restrict__ Vth,
                                                        const unsigned short* __restrict__ Vtl,
                                                        const unsigned* __restrict__ SEL,
                                                        unsigned short* __restrict__ CTXB) {
  const int flat = blockIdx.x;
  const int qt = 31 - (flat >> 4);        // longest blocks dispatch first
  const int h = flat & 15;
  const int b = blockIdx.y;
  const int q0 = qt * 64;
  const int tid = threadIdx.x, wave = tid >> 6, lane = tid & 63;
  const int fr = lane & 15, fg = lane >> 4;
  const float scale = 0.07216878364870323f;  // 1/sqrt(192)

  __shared__ unsigned short KsH[2 * 64 * 36], KsL[2 * 64 * 36];  // double-buffered, pad-36 rows
  __shared__ unsigned short Ph[64 * 68], Pl[64 * 68];            // pad-68 rows
  __shared__ unsigned short Vs[128 * 68];                        // pad-68 rows
  __shared__ unsigned selw[64][2];
  // LDS total: 2*4608*2*2 + 2*4352*2 + 8704*2 + 512 = 53760 B -> 3 blocks/CU

  bf16x8 qh[6], ql[6];
  {
    const size_t qbase = ((size_t)((b * 16 + h) * 2048 + q0 + wave * 16 + fr)) * 192;
#pragma unroll
    for (int kc = 0; kc < 6; ++kc) {
      qh[kc] = *(const bf16x8*)&Qh[qbase + kc * 32 + fg * 8];
      ql[kc] = *(const bf16x8*)&Ql[qbase + kc * 32 + fg * 8];
    }
  }
  float m_run[4], l_run[4];
#pragma unroll
  for (int r = 0; r < 4; ++r) { m_run[r] = kNeg; l_run[r] = 0.0f; }
  f32x4 O[8];
  const f32x4 vzero = {0.f, 0.f, 0.f, 0.f};
#pragma unroll
  for (int j = 0; j < 8; ++j) O[j] = vzero;

  const int key = tid >> 2, sub = (tid & 3) * 8;
  const size_t knbase = (size_t)((b * 16 + h) * 2048) * 128;
  const size_t krbase = (size_t)(b * 2048) * 64;
  const size_t vbase0 = ((size_t)((b * 16 + h) * 128)) * 2048;

  const int nkt = qt + 1;
  for (int kt = 0; kt < nkt; ++kt) {
    const int k0 = kt * 64;
    const size_t vbase = vbase0 + k0;
    unsigned selreg = 0;
    if (tid < 128)
      selreg = SEL[(size_t)(b * kS + q0 + (tid >> 1)) * (kS / 32) + (k0 >> 5) + (tid & 1)];
    bf16x8 kh_pre[2], kl_pre[2];
    {
      size_t src = knbase + (size_t)(k0 + key) * 128 + sub;   // chunk 0
      kh_pre[0] = *(const bf16x8*)&Knh[src];
      kl_pre[0] = *(const bf16x8*)&Knl[src];
    }
    bf16x8 vpre[4];
#pragma unroll
    for (int it = 0; it < 4; ++it) {
      int idx = it * 256 + tid;
      int dv = idx >> 3, ks8 = (idx & 7) * 8;
      vpre[it] = *(const bf16x8*)&Vth[vbase + (size_t)dv * 2048 + ks8];
    }
    __syncthreads();  // B1: prev tile's Ks(last chunk)/Vs/selw reads done
    if (tid < 128) selw[tid >> 1][tid & 1] = selreg;
    f32x4 acc[4];
#pragma unroll
    for (int j = 0; j < 4; ++j) acc[j] = vzero;
#pragma unroll
    for (int kc = 0; kc < 6; ++kc) {
      const int buf = (kc & 1) * 2304;
      *(bf16x8*)&KsH[buf + key * 36 + sub] = kh_pre[kc & 1];
      *(bf16x8*)&KsL[buf + key * 36 + sub] = kl_pre[kc & 1];
      if (kc < 5) {   // prefetch next chunk (hidden under barrier+MFMA)
        if (kc + 1 < 4) {
          size_t src = knbase + (size_t)(k0 + key) * 128 + (kc + 1) * 32 + sub;
          kh_pre[(kc + 1) & 1] = *(const bf16x8*)&Knh[src];
          kl_pre[(kc + 1) & 1] = *(const bf16x8*)&Knl[src];
        } else {
          size_t src = krbase + (size_t)(k0 + key) * 64 + (kc - 3) * 32 + sub;
          kh_pre[(kc + 1) & 1] = *(const bf16x8*)&Krh[src];
          kl_pre[(kc + 1) & 1] = *(const bf16x8*)&Krl[src];
        }
      }
      __syncthreads();  // single barrier per chunk (double-buffered Ks)
#pragma unroll
      for (int j = 0; j < 4; ++j) {
        bf16x8 kh = *(const bf16x8*)&KsH[buf + (j * 16 + fr) * 36 + fg * 8];
        bf16x8 kl = *(const bf16x8*)&KsL[buf + (j * 16 + fr) * 36 + fg * 8];
        acc[j] = __builtin_amdgcn_mfma_f32_16x16x32_bf16(qh[kc], kh, acc[j], 0, 0, 0);
        acc[j] = __builtin_amdgcn_mfma_f32_16x16x32_bf16(qh[kc], kl, acc[j], 0, 0, 0);
        acc[j] = __builtin_amdgcn_mfma_f32_16x16x32_bf16(ql[kc], kh, acc[j], 0, 0, 0);
      }
    }
    float p[4][4];
    float fsc[4];
#pragma unroll
    for (int r = 0; r < 4; ++r) {
      int row = wave * 16 + fg * 4 + r;
      float sv[4];
      float vmax = kNeg;
#pragma unroll
      for (int j = 0; j < 4; ++j) {
        int col = j * 16 + fr;
        bool bit = (selw[row][col >> 5] >> (col & 31)) & 1u;
        float s = bit ? acc[j][r] * scale : kNeg;
        sv[j] = s;
        vmax = fmaxf(vmax, s);
      }
#pragma unroll
      for (int m = 1; m <= 8; m <<= 1) vmax = fmaxf(vmax, __shfl_xor(vmax, m, 64));
      float newm = fmaxf(m_run[r], vmax);
      float sum = 0.0f;
#pragma unroll
      for (int j = 0; j < 4; ++j) {
        float pp = (sv[j] < -1e29f) ? 0.0f : expf(sv[j] - newm);
        p[j][r] = pp;
        sum += pp;
      }
#pragma unroll
      for (int m = 1; m <= 8; m <<= 1) sum += __shfl_xor(sum, m, 64);
      fsc[r] = expf(m_run[r] - newm);
      l_run[r] = l_run[r] * fsc[r] + sum;
      m_run[r] = newm;
    }
#pragma unroll
    for (int j = 0; j < 8; ++j)
#pragma unroll
      for (int r = 0; r < 4; ++r) O[j][r] *= fsc[r];
#pragma unroll
    for (int r = 0; r < 4; ++r) {
      int row = wave * 16 + fg * 4 + r;
#pragma unroll
      for (int j = 0; j < 4; ++j) {
        int col = j * 16 + fr;
        float pp = p[j][r];
        unsigned short hi = f32_to_bf16(pp);
        Ph[row * 68 + col] = hi;
        Pl[row * 68 + col] = f32_to_bf16(pp - bf16_to_f32(hi));
      }
    }
#pragma unroll
    for (int it = 0; it < 4; ++it) {
      int idx = it * 256 + tid;
      int dv = idx >> 3, ks8 = (idx & 7) * 8;
      *(bf16x8*)&Vs[dv * 68 + ks8] = vpre[it];
    }
#pragma unroll
    for (int it = 0; it < 4; ++it) {
      int idx = it * 256 + tid;
      int dv = idx >> 3, ks8 = (idx & 7) * 8;
      vpre[it] = *(const bf16x8*)&Vtl[vbase + (size_t)dv * 2048 + ks8];
    }
    __syncthreads();  // B3: Vs (hi) ready
#pragma unroll
    for (int kk = 0; kk < 2; ++kk) {
      bf16x8 pah = *(const bf16x8*)&Ph[(wave * 16 + fr) * 68 + kk * 32 + fg * 8];
      bf16x8 pal = *(const bf16x8*)&Pl[(wave * 16 + fr) * 68 + kk * 32 + fg * 8];
#pragma unroll
      for (int j = 0; j < 8; ++j) {
        bf16x8 vb = *(const bf16x8*)&Vs[(j * 16 + fr) * 68 + kk * 32 + fg * 8];
        O[j] = __builtin_amdgcn_mfma_f32_16x16x32_bf16(pah, vb, O[j], 0, 0, 0);
        O[j] = __builtin_amdgcn_mfma_f32_16x16x32_bf16(pal, vb, O[j], 0, 0, 0);
      }
    }
    __syncthreads();  // B4: PV1 Vs reads done
#pragma unroll
    for (int it = 0; it < 4; ++it) {
      int idx = it * 256 + tid;
      int dv = idx >> 3, ks8 = (idx & 7) * 8;
      *(bf16x8*)&Vs[dv * 68 + ks8] = vpre[it];
    }
    __syncthreads();  // B5: Vs (lo) ready
#pragma unroll
    for (int kk = 0; kk < 2; ++kk) {
      bf16x8 pah = *(const bf16x8*)&Ph[(wave * 16 + fr) * 68 + kk * 32 + fg * 8];
#pragma unroll
      for (int j = 0; j < 8; ++j) {
        bf16x8 vb = *(const bf16x8*)&Vs[(j * 16 + fr) * 68 + kk * 32 + fg * 8];
        O[j] = __builtin_amdgcn_mfma_f32_16x16x32_bf16(pah, vb, O[j], 0, 0, 0);
      }
    }
  }
#pragma unroll
  for (int r = 0; r < 4; ++r) {
    float inv = 1.0f / l_run[r];
    float vals[8];
    float am = 0.0f;
#pragma unroll
    for (int j = 0; j < 8; ++j) {
      vals[j] = O[j][r] * inv;
      am = fmaxf(am, fabsf(vals[j]));
    }
#pragma unroll
    for (int m = 1; m <= 8; m <<= 1) am = fmaxf(am, __shfl_xor(am, m, 64));
    am = fmaxf(am, 1e-4f);
    float s = act_scale_from_amax(am);
    size_t obase = (size_t)(b * kS + q0 + wave * 16 + fg * 4 + r) * 2048 + h * 128;
#pragma unroll
    for (int j = 0; j < 8; ++j)
      CTXB[obase + j * 16 + fr] = f32_to_bf16(fp8_e4m3_qdq(clamp448(vals[j] / s)) * s);
  }
}

extern "C" void kernel_launch(void* const* d_in, const int* in_sizes, int n_in,
                              void* d_out, int out_size, void* d_ws, size_t ws_size,
                              hipStream_t stream) {
  (void)in_sizes; (void)n_in;

  const float* hidden = (const float*)d_in[0];
  const float* Wqa    = (const float*)d_in[1];
  const float* qnw    = (const float*)d_in[2];
  const float* Wqb    = (const float*)d_in[3];
  const float* Wkva   = (const float*)d_in[4];
  const float* kvnw   = (const float*)d_in[5];
  const float* Wkvb   = (const float*)d_in[6];
  const float* Wiq    = (const float*)d_in[7];
  const float* Wik    = (const float*)d_in[8];
  const float* Wig    = (const float*)d_in[9];
  const float* Wo     = (const float*)d_in[10];
  const int*   pos    = (const int*)d_in[11];
  char* ws = (char*)d_ws;
  float* out = (float*)d_out;

  if (ws_size < WS_NEED) {
    fill_kernel<<<dim3((out_size + 255) / 256), dim3(256), 0, stream>>>(out, out_size, 54321.0f);
    return;
  }

  float* scWqa  = (float*)(ws + OFF_SC) + 0;
  float* scWqb  = (float*)(ws + OFF_SC) + 128;
  float* scWkva = (float*)(ws + OFF_SC) + 320;
  float* scWkvb = (float*)(ws + OFF_SC) + 400;
  float* scWo   = (float*)(ws + OFF_SC) + 528;
  unsigned* sel = (unsigned*)(ws + OFF_SEL_B);
  float* wgt    = (float*)(ws + OFF_WGT_B);
  unsigned short* krh = (unsigned short*)(ws + OFF_KRH_B);
  unsigned short* krl = (unsigned short*)(ws + OFF_KRL_B);
  unsigned short* wo_b = (unsigned short*)(ws + OFF_WOB_B);

  unsigned short* h_hi  = (unsigned short*)(ws + A_HHI);
  unsigned short* h_lo  = (unsigned short*)(ws + A_HLO);
  unsigned short* wqk_h = (unsigned short*)(ws + A_WQKH);
  unsigned short* wqk_l = (unsigned short*)(ws + A_WQKL);
  unsigned short* qik_h = (unsigned short*)(ws + A_QIKH);
  unsigned short* qik_l = (unsigned short*)(ws + A_QIKL);
  float* isc = (float*)(ws + A_ISC);

  unsigned short* hidq_b = (unsigned short*)(ws + B_HIDQ);
  unsigned short* wqa_b  = (unsigned short*)(ws + B_WQA);
  unsigned short* wqb_b  = (unsigned short*)(ws + B_WQB);
  unsigned short* wkva_b = (unsigned short*)(ws + B_WKVA);
  unsigned short* wkvb_b = (unsigned short*)(ws + B_WKVB);
  float* qa_f   = (float*)(ws + B_QAF);
  unsigned short* qa_b  = (unsigned short*)(ws + B_QAB);
  float* kva    = (float*)(ws + B_KVA);
  unsigned short* ckv_b = (unsigned short*)(ws + B_CKV);
  unsigned short* q_h   = (unsigned short*)(ws + B_QH);
  unsigned short* q_l   = (unsigned short*)(ws + B_QL);
  unsigned short* kn_h  = (unsigned short*)(ws + B_KNH);
  unsigned short* kn_l  = (unsigned short*)(ws + B_KNL);
  unsigned short* v_th  = (unsigned short*)(ws + B_VTH);
  unsigned short* v_tl  = (unsigned short*)(ws + B_VTL);
  unsigned short* ctx_b = (unsigned short*)(ws + B_CTXB);

  // ---------- Phase A: indexer + top-k ----------
  hidden_prep_kernel<<<dim3(16384), dim3(256), 0, stream>>>(hidden, h_hi, h_lo, hidq_b);
  split_bf16x2_kernel<<<dim3(8192),  dim3(256), 0, stream>>>(Wiq, wqk_h, wqk_l, (size_t)kHI * kDI * kDH);
  split_bf16x2_kernel<<<dim3(1024),  dim3(256), 0, stream>>>(Wik, wqk_h + (size_t)1024 * kDH, wqk_l + (size_t)1024 * kDH, (size_t)kDI * kDH);
  gemm_f32_kernel<<<dim3(1, 64), dim3(256), 0, stream>>>(hidden, Wig, wgt, kHI, kDH, 0.35355339059327373f, 16);
  mfma_gemm3_kernel<<<dim3(9, 32), dim3(256), 0, stream>>>(h_hi, h_lo, wqk_h, wqk_l, qik_h, qik_l, kDH, 1152);
  isc_mfma_kernel<<<dim3(32, 16, kB), dim3(256), 0, stream>>>(qik_h, qik_l, wgt, isc);
  topk_kernel<<<dim3(kNTok), dim3(256), 0, stream>>>(isc, sel);

  // ---------- Phase B: fp8-path linears on MFMA ----------
  fused_weight_kernel<<<dim3(16, 8),  dim3(256), 0, stream>>>(Wqa,  scWqa,  wqa_b,  kQLora, kDH);
  fused_weight_kernel<<<dim3(8, 24),  dim3(256), 0, stream>>>(Wqb,  scWqb,  wqb_b,  kH * (kDN + kDR), kQLora);
  fused_weight_kernel<<<dim3(16, 5),  dim3(256), 0, stream>>>(Wkva, scWkva, wkva_b, kKvLora + kDR, kDH);
  fused_weight_kernel<<<dim3(4, 32),  dim3(256), 0, stream>>>(Wkvb, scWkvb, wkvb_b, kH * (kDN + kDV), kKvLora);
  fused_weight_kernel<<<dim3(16, 16), dim3(256), 0, stream>>>(Wo,   scWo,   wo_b,   kDH, kH * kDV);

  // q_a -> rms -> q (bf16 hi/lo, [b,h,s,192])
  mfma_gemm_kernel<0, true><<<dim3(8, 32), dim3(256), 0, stream>>>(hidq_b, wqa_b, scWqa, qa_f, nullptr, nullptr, nullptr, nullptr, 1024, kDH, 1024);
  rms_qdq_kernel<<<dim3(kNTok), dim3(256), 0, stream>>>(qa_f, qnw, qa_b, kQLora, kQLora, kQLora);
  mfma_gemm_kernel<1, true><<<dim3(24, 32), dim3(256), 0, stream>>>(qa_b, wqb_b, scWqb, nullptr, q_h, q_l, nullptr, nullptr, 3072, kQLora, 3072);
  // kv_a -> rms -> kv (split to Kn hi/lo [b,h,s,128] + V^T hi/lo [b,h,dv,s])
  mfma_gemm_kernel<0, true><<<dim3(5, 32), dim3(256), 0, stream>>>(hidq_b, wkva_b, scWkva, kva, nullptr, nullptr, nullptr, nullptr, 576, kDH, 576);
  rms_qdq_kernel<<<dim3(kNTok), dim3(256), 0, stream>>>(kva, kvnw, ckv_b, kKvLora, kKvLora + kDR, kKvLora);
  rope_split_kernel<<<dim3(kNTok), dim3(64), 0, stream>>>(q_h, q_l, kva, krh, krl, pos);
  mfma_gemm_kernel<2, true><<<dim3(32, 32), dim3(256), 0, stream>>>(ckv_b, wkvb_b, scWkvb, nullptr, kn_h, kn_l, v_th, v_tl, 4096, kKvLora, 4096);

  // ---------- attention (fused ctx fp8-qdq) + output ----------
  attn_mfma_kernel<<<dim3(512, kB), dim3(256), 0, stream>>>(q_h, q_l, kn_h, kn_l, krh, krl, v_th, v_tl, sel, ctx_b);
  mfma_gemm_kernel<0, true><<<dim3(16, 32), dim3(256), 0, stream>>>(ctx_b, wo_b, scWo, out, nullptr, nullptr, nullptr, nullptr, kDH, kH * kDV, 2048);
}

// Round 15
// 1177.325 us; speedup vs baseline: 1.0816x; 1.0816x over previous
//
#include <hip/hip_runtime.h>
#include <math.h>

namespace {
constexpr int kB = 2, kS = 2048, kDH = 2048, kH = 16, kDN = 128, kDR = 64, kDV = 128;
constexpr int kKvLora = 512, kQLora = 1024, kHI = 8, kDI = 128, kTopK = 1024;
constexpr int kNTok = kB * kS;             // 4096
constexpr float kNeg = -1e30f;

// ---- fixed region (bytes) ----
constexpr size_t OFF_SC    = 0;                          // 784 f32 scales
constexpr size_t OFF_SEL_B = 4096;                       // 1 MB
constexpr size_t OFF_WGT_B = OFF_SEL_B + 1048576;        // 128 KB
constexpr size_t OFF_KRH_B = OFF_WGT_B + 131072;         // 512 KB
constexpr size_t OFF_KRL_B = OFF_KRH_B + 524288;         // 512 KB
constexpr size_t OFF_WOB_B = OFF_KRL_B + 524288;         // 8 MB  (Wo bf16)
constexpr size_t POOL      = OFF_WOB_B + 8388608;        // 10,620,928
// ---- phase B core ----
constexpr size_t B_HIDQ = POOL;                 // 16 MB bf16
constexpr size_t B_WQA  = POOL + 16777216;      // 4 MB
constexpr size_t B_WQB  = POOL + 20971520;      // 6 MB
constexpr size_t B_WKVA = POOL + 27262976;      // 2.5 MB
constexpr size_t B_WKVB = POOL + 29884416;      // 4 MB
constexpr size_t B_QAF  = POOL + 34078720;      // 16 MB f32
constexpr size_t B_QAB  = POOL + 50855936;      // 8 MB bf16
constexpr size_t B_KVA  = POOL + 59244544;      // 9.4 MB f32
constexpr size_t B_CKV  = POOL + 68681728;      // 4 MB bf16
constexpr size_t B_QH   = POOL + 72876032;      // 24 MB bf16
constexpr size_t B_QL   = POOL + 98041856;      // 24 MB bf16
constexpr size_t B_KNH  = POOL + 123207680;     // 16 MB
constexpr size_t B_KNL  = POOL + 139984896;     // 16 MB
constexpr size_t B_VTH  = POOL;                 // 16 MB (over dead hidq)
constexpr size_t B_VTL  = POOL + 34078720;      // 16 MB (over dead qa_f)
constexpr size_t B_CTXB = POOL + 50855936;      // 16 MB (over dead qa_b + kva)
// ---- phase A (indexer) ----
constexpr size_t A_HHI  = POOL + 16777216;      // 16 MB bf16
constexpr size_t A_HLO  = POOL + 33554432;      // 16 MB bf16
constexpr size_t A_WQKH = POOL + 50331648;      // 4,718,592
constexpr size_t A_WQKL = POOL + 55050240;      // 4,718,592
constexpr size_t A_QIKH = POOL + 59768832;      // 9,437,184 bf16 [4096][1152]
constexpr size_t A_QIKL = POOL + 69206016;      // 9,437,184
constexpr size_t A_ISC  = POOL + 78643200;      // 33,554,432 f32 [4096][2048]
constexpr size_t WS_NEED = POOL + 156762112;    // 167,383,040 B (known-good)
} // namespace

typedef __attribute__((ext_vector_type(4))) float f32x4;
typedef __attribute__((ext_vector_type(8))) short bf16x8;
typedef __attribute__((address_space(1))) const void gvoid;
typedef __attribute__((address_space(3))) void lvoid;

// Exact e4m3fn round-to-nearest-even quant-dequant for |x| <= 448 (incl. subnormals).
__device__ __forceinline__ float fp8_e4m3_qdq(float x) {
  float ax = fabsf(x);
  int e;
  (void)frexpf(ax, &e);
  int ee = e - 1;
  if (ee < -6) ee = -6;
  float q = ldexpf(1.0f, ee - 3);
  float y = rintf(ax / q) * q;
  return (x < 0.0f) ? -y : y;
}

__device__ __forceinline__ float act_scale_from_amax(float amax) {
  float t = amax / 448.0f;
  unsigned u = __float_as_uint(t);
  int e = (int)((u >> 23) & 255u) - 127;
  if (u & 0x7fffffu) e += 1;
  return __uint_as_float((unsigned)(e + 127) << 23);
}

__device__ __forceinline__ float clamp448(float v) {
  return fminf(fmaxf(v, -448.0f), 448.0f);
}

__device__ __forceinline__ unsigned short f32_to_bf16(float f) {
  unsigned u = __float_as_uint(f);
  unsigned r = (u + 0x7FFFu + ((u >> 16) & 1u)) >> 16;
  return (unsigned short)r;
}
__device__ __forceinline__ float bf16_to_f32(unsigned short h) {
  return __uint_as_float((unsigned)h << 16);
}

__global__ __launch_bounds__(256) void fill_kernel(float* p, int n, float v) {
  int i = blockIdx.x * 256 + threadIdx.x;
  if (i < n) p[i] = v;
}

// ---------------- fused hidden prep: hi/lo split + fp8-qdq -> bf16 (one read) ----------------
__global__ __launch_bounds__(256) void hidden_prep_kernel(const float* __restrict__ X,
                                                          unsigned short* __restrict__ HI,
                                                          unsigned short* __restrict__ LO,
                                                          unsigned short* __restrict__ QB) {
  int wid = blockIdx.x * 4 + (threadIdx.x >> 6);
  int lane = threadIdx.x & 63;
  const float* x = X + (size_t)wid * 128;
  float v0 = x[lane], v1 = x[lane + 64];
  size_t o0 = (size_t)wid * 128 + lane, o1 = o0 + 64;
  unsigned short h0 = f32_to_bf16(v0);
  HI[o0] = h0; LO[o0] = f32_to_bf16(v0 - bf16_to_f32(h0));
  unsigned short h1 = f32_to_bf16(v1);
  HI[o1] = h1; LO[o1] = f32_to_bf16(v1 - bf16_to_f32(h1));
  float am = fmaxf(fabsf(v0), fabsf(v1));
#pragma unroll
  for (int m = 32; m >= 1; m >>= 1) am = fmaxf(am, __shfl_xor(am, m, 64));
  am = fmaxf(am, 1e-4f);
  float s = act_scale_from_amax(am);
  QB[o0] = f32_to_bf16(fp8_e4m3_qdq(clamp448(v0 / s)) * s);
  QB[o1] = f32_to_bf16(fp8_e4m3_qdq(clamp448(v1 / s)) * s);
}

// ---------------- fused weight 128x128-block scale + bf16 quantized values ----------------
__global__ __launch_bounds__(256) void fused_weight_kernel(const float* __restrict__ W,
                                                           float* __restrict__ SC,
                                                           unsigned short* __restrict__ WB,
                                                           int O, int I) {
  int kb = blockIdx.x, ob = blockIdx.y;
  int bo = ob * 128, bi = kb * 128;
  int tid = threadIdx.x;
  __shared__ float red[256];
  __shared__ float s_scale;
  float am = 0.0f;
  for (int idx = tid; idx < 128 * 128; idx += 256) {
    int r = bo + (idx >> 7), c = bi + (idx & 127);
    if (r < O) am = fmaxf(am, fabsf(W[(size_t)r * I + c]));
  }
  red[tid] = am; __syncthreads();
  for (int s = 128; s >= 1; s >>= 1) {
    if (tid < s) red[tid] = fmaxf(red[tid], red[tid + s]);
    __syncthreads();
  }
  if (tid == 0) {
    float sc = fmaxf(red[0], 1e-4f) / 448.0f;
    SC[(size_t)ob * gridDim.x + kb] = sc;
    s_scale = sc;
  }
  __syncthreads();
  float sc = s_scale;
  for (int idx = tid; idx < 128 * 128; idx += 256) {
    int r = bo + (idx >> 7), c = bi + (idx & 127);
    unsigned short v = 0;
    if (r < O) v = f32_to_bf16(fp8_e4m3_qdq(clamp448(W[(size_t)r * I + c] / sc)));
    WB[(size_t)r * I + c] = v;
  }
}

// ---------------- f32 -> bf16 hi/lo split ----------------
__global__ __launch_bounds__(256) void split_bf16x2_kernel(const float* __restrict__ X,
                                                           unsigned short* __restrict__ HI,
                                                           unsigned short* __restrict__ LO,
                                                           size_t n) {
  size_t i = (size_t)blockIdx.x * 256 + threadIdx.x;
  if (i >= n) return;
  float x = X[i];
  unsigned short h = f32_to_bf16(x);
  HI[i] = h;
  LO[i] = f32_to_bf16(x - bf16_to_f32(h));
}

// ---------------- fused RMSNorm + activation qdq -> bf16 (per row) ----------------
__global__ __launch_bounds__(256) void rms_qdq_kernel(const float* __restrict__ X,
                                                      const float* __restrict__ G,
                                                      unsigned short* __restrict__ Y,
                                                      int C, int xs, int ys) {
  int row = blockIdx.x, tid = threadIdx.x;
  __shared__ float xr[1024];
  __shared__ float red[256];
  const float* x = X + (size_t)row * xs;
  float ssq = 0.0f;
  for (int i = tid; i < C; i += 256) { float v = x[i]; xr[i] = v; ssq += v * v; }
  red[tid] = ssq; __syncthreads();
  for (int s = 128; s >= 1; s >>= 1) { if (tid < s) red[tid] += red[tid + s]; __syncthreads(); }
  float inv = 1.0f / sqrtf(red[0] / (float)C + 1e-6f);
  __syncthreads();
  int wv = tid >> 6, lane = tid & 63;
  for (int blk = wv; blk < C / 128; blk += 4) {
    int i0 = blk * 128 + lane, i1 = i0 + 64;
    float y0 = xr[i0] * inv * G[i0];
    float y1 = xr[i1] * inv * G[i1];
    float am = fmaxf(fabsf(y0), fabsf(y1));
#pragma unroll
    for (int m = 32; m >= 1; m >>= 1) am = fmaxf(am, __shfl_xor(am, m, 64));
    am = fmaxf(am, 1e-4f);
    float s = act_scale_from_amax(am);
    Y[(size_t)row * ys + i0] = f32_to_bf16(fp8_e4m3_qdq(clamp448(y0 / s)) * s);
    Y[(size_t)row * ys + i1] = f32_to_bf16(fp8_e4m3_qdq(clamp448(y1 / s)) * s);
  }
}

// ---------------- bf16 MFMA GEMM, templated epilogue ----------------
template <int OMODE, bool SCALED>
__global__ __launch_bounds__(256) void mfma_gemm_kernel(const unsigned short* __restrict__ A,
                                                        const unsigned short* __restrict__ B,
                                                        const float* __restrict__ Bsc,
                                                        float* __restrict__ C,
                                                        unsigned short* __restrict__ O1,
                                                        unsigned short* __restrict__ O2,
                                                        unsigned short* __restrict__ O3,
                                                        unsigned short* __restrict__ O4,
                                                        int N, int K, int ldc) {
  __shared__ unsigned short lA[128 * 64];
  __shared__ unsigned short lB[128 * 64];
  const int tid = threadIdx.x;
  const int wave = tid >> 6, lane = tid & 63;
  const int wr = (wave >> 1) * 64, wc = (wave & 1) * 64;
  const int m0 = blockIdx.y * 128, n0 = blockIdx.x * 128;
  const int KB = K >> 7;
  const int frow = lane & 15, fk = (lane >> 4) * 8;

  f32x4 mainAcc[4][4];
  f32x4 part[4][4];
  const f32x4 vzero = {0.f, 0.f, 0.f, 0.f};
#pragma unroll
  for (int i = 0; i < 4; ++i)
#pragma unroll
    for (int j = 0; j < 4; ++j) { mainAcc[i][j] = vzero; part[i][j] = vzero; }

  const int nkt = K >> 6;
  for (int kt = 0; kt < nkt; ++kt) {
    const int k0 = kt << 6;
    __syncthreads();
#pragma unroll
    for (int it = 0; it < 4; ++it) {
      int o = it * 4096 + wave * 1024 + lane * 16;
      int row = o >> 7;
      int kb = o & 127;
      const char* ga = (const char*)(A + (size_t)(m0 + row) * K + k0) + kb;
      const char* gb = (const char*)(B + (size_t)(n0 + row) * K + k0) + kb;
      __builtin_amdgcn_global_load_lds((gvoid*)ga, (lvoid*)((char*)lA + o), 16, 0, 0);
      __builtin_amdgcn_global_load_lds((gvoid*)gb, (lvoid*)((char*)lB + o), 16, 0, 0);
    }
    __syncthreads();
#pragma unroll
    for (int ks = 0; ks < 2; ++ks) {
      bf16x8 af[4], bfr[4];
#pragma unroll
      for (int i = 0; i < 4; ++i)
        af[i] = *(const bf16x8*)&lA[(wr + i * 16 + frow) * 64 + ks * 32 + fk];
#pragma unroll
      for (int j = 0; j < 4; ++j)
        bfr[j] = *(const bf16x8*)&lB[(wc + j * 16 + frow) * 64 + ks * 32 + fk];
#pragma unroll
      for (int i = 0; i < 4; ++i)
#pragma unroll
        for (int j = 0; j < 4; ++j)
          part[i][j] = __builtin_amdgcn_mfma_f32_16x16x32_bf16(af[i], bfr[j], part[i][j], 0, 0, 0);
    }
    if (SCALED) {
      float bs = Bsc[(size_t)(n0 >> 7) * KB + (k0 >> 7)];
#pragma unroll
      for (int i = 0; i < 4; ++i)
#pragma unroll
        for (int j = 0; j < 4; ++j) {
          mainAcc[i][j] += part[i][j] * bs;
          part[i][j] = vzero;
        }
    }
  }
  const int crow0 = (lane >> 4) * 4;
  const int ccol = lane & 15;
#pragma unroll
  for (int i = 0; i < 4; ++i) {
#pragma unroll
    for (int j = 0; j < 4; ++j) {
      f32x4 v = SCALED ? mainAcc[i][j] : part[i][j];
      int col = n0 + wc + j * 16 + ccol;
      if (col < N) {
#pragma unroll
        for (int r = 0; r < 4; ++r) {
          int m = m0 + wr + i * 16 + crow0 + r;
          float val = v[r];
          if (OMODE == 0) {
            C[(size_t)m * ldc + col] = val;
          } else if (OMODE == 1) {
            int hh = col / 192, d = col - hh * 192;
            int bb = m >> 11, s = m & 2047;
            size_t off = ((size_t)((bb * 16 + hh) * 2048 + s)) * 192 + d;
            unsigned short hi = f32_to_bf16(val);
            O1[off] = hi;
            O2[off] = f32_to_bf16(val - bf16_to_f32(hi));
          } else {
            int hh = col >> 8, d = col & 255;
            int bb = m >> 11, s = m & 2047;
            if (d < 128) {
              size_t off = ((size_t)((bb * 16 + hh) * 2048 + s)) * 128 + d;
              unsigned short hi = f32_to_bf16(val);
              O1[off] = hi;
              O2[off] = f32_to_bf16(val - bf16_to_f32(hi));
            } else {
              size_t off = ((size_t)((bb * 16 + hh) * 128 + (d - 128))) * 2048 + s;
              unsigned short hi = f32_to_bf16(val);
              O3[off] = hi;
              O4[off] = f32_to_bf16(val - bf16_to_f32(hi));
            }
          }
        }
      }
    }
  }
}

// ---------------- 3-product split GEMM -> bf16 hi/lo output [4096][1152] ----------------
__global__ __launch_bounds__(256) void mfma_gemm3_kernel(const unsigned short* __restrict__ Ah,
                                                         const unsigned short* __restrict__ Al,
                                                         const unsigned short* __restrict__ Bh,
                                                         const unsigned short* __restrict__ Bl,
                                                         unsigned short* __restrict__ OH,
                                                         unsigned short* __restrict__ OL,
                                                         int K, int ldc) {
  if (blockIdx.x < 8 && !(blockIdx.y & 8)) return;   // qi rows q<1024 never used
  __shared__ unsigned short lAh[128 * 64], lAl[128 * 64];
  __shared__ unsigned short lBh[128 * 64], lBl[128 * 64];
  const int tid = threadIdx.x;
  const int wave = tid >> 6, lane = tid & 63;
  const int wr = (wave >> 1) * 64, wc = (wave & 1) * 64;
  const int m0 = blockIdx.y * 128, n0 = blockIdx.x * 128;
  const int frow = lane & 15, fk = (lane >> 4) * 8;

  f32x4 part[4][4];
  const f32x4 vzero = {0.f, 0.f, 0.f, 0.f};
#pragma unroll
  for (int i = 0; i < 4; ++i)
#pragma unroll
    for (int j = 0; j < 4; ++j) part[i][j] = vzero;

  const int nkt = K >> 6;
  for (int kt = 0; kt < nkt; ++kt) {
    const int k0 = kt << 6;
    __syncthreads();
#pragma unroll
    for (int it = 0; it < 4; ++it) {
      int o = it * 4096 + wave * 1024 + lane * 16;
      int row = o >> 7;
      int kb = o & 127;
      size_t ga = (size_t)(m0 + row) * K + k0;
      size_t gb = (size_t)(n0 + row) * K + k0;
      __builtin_amdgcn_global_load_lds((gvoid*)((const char*)(Ah + ga) + kb), (lvoid*)((char*)lAh + o), 16, 0, 0);
      __builtin_amdgcn_global_load_lds((gvoid*)((const char*)(Al + ga) + kb), (lvoid*)((char*)lAl + o), 16, 0, 0);
      __builtin_amdgcn_global_load_lds((gvoid*)((const char*)(Bh + gb) + kb), (lvoid*)((char*)lBh + o), 16, 0, 0);
      __builtin_amdgcn_global_load_lds((gvoid*)((const char*)(Bl + gb) + kb), (lvoid*)((char*)lBl + o), 16, 0, 0);
    }
    __syncthreads();
#pragma unroll
    for (int ks = 0; ks < 2; ++ks) {
      bf16x8 ah[4], al[4], bh[4], bl[4];
#pragma unroll
      for (int i = 0; i < 4; ++i) {
        ah[i] = *(const bf16x8*)&lAh[(wr + i * 16 + frow) * 64 + ks * 32 + fk];
        al[i] = *(const bf16x8*)&lAl[(wr + i * 16 + frow) * 64 + ks * 32 + fk];
      }
#pragma unroll
      for (int j = 0; j < 4; ++j) {
        bh[j] = *(const bf16x8*)&lBh[(wc + j * 16 + frow) * 64 + ks * 32 + fk];
        bl[j] = *(const bf16x8*)&lBl[(wc + j * 16 + frow) * 64 + ks * 32 + fk];
      }
#pragma unroll
      for (int i = 0; i < 4; ++i)
#pragma unroll
        for (int j = 0; j < 4; ++j) {
          part[i][j] = __builtin_amdgcn_mfma_f32_16x16x32_bf16(ah[i], bh[j], part[i][j], 0, 0, 0);
          part[i][j] = __builtin_amdgcn_mfma_f32_16x16x32_bf16(ah[i], bl[j], part[i][j], 0, 0, 0);
          part[i][j] = __builtin_amdgcn_mfma_f32_16x16x32_bf16(al[i], bh[j], part[i][j], 0, 0, 0);
        }
    }
  }
  const int crow0 = (lane >> 4) * 4;
  const int ccol = lane & 15;
#pragma unroll
  for (int i = 0; i < 4; ++i)
#pragma unroll
    for (int j = 0; j < 4; ++j) {
      int col = n0 + wc + j * 16 + ccol;
#pragma unroll
      for (int r = 0; r < 4; ++r) {
        float val = part[i][j][r];
        size_t off = (size_t)(m0 + wr + i * 16 + crow0 + r) * ldc + col;
        unsigned short hi = f32_to_bf16(val);
        OH[off] = hi;
        OL[off] = f32_to_bf16(val - bf16_to_f32(hi));
      }
    }
}

// ---------------- f32 GEMM (tiny Wig only); rowskip: skip tiles with (y & rowskip)==0 ----------------
__global__ __launch_bounds__(256) void gemm_f32_kernel(const float* __restrict__ A,
                                                       const float* __restrict__ Bw,
                                                       float* __restrict__ C,
                                                       int N, int K, float alpha, int rowskip) {
  if (rowskip && !(blockIdx.y & rowskip)) return;
  __shared__ __align__(16) float As[16][68];
  __shared__ __align__(16) float Bs[16][68];
  int n0 = blockIdx.x * 64;
  int m0 = blockIdx.y * 64;
  int tid = threadIdx.x;
  int tx = tid & 15, ty = tid >> 4;
  float acc[4][4] = {};
  for (int k0 = 0; k0 < K; k0 += 16) {
#pragma unroll
    for (int t = 0; t < 4; ++t) {
      int idx = tid + t * 256;
      int rr = idx >> 4;
      int kk = idx & 15;
      As[kk][rr] = A[(size_t)(m0 + rr) * K + (k0 + kk)];
      Bs[kk][rr] = (n0 + rr < N) ? Bw[(size_t)(n0 + rr) * K + (k0 + kk)] : 0.0f;
    }
    __syncthreads();
#pragma unroll
    for (int kk = 0; kk < 16; ++kk) {
      float4 a = *(const float4*)&As[kk][ty * 4];
      float4 b = *(const float4*)&Bs[kk][tx * 4];
      float av[4] = {a.x, a.y, a.z, a.w};
      float bv[4] = {b.x, b.y, b.z, b.w};
#pragma unroll
      for (int i = 0; i < 4; ++i)
#pragma unroll
        for (int j = 0; j < 4; ++j) acc[i][j] += av[i] * bv[j];
    }
    __syncthreads();
  }
#pragma unroll
  for (int i = 0; i < 4; ++i) {
    int m = m0 + ty * 4 + i;
#pragma unroll
    for (int j = 0; j < 4; ++j) {
      int n = n0 + tx * 4 + j;
      if (n < N) C[(size_t)m * N + n] = alpha * acc[i][j];
    }
  }
}

// ---------------- RoPE on split Q (in place, [b,h,s,192]) + k_rope -> Krh/Krl ----------------
__global__ __launch_bounds__(64) void rope_split_kernel(unsigned short* __restrict__ Qh,
                                                        unsigned short* __restrict__ Ql,
                                                        const float* __restrict__ KVA,
                                                        unsigned short* __restrict__ Krh,
                                                        unsigned short* __restrict__ Krl,
                                                        const int* __restrict__ POS) {
  int t = blockIdx.x;  // b*S + s
  int tid = threadIdx.x;
  int b = t >> 11, s = t & 2047;
  __shared__ float cs[32], sn[32];
  if (tid < 32) {
    int pos = POS[t];
    double inv = pow(10000.0, -((double)(2 * tid) / 64.0));
    float ang = (float)pos * (float)inv;
    cs[tid] = cosf(ang);
    sn[tid] = sinf(ang);
  }
  __syncthreads();
  if (tid < 32) {
    const float* kr = KVA + (size_t)t * (kKvLora + kDR) + kKvLora;
    float x1 = kr[tid], x2 = kr[32 + tid];
    float y1 = x1 * cs[tid] - x2 * sn[tid];
    float y2 = x2 * cs[tid] + x1 * sn[tid];
    unsigned short h1 = f32_to_bf16(y1);
    Krh[(size_t)t * 64 + tid] = h1;
    Krl[(size_t)t * 64 + tid] = f32_to_bf16(y1 - bf16_to_f32(h1));
    unsigned short h2 = f32_to_bf16(y2);
    Krh[(size_t)t * 64 + 32 + tid] = h2;
    Krl[(size_t)t * 64 + 32 + tid] = f32_to_bf16(y2 - bf16_to_f32(h2));
  }
  for (int it = tid; it < kH * 32; it += 64) {
    int h = it >> 5, i = it & 31;
    size_t base = ((size_t)((b * 16 + h) * 2048 + s)) * 192 + 128;
    float x1 = bf16_to_f32(Qh[base + i]) + bf16_to_f32(Ql[base + i]);
    float x2 = bf16_to_f32(Qh[base + 32 + i]) + bf16_to_f32(Ql[base + 32 + i]);
    float y1 = x1 * cs[i] - x2 * sn[i];
    float y2 = x2 * cs[i] + x1 * sn[i];
    unsigned short h1 = f32_to_bf16(y1);
    Qh[base + i] = h1;
    Ql[base + i] = f32_to_bf16(y1 - bf16_to_f32(h1));
    unsigned short h2 = f32_to_bf16(y2);
    Qh[base + 32 + i] = h2;
    Ql[base + 32 + i] = f32_to_bf16(y2 - bf16_to_f32(h2));
  }
}

// ---------------- MFMA indexer scores: one 64x64 tile per block (rows q>=1024 only) ----------------
__global__ __launch_bounds__(256) void isc_mfma_kernel(const unsigned short* __restrict__ QIKH,
                                                       const unsigned short* __restrict__ QIKL,
                                                       const float* __restrict__ WGT,
                                                       float* __restrict__ ISC) {
  const int qt = blockIdx.y + 16;
  const int kt = blockIdx.x;
  if (kt > qt) return;
  const int b = blockIdx.z;
  const int q0 = qt * 64, k0 = kt * 64;
  const int tid = threadIdx.x, wave = tid >> 6, lane = tid & 63;
  const int fr = lane & 15, fg = lane >> 4;

  __shared__ unsigned short KiH[4 * 64 * 40], KiL[4 * 64 * 40];
  __shared__ float wgs[64 * 8];

  {
    int key = tid >> 2, sub = (tid & 3) * 8;
    size_t rb = (size_t)(b * kS + k0 + key) * 1152 + 1024;
#pragma unroll
    for (int kc = 0; kc < 4; ++kc) {
      *(bf16x8*)&KiH[kc * 2560 + key * 40 + sub] = *(const bf16x8*)&QIKH[rb + kc * 32 + sub];
      *(bf16x8*)&KiL[kc * 2560 + key * 40 + sub] = *(const bf16x8*)&QIKL[rb + kc * 32 + sub];
    }
#pragma unroll
    for (int t = 0; t < 2; ++t) {
      int i = t * 256 + tid;
      wgs[i] = WGT[(size_t)(b * kS + q0 + (i >> 3)) * kHI + (i & 7)];
    }
  }
  const size_t qrow = (size_t)(b * kS + q0 + wave * 16 + fr) * 1152;
  f32x4 sacc[4];
  const f32x4 vzero = {0.f, 0.f, 0.f, 0.f};
#pragma unroll
  for (int j = 0; j < 4; ++j) sacc[j] = vzero;

  bf16x8 qAh[4], qAl[4], qBh[4], qBl[4];
#define LOADQ(DH_, DL_, H_)                                                     \
  _Pragma("unroll") for (int kc = 0; kc < 4; ++kc) {                            \
    DH_[kc] = *(const bf16x8*)&QIKH[qrow + (H_)*128 + kc * 32 + fg * 8];        \
    DL_[kc] = *(const bf16x8*)&QIKL[qrow + (H_)*128 + kc * 32 + fg * 8];        \
  }
  LOADQ(qAh, qAl, 0)
  __syncthreads();
#define MFMA_HEAD(QH_, QL_, H_)                                                 \
  {                                                                             \
    f32x4 acc[4];                                                               \
    _Pragma("unroll") for (int j = 0; j < 4; ++j) acc[j] = vzero;               \
    _Pragma("unroll") for (int kc = 0; kc < 4; ++kc) {                          \
      _Pragma("unroll") for (int j = 0; j < 4; ++j) {                           \
        bf16x8 kh = *(const bf16x8*)&KiH[kc * 2560 + (j * 16 + fr) * 40 + fg * 8]; \
        bf16x8 kl = *(const bf16x8*)&KiL[kc * 2560 + (j * 16 + fr) * 40 + fg * 8]; \
        acc[j] = __builtin_amdgcn_mfma_f32_16x16x32_bf16(QH_[kc], kh, acc[j], 0, 0, 0); \
        acc[j] = __builtin_amdgcn_mfma_f32_16x16x32_bf16(QH_[kc], kl, acc[j], 0, 0, 0); \
        acc[j] = __builtin_amdgcn_mfma_f32_16x16x32_bf16(QL_[kc], kh, acc[j], 0, 0, 0); \
      }                                                                         \
    }                                                                           \
    float wv[4];                                                                \
    _Pragma("unroll") for (int r = 0; r < 4; ++r)                               \
        wv[r] = wgs[(wave * 16 + fg * 4 + r) * 8 + (H_)];                       \
    _Pragma("unroll") for (int j = 0; j < 4; ++j)                               \
      _Pragma("unroll") for (int r = 0; r < 4; ++r)                             \
        sacc[j][r] += fmaxf(acc[j][r], 0.0f) * wv[r];                           \
  }
#pragma unroll
  for (int hp = 0; hp < 4; ++hp) {
    int h0 = hp * 2;
    LOADQ(qBh, qBl, h0 + 1)
    MFMA_HEAD(qAh, qAl, h0)
    if (hp < 3) LOADQ(qAh, qAl, h0 + 2)
    MFMA_HEAD(qBh, qBl, h0 + 1)
  }
#undef LOADQ
#undef MFMA_HEAD
#pragma unroll
  for (int r = 0; r < 4; ++r) {
    size_t ob = (size_t)(b * kS + q0 + wave * 16 + fg * 4 + r) * kS + k0;
#pragma unroll
    for (int j = 0; j < 4; ++j) ISC[ob + j * 16 + fr] = sacc[j][r];
  }
}

// ---------------- exact stable top-k from precomputed scores ----------------
__global__ __launch_bounds__(256) void topk_kernel(const float* __restrict__ ISC,
                                                   unsigned* __restrict__ SEL) {
  int row = blockIdx.x;
  int q = row & (kS - 1);
  int L = q + 1;
  unsigned* selrow = SEL + (size_t)row * (kS / 32);
  int tid = threadIdx.x;
  if (L <= kTopK) {
    if (tid < kS / 32) {
      int base = tid * 32;
      unsigned w;
      if (base + 32 <= L) w = 0xFFFFFFFFu;
      else if (base >= L) w = 0u;
      else w = (1u << (L - base)) - 1u;
      selrow[tid] = w;
    }
    return;
  }
  __shared__ unsigned keys[kS];
  __shared__ unsigned hist[256];
  __shared__ unsigned msk[kS / 32];
  __shared__ unsigned pick[2];
  if (tid < kS / 32) msk[tid] = 0u;
  const float* x = ISC + (size_t)row * kS;
  for (int k = tid; k < L; k += 256) {
    unsigned u = __float_as_uint(x[k]);
    keys[k] = (u & 0x80000000u) ? ~u : (u | 0x80000000u);
  }
  __syncthreads();
  unsigned prefix = 0u;
  int r = kTopK;
  for (int shift = 24; shift >= 0; shift -= 8) {
    hist[tid] = 0u;
    __syncthreads();
    unsigned hm = (shift == 24) ? 0u : (0xFFFFFFFFu << (shift + 8));
    for (int k = tid; k < L; k += 256) {
      unsigned key = keys[k];
      if ((key & hm) == (prefix & hm)) atomicAdd(&hist[(key >> shift) & 255u], 1u);
    }
    __syncthreads();
    if (tid == 0) {
      int rr = r, bsel = 0;
      for (int bb = 255; bb >= 0; --bb) {
        int c = (int)hist[bb];
        if (rr <= c) { bsel = bb; break; }
        rr -= c;
      }
      pick[0] = (unsigned)bsel;
      pick[1] = (unsigned)rr;
    }
    __syncthreads();
    prefix |= pick[0] << shift;
    r = (int)pick[1];
    __syncthreads();
  }
  unsigned T = prefix;
  int ties_take = r;
  int base = tid * 8;
  int cnt = 0;
#pragma unroll
  for (int j = 0; j < 8; ++j) {
    int k = base + j;
    if (k < L && keys[k] == T) ++cnt;
  }
  hist[tid] = (unsigned)cnt;
  __syncthreads();
  if (tid == 0) {
    unsigned run = 0;
    for (int t = 0; t < 256; ++t) { unsigned c = hist[t]; hist[t] = run; run += c; }
  }
  __syncthreads();
  int trank = (int)hist[tid];
  unsigned bits = 0u;
#pragma unroll
  for (int j = 0; j < 8; ++j) {
    int k = base + j;
    if (k < L) {
      unsigned key = keys[k];
      bool s;
      if (key > T) s = true;
      else if (key == T) { s = trank < ties_take; ++trank; }
      else s = false;
      if (s) bits |= (1u << j);
    }
  }
  atomicOr(&msk[tid >> 2], bits << ((tid & 3) * 8));
  __syncthreads();
  if (tid < kS / 32) selrow[tid] = msk[tid];
}

// ---------------- MFMA flash attention (measured-best round-10 structure, restored exactly) ----------------
// grid.x = flattened (qt,h), global longest-first: qt = 31 - (x>>4), h = x&15; b = grid.y.
// QK^T: 3-pass hi/lo; K chunks LDS double-buffered (1 barrier/chunk) with reg prefetch.
// PV: (Ph+Pl)*Vh then Ph*Vl; V prefetched into regs early. Pads 40/72 (16B-aligned rows).
__global__ __launch_bounds__(256) void attn_mfma_kernel(const unsigned short* __restrict__ Qh,
                                                        const unsigned short* __restrict__ Ql,
                                                        const unsigned short* __restrict__ Knh,
                                                        const unsigned short* __restrict__ Knl,
                                                        const unsigned short* __restrict__ Krh,
                                                        const unsigned short* __restrict__ Krl,
                                                        const unsigned short* __restrict__ Vth,
                                                        const unsigned short* __restrict__ Vtl,
                                                        const unsigned* __restrict__ SEL,
                                                        unsigned short* __restrict__ CTXB) {
  const int flat = blockIdx.x;
  const int qt = 31 - (flat >> 4);        // longest blocks dispatch first
  const int h = flat & 15;
  const int b = blockIdx.y;
  const int q0 = qt * 64;
  const int tid = threadIdx.x, wave = tid >> 6, lane = tid & 63;
  const int fr = lane & 15, fg = lane >> 4;
  const float scale = 0.07216878364870323f;  // 1/sqrt(192)

  __shared__ unsigned short KsH[2 * 64 * 40], KsL[2 * 64 * 40];  // double-buffered K chunk
  __shared__ unsigned short Ph[64 * 72], Pl[64 * 72];
  __shared__ unsigned short Vs[128 * 72];
  __shared__ unsigned selw[64][2];

  bf16x8 qh[6], ql[6];
  {
    const size_t qbase = ((size_t)((b * 16 + h) * 2048 + q0 + wave * 16 + fr)) * 192;
#pragma unroll
    for (int kc = 0; kc < 6; ++kc) {
      qh[kc] = *(const bf16x8*)&Qh[qbase + kc * 32 + fg * 8];
      ql[kc] = *(const bf16x8*)&Ql[qbase + kc * 32 + fg * 8];
    }
  }
  float m_run[4], l_run[4];
#pragma unroll
  for (int r = 0; r < 4; ++r) { m_run[r] = kNeg; l_run[r] = 0.0f; }
  f32x4 O[8];
  const f32x4 vzero = {0.f, 0.f, 0.f, 0.f};
#pragma unroll
  for (int j = 0; j < 8; ++j) O[j] = vzero;

  const int key = tid >> 2, sub = (tid & 3) * 8;
  const size_t knbase = (size_t)((b * 16 + h) * 2048) * 128;
  const size_t krbase = (size_t)(b * 2048) * 64;
  const size_t vbase0 = ((size_t)((b * 16 + h) * 128)) * 2048;

  const int nkt = qt + 1;
  for (int kt = 0; kt < nkt; ++kt) {
    const int k0 = kt * 64;
    const size_t vbase = vbase0 + k0;
    unsigned selreg = 0;
    if (tid < 128)
      selreg = SEL[(size_t)(b * kS + q0 + (tid >> 1)) * (kS / 32) + (k0 >> 5) + (tid & 1)];
    bf16x8 kh_pre[2], kl_pre[2];
    {
      size_t src = knbase + (size_t)(k0 + key) * 128 + sub;   // chunk 0
      kh_pre[0] = *(const bf16x8*)&Knh[src];
      kl_pre[0] = *(const bf16x8*)&Knl[src];
    }
    bf16x8 vpre[4];
#pragma unroll
    for (int it = 0; it < 4; ++it) {
      int idx = it * 256 + tid;
      int dv = idx >> 3, ks8 = (idx & 7) * 8;
      vpre[it] = *(const bf16x8*)&Vth[vbase + (size_t)dv * 2048 + ks8];
    }
    __syncthreads();  // B1: prev tile's Ks(last chunk)/Vs/selw reads done
    if (tid < 128) selw[tid >> 1][tid & 1] = selreg;
    f32x4 acc[4];
#pragma unroll
    for (int j = 0; j < 4; ++j) acc[j] = vzero;
#pragma unroll
    for (int kc = 0; kc < 6; ++kc) {
      const int buf = (kc & 1) * 2560;
      *(bf16x8*)&KsH[buf + key * 40 + sub] = kh_pre[kc & 1];
      *(bf16x8*)&KsL[buf + key * 40 + sub] = kl_pre[kc & 1];
      if (kc < 5) {   // prefetch next chunk (hidden under barrier+MFMA)
        if (kc + 1 < 4) {
          size_t src = knbase + (size_t)(k0 + key) * 128 + (kc + 1) * 32 + sub;
          kh_pre[(kc + 1) & 1] = *(const bf16x8*)&Knh[src];
          kl_pre[(kc + 1) & 1] = *(const bf16x8*)&Knl[src];
        } else {
          size_t src = krbase + (size_t)(k0 + key) * 64 + (kc - 3) * 32 + sub;
          kh_pre[(kc + 1) & 1] = *(const bf16x8*)&Krh[src];
          kl_pre[(kc + 1) & 1] = *(const bf16x8*)&Krl[src];
        }
      }
      __syncthreads();  // single barrier per chunk (double-buffered Ks)
#pragma unroll
      for (int j = 0; j < 4; ++j) {
        bf16x8 kh = *(const bf16x8*)&KsH[buf + (j * 16 + fr) * 40 + fg * 8];
        bf16x8 kl = *(const bf16x8*)&KsL[buf + (j * 16 + fr) * 40 + fg * 8];
        acc[j] = __builtin_amdgcn_mfma_f32_16x16x32_bf16(qh[kc], kh, acc[j], 0, 0, 0);
        acc[j] = __builtin_amdgcn_mfma_f32_16x16x32_bf16(qh[kc], kl, acc[j], 0, 0, 0);
        acc[j] = __builtin_amdgcn_mfma_f32_16x16x32_bf16(ql[kc], kh, acc[j], 0, 0, 0);
      }
    }
    float p[4][4];
    float fsc[4];
#pragma unroll
    for (int r = 0; r < 4; ++r) {
      int row = wave * 16 + fg * 4 + r;
      float sv[4];
      float vmax = kNeg;
#pragma unroll
      for (int j = 0; j < 4; ++j) {
        int col = j * 16 + fr;
        bool bit = (selw[row][col >> 5] >> (col & 31)) & 1u;
        float s = bit ? acc[j][r] * scale : kNeg;
        sv[j] = s;
        vmax = fmaxf(vmax, s);
      }
#pragma unroll
      for (int m = 1; m <= 8; m <<= 1) vmax = fmaxf(vmax, __shfl_xor(vmax, m, 64));
      float newm = fmaxf(m_run[r], vmax);
      float sum = 0.0f;
#pragma unroll
      for (int j = 0; j < 4; ++j) {
        float pp = (sv[j] < -1e29f) ? 0.0f : expf(sv[j] - newm);
        p[j][r] = pp;
        sum += pp;
      }
#pragma unroll
      for (int m = 1; m <= 8; m <<= 1) sum += __shfl_xor(sum, m, 64);
      fsc[r] = expf(m_run[r] - newm);
      l_run[r] = l_run[r] * fsc[r] + sum;
      m_run[r] = newm;
    }
#pragma unroll
    for (int j = 0; j < 8; ++j)
#pragma unroll
      for (int r = 0; r < 4; ++r) O[j][r] *= fsc[r];
#pragma unroll
    for (int r = 0; r < 4; ++r) {
      int row = wave * 16 + fg * 4 + r;
#pragma unroll
      for (int j = 0; j < 4; ++j) {
        int col = j * 16 + fr;
        float pp = p[j][r];
        unsigned short hi = f32_to_bf16(pp);
        Ph[row * 72 + col] = hi;
        Pl[row * 72 + col] = f32_to_bf16(pp - bf16_to_f32(hi));
      }
    }
#pragma unroll
    for (int it = 0; it < 4; ++it) {
      int idx = it * 256 + tid;
      int dv = idx >> 3, ks8 = (idx & 7) * 8;
      *(bf16x8*)&Vs[dv * 72 + ks8] = vpre[it];
    }
#pragma unroll
    for (int it = 0; it < 4; ++it) {
      int idx = it * 256 + tid;
      int dv = idx >> 3, ks8 = (idx & 7) * 8;
      vpre[it] = *(const bf16x8*)&Vtl[vbase + (size_t)dv * 2048 + ks8];
    }
    __syncthreads();  // B3: Vs (hi) ready
#pragma unroll
    for (int kk = 0; kk < 2; ++kk) {
      bf16x8 pah = *(const bf16x8*)&Ph[(wave * 16 + fr) * 72 + kk * 32 + fg * 8];
      bf16x8 pal = *(const bf16x8*)&Pl[(wave * 16 + fr) * 72 + kk * 32 + fg * 8];
#pragma unroll
      for (int j = 0; j < 8; ++j) {
        bf16x8 vb = *(const bf16x8*)&Vs[(j * 16 + fr) * 72 + kk * 32 + fg * 8];
        O[j] = __builtin_amdgcn_mfma_f32_16x16x32_bf16(pah, vb, O[j], 0, 0, 0);
        O[j] = __builtin_amdgcn_mfma_f32_16x16x32_bf16(pal, vb, O[j], 0, 0, 0);
      }
    }
    __syncthreads();  // B4: PV1 Vs reads done
#pragma unroll
    for (int it = 0; it < 4; ++it) {
      int idx = it * 256 + tid;
      int dv = idx >> 3, ks8 = (idx & 7) * 8;
      *(bf16x8*)&Vs[dv * 72 + ks8] = vpre[it];
    }
    __syncthreads();  // B5: Vs (lo) ready
#pragma unroll
    for (int kk = 0; kk < 2; ++kk) {
      bf16x8 pah = *(const bf16x8*)&Ph[(wave * 16 + fr) * 72 + kk * 32 + fg * 8];
#pragma unroll
      for (int j = 0; j < 8; ++j) {
        bf16x8 vb = *(const bf16x8*)&Vs[(j * 16 + fr) * 72 + kk * 32 + fg * 8];
        O[j] = __builtin_amdgcn_mfma_f32_16x16x32_bf16(pah, vb, O[j], 0, 0, 0);
      }
    }
  }
#pragma unroll
  for (int r = 0; r < 4; ++r) {
    float inv = 1.0f / l_run[r];
    float vals[8];
    float am = 0.0f;
#pragma unroll
    for (int j = 0; j < 8; ++j) {
      vals[j] = O[j][r] * inv;
      am = fmaxf(am, fabsf(vals[j]));
    }
#pragma unroll
    for (int m = 1; m <= 8; m <<= 1) am = fmaxf(am, __shfl_xor(am, m, 64));
    am = fmaxf(am, 1e-4f);
    float s = act_scale_from_amax(am);
    size_t obase = (size_t)(b * kS + q0 + wave * 16 + fg * 4 + r) * 2048 + h * 128;
#pragma unroll
    for (int j = 0; j < 8; ++j)
      CTXB[obase + j * 16 + fr] = f32_to_bf16(fp8_e4m3_qdq(clamp448(vals[j] / s)) * s);
  }
}

extern "C" void kernel_launch(void* const* d_in, const int* in_sizes, int n_in,
                              void* d_out, int out_size, void* d_ws, size_t ws_size,
                              hipStream_t stream) {
  (void)in_sizes; (void)n_in;

  const float* hidden = (const float*)d_in[0];
  const float* Wqa    = (const float*)d_in[1];
  const float* qnw    = (const float*)d_in[2];
  const float* Wqb    = (const float*)d_in[3];
  const float* Wkva   = (const float*)d_in[4];
  const float* kvnw   = (const float*)d_in[5];
  const float* Wkvb   = (const float*)d_in[6];
  const float* Wiq    = (const float*)d_in[7];
  const float* Wik    = (const float*)d_in[8];
  const float* Wig    = (const float*)d_in[9];
  const float* Wo     = (const float*)d_in[10];
  const int*   pos    = (const int*)d_in[11];
  char* ws = (char*)d_ws;
  float* out = (float*)d_out;

  if (ws_size < WS_NEED) {
    fill_kernel<<<dim3((out_size + 255) / 256), dim3(256), 0, stream>>>(out, out_size, 54321.0f);
    return;
  }

  float* scWqa  = (float*)(ws + OFF_SC) + 0;
  float* scWqb  = (float*)(ws + OFF_SC) + 128;
  float* scWkva = (float*)(ws + OFF_SC) + 320;
  float* scWkvb = (float*)(ws + OFF_SC) + 400;
  float* scWo   = (float*)(ws + OFF_SC) + 528;
  unsigned* sel = (unsigned*)(ws + OFF_SEL_B);
  float* wgt    = (float*)(ws + OFF_WGT_B);
  unsigned short* krh = (unsigned short*)(ws + OFF_KRH_B);
  unsigned short* krl = (unsigned short*)(ws + OFF_KRL_B);
  unsigned short* wo_b = (unsigned short*)(ws + OFF_WOB_B);

  unsigned short* h_hi  = (unsigned short*)(ws + A_HHI);
  unsigned short* h_lo  = (unsigned short*)(ws + A_HLO);
  unsigned short* wqk_h = (unsigned short*)(ws + A_WQKH);
  unsigned short* wqk_l = (unsigned short*)(ws + A_WQKL);
  unsigned short* qik_h = (unsigned short*)(ws + A_QIKH);
  unsigned short* qik_l = (unsigned short*)(ws + A_QIKL);
  float* isc = (float*)(ws + A_ISC);

  unsigned short* hidq_b = (unsigned short*)(ws + B_HIDQ);
  unsigned short* wqa_b  = (unsigned short*)(ws + B_WQA);
  unsigned short* wqb_b  = (unsigned short*)(ws + B_WQB);
  unsigned short* wkva_b = (unsigned short*)(ws + B_WKVA);
  unsigned short* wkvb_b = (unsigned short*)(ws + B_WKVB);
  float* qa_f   = (float*)(ws + B_QAF);
  unsigned short* qa_b  = (unsigned short*)(ws + B_QAB);
  float* kva    = (float*)(ws + B_KVA);
  unsigned short* ckv_b = (unsigned short*)(ws + B_CKV);
  unsigned short* q_h   = (unsigned short*)(ws + B_QH);
  unsigned short* q_l   = (unsigned short*)(ws + B_QL);
  unsigned short* kn_h  = (unsigned short*)(ws + B_KNH);
  unsigned short* kn_l  = (unsigned short*)(ws + B_KNL);
  unsigned short* v_th  = (unsigned short*)(ws + B_VTH);
  unsigned short* v_tl  = (unsigned short*)(ws + B_VTL);
  unsigned short* ctx_b = (unsigned short*)(ws + B_CTXB);

  // ---------- Phase A: indexer + top-k ----------
  hidden_prep_kernel<<<dim3(16384), dim3(256), 0, stream>>>(hidden, h_hi, h_lo, hidq_b);
  split_bf16x2_kernel<<<dim3(8192),  dim3(256), 0, stream>>>(Wiq, wqk_h, wqk_l, (size_t)kHI * kDI * kDH);
  split_bf16x2_kernel<<<dim3(1024),  dim3(256), 0, stream>>>(Wik, wqk_h + (size_t)1024 * kDH, wqk_l + (size_t)1024 * kDH, (size_t)kDI * kDH);
  gemm_f32_kernel<<<dim3(1, 64), dim3(256), 0, stream>>>(hidden, Wig, wgt, kHI, kDH, 0.35355339059327373f, 16);
  mfma_gemm3_kernel<<<dim3(9, 32), dim3(256), 0, stream>>>(h_hi, h_lo, wqk_h, wqk_l, qik_h, qik_l, kDH, 1152);
  isc_mfma_kernel<<<dim3(32, 16, kB), dim3(256), 0, stream>>>(qik_h, qik_l, wgt, isc);
  topk_kernel<<<dim3(kNTok), dim3(256), 0, stream>>>(isc, sel);

  // ---------- Phase B: fp8-path linears on MFMA ----------
  fused_weight_kernel<<<dim3(16, 8),  dim3(256), 0, stream>>>(Wqa,  scWqa,  wqa_b,  kQLora, kDH);
  fused_weight_kernel<<<dim3(8, 24),  dim3(256), 0, stream>>>(Wqb,  scWqb,  wqb_b,  kH * (kDN + kDR), kQLora);
  fused_weight_kernel<<<dim3(16, 5),  dim3(256), 0, stream>>>(Wkva, scWkva, wkva_b, kKvLora + kDR, kDH);
  fused_weight_kernel<<<dim3(4, 32),  dim3(256), 0, stream>>>(Wkvb, scWkvb, wkvb_b, kH * (kDN + kDV), kKvLora);
  fused_weight_kernel<<<dim3(16, 16), dim3(256), 0, stream>>>(Wo,   scWo,   wo_b,   kDH, kH * kDV);

  // q_a -> rms -> q (bf16 hi/lo, [b,h,s,192])
  mfma_gemm_kernel<0, true><<<dim3(8, 32), dim3(256), 0, stream>>>(hidq_b, wqa_b, scWqa, qa_f, nullptr, nullptr, nullptr, nullptr, 1024, kDH, 1024);
  rms_qdq_kernel<<<dim3(kNTok), dim3(256), 0, stream>>>(qa_f, qnw, qa_b, kQLora, kQLora, kQLora);
  mfma_gemm_kernel<1, true><<<dim3(24, 32), dim3(256), 0, stream>>>(qa_b, wqb_b, scWqb, nullptr, q_h, q_l, nullptr, nullptr, 3072, kQLora, 3072);
  // kv_a -> rms -> kv (split to Kn hi/lo [b,h,s,128] + V^T hi/lo [b,h,dv,s])
  mfma_gemm_kernel<0, true><<<dim3(5, 32), dim3(256), 0, stream>>>(hidq_b, wkva_b, scWkva, kva, nullptr, nullptr, nullptr, nullptr, 576, kDH, 576);
  rms_qdq_kernel<<<dim3(kNTok), dim3(256), 0, stream>>>(kva, kvnw, ckv_b, kKvLora, kKvLora + kDR, kKvLora);
  rope_split_kernel<<<dim3(kNTok), dim3(64), 0, stream>>>(q_h, q_l, kva, krh, krl, pos);
  mfma_gemm_kernel<2, true><<<dim3(32, 32), dim3(256), 0, stream>>>(ckv_b, wkvb_b, scWkvb, nullptr, kn_h, kn_l, v_th, v_tl, 4096, kKvLora, 4096);

  // ---------- attention (fused ctx fp8-qdq) + output ----------
  attn_mfma_kernel<<<dim3(512, kB), dim3(256), 0, stream>>>(q_h, q_l, kn_h, kn_l, krh, krl, v_th, v_tl, sel, ctx_b);
  mfma_gemm_kernel<0, true><<<dim3(16, 32), dim3(256), 0, stream>>>(ctx_b, wo_b, scWo, out, nullptr, nullptr, nullptr, nullptr, kDH, kH * kDV, 2048);
}

// Round 16
// 1163.639 us; speedup vs baseline: 1.0943x; 1.0118x over previous
//
#include <hip/hip_runtime.h>
#include <math.h>

namespace {
constexpr int kB = 2, kS = 2048, kDH = 2048, kH = 16, kDN = 128, kDR = 64, kDV = 128;
constexpr int kKvLora = 512, kQLora = 1024, kHI = 8, kDI = 128, kTopK = 1024;
constexpr int kNTok = kB * kS;             // 4096
constexpr float kNeg = -1e30f;

// ---- fixed region (bytes) ----
constexpr size_t OFF_SC    = 0;                          // 784 f32 scales
constexpr size_t OFF_SEL_B = 4096;                       // 1 MB
constexpr size_t OFF_WGT_B = OFF_SEL_B + 1048576;        // 128 KB
constexpr size_t OFF_KRH_B = OFF_WGT_B + 131072;         // 512 KB
constexpr size_t OFF_KRL_B = OFF_KRH_B + 524288;         // 512 KB
constexpr size_t OFF_WOB_B = OFF_KRL_B + 524288;         // 8 MB  (Wo bf16)
constexpr size_t POOL      = OFF_WOB_B + 8388608;        // 10,620,928
// ---- phase B core ----
constexpr size_t B_HIDQ = POOL;                 // 16 MB bf16
constexpr size_t B_WQA  = POOL + 16777216;      // 4 MB
constexpr size_t B_WQB  = POOL + 20971520;      // 6 MB
constexpr size_t B_WKVA = POOL + 27262976;      // 2.5 MB
constexpr size_t B_WKVB = POOL + 29884416;      // 4 MB
constexpr size_t B_QAF  = POOL + 34078720;      // 16 MB f32
constexpr size_t B_QAB  = POOL + 50855936;      // 8 MB bf16
constexpr size_t B_KVA  = POOL + 59244544;      // 9.4 MB f32
constexpr size_t B_CKV  = POOL + 68681728;      // 4 MB bf16
constexpr size_t B_QH   = POOL + 72876032;      // 24 MB bf16
constexpr size_t B_QL   = POOL + 98041856;      // 24 MB bf16
constexpr size_t B_KNH  = POOL + 123207680;     // 16 MB
constexpr size_t B_KNL  = POOL + 139984896;     // 16 MB
constexpr size_t B_VTH  = POOL;                 // 16 MB (over dead hidq)
constexpr size_t B_VTL  = POOL + 34078720;      // 16 MB (over dead qa_f)
constexpr size_t B_CTXB = POOL + 50855936;      // 16 MB (over dead qa_b + kva)
// ---- phase A (indexer) ----
constexpr size_t A_HHI  = POOL + 16777216;      // 16 MB bf16
constexpr size_t A_HLO  = POOL + 33554432;      // 16 MB bf16
constexpr size_t A_WQKH = POOL + 50331648;      // 4,718,592
constexpr size_t A_WQKL = POOL + 55050240;      // 4,718,592
constexpr size_t A_QIKH = POOL + 59768832;      // 9,437,184 bf16 [4096][1152]
constexpr size_t A_QIKL = POOL + 69206016;      // 9,437,184
constexpr size_t A_ISC  = POOL + 78643200;      // 33,554,432 f32 [4096][2048]
constexpr size_t WS_NEED = POOL + 156762112;    // 167,383,040 B (known-good)
} // namespace

typedef __attribute__((ext_vector_type(4))) float f32x4;
typedef __attribute__((ext_vector_type(8))) short bf16x8;
typedef __attribute__((address_space(1))) const void gvoid;
typedef __attribute__((address_space(3))) void lvoid;

// Exact e4m3fn round-to-nearest-even quant-dequant for |x| <= 448 (incl. subnormals).
__device__ __forceinline__ float fp8_e4m3_qdq(float x) {
  float ax = fabsf(x);
  int e;
  (void)frexpf(ax, &e);
  int ee = e - 1;
  if (ee < -6) ee = -6;
  float q = ldexpf(1.0f, ee - 3);
  float y = rintf(ax / q) * q;
  return (x < 0.0f) ? -y : y;
}

__device__ __forceinline__ float act_scale_from_amax(float amax) {
  float t = amax / 448.0f;
  unsigned u = __float_as_uint(t);
  int e = (int)((u >> 23) & 255u) - 127;
  if (u & 0x7fffffu) e += 1;
  return __uint_as_float((unsigned)(e + 127) << 23);
}

__device__ __forceinline__ float clamp448(float v) {
  return fminf(fmaxf(v, -448.0f), 448.0f);
}

__device__ __forceinline__ unsigned short f32_to_bf16(float f) {
  unsigned u = __float_as_uint(f);
  unsigned r = (u + 0x7FFFu + ((u >> 16) & 1u)) >> 16;
  return (unsigned short)r;
}
__device__ __forceinline__ float bf16_to_f32(unsigned short h) {
  return __uint_as_float((unsigned)h << 16);
}

__global__ __launch_bounds__(256) void fill_kernel(float* p, int n, float v) {
  int i = blockIdx.x * 256 + threadIdx.x;
  if (i < n) p[i] = v;
}

// ---------------- fused hidden prep: hi/lo split + fp8-qdq -> bf16 (one read) ----------------
__global__ __launch_bounds__(256) void hidden_prep_kernel(const float* __restrict__ X,
                                                          unsigned short* __restrict__ HI,
                                                          unsigned short* __restrict__ LO,
                                                          unsigned short* __restrict__ QB) {
  int wid = blockIdx.x * 4 + (threadIdx.x >> 6);
  int lane = threadIdx.x & 63;
  const float* x = X + (size_t)wid * 128;
  float v0 = x[lane], v1 = x[lane + 64];
  size_t o0 = (size_t)wid * 128 + lane, o1 = o0 + 64;
  unsigned short h0 = f32_to_bf16(v0);
  HI[o0] = h0; LO[o0] = f32_to_bf16(v0 - bf16_to_f32(h0));
  unsigned short h1 = f32_to_bf16(v1);
  HI[o1] = h1; LO[o1] = f32_to_bf16(v1 - bf16_to_f32(h1));
  float am = fmaxf(fabsf(v0), fabsf(v1));
#pragma unroll
  for (int m = 32; m >= 1; m >>= 1) am = fmaxf(am, __shfl_xor(am, m, 64));
  am = fmaxf(am, 1e-4f);
  float s = act_scale_from_amax(am);
  QB[o0] = f32_to_bf16(fp8_e4m3_qdq(clamp448(v0 / s)) * s);
  QB[o1] = f32_to_bf16(fp8_e4m3_qdq(clamp448(v1 / s)) * s);
}

// ---------------- fused weight 128x128-block scale + bf16 quantized values ----------------
__global__ __launch_bounds__(256) void fused_weight_kernel(const float* __restrict__ W,
                                                           float* __restrict__ SC,
                                                           unsigned short* __restrict__ WB,
                                                           int O, int I) {
  int kb = blockIdx.x, ob = blockIdx.y;
  int bo = ob * 128, bi = kb * 128;
  int tid = threadIdx.x;
  __shared__ float red[256];
  __shared__ float s_scale;
  float am = 0.0f;
  for (int idx = tid; idx < 128 * 128; idx += 256) {
    int r = bo + (idx >> 7), c = bi + (idx & 127);
    if (r < O) am = fmaxf(am, fabsf(W[(size_t)r * I + c]));
  }
  red[tid] = am; __syncthreads();
  for (int s = 128; s >= 1; s >>= 1) {
    if (tid < s) red[tid] = fmaxf(red[tid], red[tid + s]);
    __syncthreads();
  }
  if (tid == 0) {
    float sc = fmaxf(red[0], 1e-4f) / 448.0f;
    SC[(size_t)ob * gridDim.x + kb] = sc;
    s_scale = sc;
  }
  __syncthreads();
  float sc = s_scale;
  for (int idx = tid; idx < 128 * 128; idx += 256) {
    int r = bo + (idx >> 7), c = bi + (idx & 127);
    unsigned short v = 0;
    if (r < O) v = f32_to_bf16(fp8_e4m3_qdq(clamp448(W[(size_t)r * I + c] / sc)));
    WB[(size_t)r * I + c] = v;
  }
}

// ---------------- f32 -> bf16 hi/lo split ----------------
__global__ __launch_bounds__(256) void split_bf16x2_kernel(const float* __restrict__ X,
                                                           unsigned short* __restrict__ HI,
                                                           unsigned short* __restrict__ LO,
                                                           size_t n) {
  size_t i = (size_t)blockIdx.x * 256 + threadIdx.x;
  if (i >= n) return;
  float x = X[i];
  unsigned short h = f32_to_bf16(x);
  HI[i] = h;
  LO[i] = f32_to_bf16(x - bf16_to_f32(h));
}

// ---------------- fused RMSNorm + activation qdq -> bf16 (per row) ----------------
__global__ __launch_bounds__(256) void rms_qdq_kernel(const float* __restrict__ X,
                                                      const float* __restrict__ G,
                                                      unsigned short* __restrict__ Y,
                                                      int C, int xs, int ys) {
  int row = blockIdx.x, tid = threadIdx.x;
  __shared__ float xr[1024];
  __shared__ float red[256];
  const float* x = X + (size_t)row * xs;
  float ssq = 0.0f;
  for (int i = tid; i < C; i += 256) { float v = x[i]; xr[i] = v; ssq += v * v; }
  red[tid] = ssq; __syncthreads();
  for (int s = 128; s >= 1; s >>= 1) { if (tid < s) red[tid] += red[tid + s]; __syncthreads(); }
  float inv = 1.0f / sqrtf(red[0] / (float)C + 1e-6f);
  __syncthreads();
  int wv = tid >> 6, lane = tid & 63;
  for (int blk = wv; blk < C / 128; blk += 4) {
    int i0 = blk * 128 + lane, i1 = i0 + 64;
    float y0 = xr[i0] * inv * G[i0];
    float y1 = xr[i1] * inv * G[i1];
    float am = fmaxf(fabsf(y0), fabsf(y1));
#pragma unroll
    for (int m = 32; m >= 1; m >>= 1) am = fmaxf(am, __shfl_xor(am, m, 64));
    am = fmaxf(am, 1e-4f);
    float s = act_scale_from_amax(am);
    Y[(size_t)row * ys + i0] = f32_to_bf16(fp8_e4m3_qdq(clamp448(y0 / s)) * s);
    Y[(size_t)row * ys + i1] = f32_to_bf16(fp8_e4m3_qdq(clamp448(y1 / s)) * s);
  }
}

// ---------------- bf16 MFMA GEMM, templated epilogue ----------------
template <int OMODE, bool SCALED>
__global__ __launch_bounds__(256) void mfma_gemm_kernel(const unsigned short* __restrict__ A,
                                                        const unsigned short* __restrict__ B,
                                                        const float* __restrict__ Bsc,
                                                        float* __restrict__ C,
                                                        unsigned short* __restrict__ O1,
                                                        unsigned short* __restrict__ O2,
                                                        unsigned short* __restrict__ O3,
                                                        unsigned short* __restrict__ O4,
                                                        int N, int K, int ldc) {
  __shared__ unsigned short lA[128 * 64];
  __shared__ unsigned short lB[128 * 64];
  const int tid = threadIdx.x;
  const int wave = tid >> 6, lane = tid & 63;
  const int wr = (wave >> 1) * 64, wc = (wave & 1) * 64;
  const int m0 = blockIdx.y * 128, n0 = blockIdx.x * 128;
  const int KB = K >> 7;
  const int frow = lane & 15, fk = (lane >> 4) * 8;

  f32x4 mainAcc[4][4];
  f32x4 part[4][4];
  const f32x4 vzero = {0.f, 0.f, 0.f, 0.f};
#pragma unroll
  for (int i = 0; i < 4; ++i)
#pragma unroll
    for (int j = 0; j < 4; ++j) { mainAcc[i][j] = vzero; part[i][j] = vzero; }

  const int nkt = K >> 6;
  for (int kt = 0; kt < nkt; ++kt) {
    const int k0 = kt << 6;
    __syncthreads();
#pragma unroll
    for (int it = 0; it < 4; ++it) {
      int o = it * 4096 + wave * 1024 + lane * 16;
      int row = o >> 7;
      int kb = o & 127;
      const char* ga = (const char*)(A + (size_t)(m0 + row) * K + k0) + kb;
      const char* gb = (const char*)(B + (size_t)(n0 + row) * K + k0) + kb;
      __builtin_amdgcn_global_load_lds((gvoid*)ga, (lvoid*)((char*)lA + o), 16, 0, 0);
      __builtin_amdgcn_global_load_lds((gvoid*)gb, (lvoid*)((char*)lB + o), 16, 0, 0);
    }
    __syncthreads();
#pragma unroll
    for (int ks = 0; ks < 2; ++ks) {
      bf16x8 af[4], bfr[4];
#pragma unroll
      for (int i = 0; i < 4; ++i)
        af[i] = *(const bf16x8*)&lA[(wr + i * 16 + frow) * 64 + ks * 32 + fk];
#pragma unroll
      for (int j = 0; j < 4; ++j)
        bfr[j] = *(const bf16x8*)&lB[(wc + j * 16 + frow) * 64 + ks * 32 + fk];
#pragma unroll
      for (int i = 0; i < 4; ++i)
#pragma unroll
        for (int j = 0; j < 4; ++j)
          part[i][j] = __builtin_amdgcn_mfma_f32_16x16x32_bf16(af[i], bfr[j], part[i][j], 0, 0, 0);
    }
    if (SCALED) {
      float bs = Bsc[(size_t)(n0 >> 7) * KB + (k0 >> 7)];
#pragma unroll
      for (int i = 0; i < 4; ++i)
#pragma unroll
        for (int j = 0; j < 4; ++j) {
          mainAcc[i][j] += part[i][j] * bs;
          part[i][j] = vzero;
        }
    }
  }
  const int crow0 = (lane >> 4) * 4;
  const int ccol = lane & 15;
#pragma unroll
  for (int i = 0; i < 4; ++i) {
#pragma unroll
    for (int j = 0; j < 4; ++j) {
      f32x4 v = SCALED ? mainAcc[i][j] : part[i][j];
      int col = n0 + wc + j * 16 + ccol;
      if (col < N) {
#pragma unroll
        for (int r = 0; r < 4; ++r) {
          int m = m0 + wr + i * 16 + crow0 + r;
          float val = v[r];
          if (OMODE == 0) {
            C[(size_t)m * ldc + col] = val;
          } else if (OMODE == 1) {
            int hh = col / 192, d = col - hh * 192;
            int bb = m >> 11, s = m & 2047;
            size_t off = ((size_t)((bb * 16 + hh) * 2048 + s)) * 192 + d;
            unsigned short hi = f32_to_bf16(val);
            O1[off] = hi;
            O2[off] = f32_to_bf16(val - bf16_to_f32(hi));
          } else {
            int hh = col >> 8, d = col & 255;
            int bb = m >> 11, s = m & 2047;
            if (d < 128) {
              size_t off = ((size_t)((bb * 16 + hh) * 2048 + s)) * 128 + d;
              unsigned short hi = f32_to_bf16(val);
              O1[off] = hi;
              O2[off] = f32_to_bf16(val - bf16_to_f32(hi));
            } else {
              size_t off = ((size_t)((bb * 16 + hh) * 128 + (d - 128))) * 2048 + s;
              unsigned short hi = f32_to_bf16(val);
              O3[off] = hi;
              O4[off] = f32_to_bf16(val - bf16_to_f32(hi));
            }
          }
        }
      }
    }
  }
}

// ---------------- 3-product split GEMM -> bf16 hi/lo output [4096][1152] ----------------
__global__ __launch_bounds__(256) void mfma_gemm3_kernel(const unsigned short* __restrict__ Ah,
                                                         const unsigned short* __restrict__ Al,
                                                         const unsigned short* __restrict__ Bh,
                                                         const unsigned short* __restrict__ Bl,
                                                         unsigned short* __restrict__ OH,
                                                         unsigned short* __restrict__ OL,
                                                         int K, int ldc) {
  if (blockIdx.x < 8 && !(blockIdx.y & 8)) return;   // qi rows q<1024 never used
  __shared__ unsigned short lAh[128 * 64], lAl[128 * 64];
  __shared__ unsigned short lBh[128 * 64], lBl[128 * 64];
  const int tid = threadIdx.x;
  const int wave = tid >> 6, lane = tid & 63;
  const int wr = (wave >> 1) * 64, wc = (wave & 1) * 64;
  const int m0 = blockIdx.y * 128, n0 = blockIdx.x * 128;
  const int frow = lane & 15, fk = (lane >> 4) * 8;

  f32x4 part[4][4];
  const f32x4 vzero = {0.f, 0.f, 0.f, 0.f};
#pragma unroll
  for (int i = 0; i < 4; ++i)
#pragma unroll
    for (int j = 0; j < 4; ++j) part[i][j] = vzero;

  const int nkt = K >> 6;
  for (int kt = 0; kt < nkt; ++kt) {
    const int k0 = kt << 6;
    __syncthreads();
#pragma unroll
    for (int it = 0; it < 4; ++it) {
      int o = it * 4096 + wave * 1024 + lane * 16;
      int row = o >> 7;
      int kb = o & 127;
      size_t ga = (size_t)(m0 + row) * K + k0;
      size_t gb = (size_t)(n0 + row) * K + k0;
      __builtin_amdgcn_global_load_lds((gvoid*)((const char*)(Ah + ga) + kb), (lvoid*)((char*)lAh + o), 16, 0, 0);
      __builtin_amdgcn_global_load_lds((gvoid*)((const char*)(Al + ga) + kb), (lvoid*)((char*)lAl + o), 16, 0, 0);
      __builtin_amdgcn_global_load_lds((gvoid*)((const char*)(Bh + gb) + kb), (lvoid*)((char*)lBh + o), 16, 0, 0);
      __builtin_amdgcn_global_load_lds((gvoid*)((const char*)(Bl + gb) + kb), (lvoid*)((char*)lBl + o), 16, 0, 0);
    }
    __syncthreads();
#pragma unroll
    for (int ks = 0; ks < 2; ++ks) {
      bf16x8 ah[4], al[4], bh[4], bl[4];
#pragma unroll
      for (int i = 0; i < 4; ++i) {
        ah[i] = *(const bf16x8*)&lAh[(wr + i * 16 + frow) * 64 + ks * 32 + fk];
        al[i] = *(const bf16x8*)&lAl[(wr + i * 16 + frow) * 64 + ks * 32 + fk];
      }
#pragma unroll
      for (int j = 0; j < 4; ++j) {
        bh[j] = *(const bf16x8*)&lBh[(wc + j * 16 + frow) * 64 + ks * 32 + fk];
        bl[j] = *(const bf16x8*)&lBl[(wc + j * 16 + frow) * 64 + ks * 32 + fk];
      }
#pragma unroll
      for (int i = 0; i < 4; ++i)
#pragma unroll
        for (int j = 0; j < 4; ++j) {
          part[i][j] = __builtin_amdgcn_mfma_f32_16x16x32_bf16(ah[i], bh[j], part[i][j], 0, 0, 0);
          part[i][j] = __builtin_amdgcn_mfma_f32_16x16x32_bf16(ah[i], bl[j], part[i][j], 0, 0, 0);
          part[i][j] = __builtin_amdgcn_mfma_f32_16x16x32_bf16(al[i], bh[j], part[i][j], 0, 0, 0);
        }
    }
  }
  const int crow0 = (lane >> 4) * 4;
  const int ccol = lane & 15;
#pragma unroll
  for (int i = 0; i < 4; ++i)
#pragma unroll
    for (int j = 0; j < 4; ++j) {
      int col = n0 + wc + j * 16 + ccol;
#pragma unroll
      for (int r = 0; r < 4; ++r) {
        float val = part[i][j][r];
        size_t off = (size_t)(m0 + wr + i * 16 + crow0 + r) * ldc + col;
        unsigned short hi = f32_to_bf16(val);
        OH[off] = hi;
        OL[off] = f32_to_bf16(val - bf16_to_f32(hi));
      }
    }
}

// ---------------- f32 GEMM (tiny Wig only); rowskip: skip tiles with (y & rowskip)==0 ----------------
__global__ __launch_bounds__(256) void gemm_f32_kernel(const float* __restrict__ A,
                                                       const float* __restrict__ Bw,
                                                       float* __restrict__ C,
                                                       int N, int K, float alpha, int rowskip) {
  if (rowskip && !(blockIdx.y & rowskip)) return;
  __shared__ __align__(16) float As[16][68];
  __shared__ __align__(16) float Bs[16][68];
  int n0 = blockIdx.x * 64;
  int m0 = blockIdx.y * 64;
  int tid = threadIdx.x;
  int tx = tid & 15, ty = tid >> 4;
  float acc[4][4] = {};
  for (int k0 = 0; k0 < K; k0 += 16) {
#pragma unroll
    for (int t = 0; t < 4; ++t) {
      int idx = tid + t * 256;
      int rr = idx >> 4;
      int kk = idx & 15;
      As[kk][rr] = A[(size_t)(m0 + rr) * K + (k0 + kk)];
      Bs[kk][rr] = (n0 + rr < N) ? Bw[(size_t)(n0 + rr) * K + (k0 + kk)] : 0.0f;
    }
    __syncthreads();
#pragma unroll
    for (int kk = 0; kk < 16; ++kk) {
      float4 a = *(const float4*)&As[kk][ty * 4];
      float4 b = *(const float4*)&Bs[kk][tx * 4];
      float av[4] = {a.x, a.y, a.z, a.w};
      float bv[4] = {b.x, b.y, b.z, b.w};
#pragma unroll
      for (int i = 0; i < 4; ++i)
#pragma unroll
        for (int j = 0; j < 4; ++j) acc[i][j] += av[i] * bv[j];
    }
    __syncthreads();
  }
#pragma unroll
  for (int i = 0; i < 4; ++i) {
    int m = m0 + ty * 4 + i;
#pragma unroll
    for (int j = 0; j < 4; ++j) {
      int n = n0 + tx * 4 + j;
      if (n < N) C[(size_t)m * N + n] = alpha * acc[i][j];
    }
  }
}

// ---------------- RoPE on split Q (in place, [b,h,s,192]) + k_rope -> Krh/Krl ----------------
__global__ __launch_bounds__(64) void rope_split_kernel(unsigned short* __restrict__ Qh,
                                                        unsigned short* __restrict__ Ql,
                                                        const float* __restrict__ KVA,
                                                        unsigned short* __restrict__ Krh,
                                                        unsigned short* __restrict__ Krl,
                                                        const int* __restrict__ POS) {
  int t = blockIdx.x;  // b*S + s
  int tid = threadIdx.x;
  int b = t >> 11, s = t & 2047;
  __shared__ float cs[32], sn[32];
  if (tid < 32) {
    int pos = POS[t];
    double inv = pow(10000.0, -((double)(2 * tid) / 64.0));
    float ang = (float)pos * (float)inv;
    cs[tid] = cosf(ang);
    sn[tid] = sinf(ang);
  }
  __syncthreads();
  if (tid < 32) {
    const float* kr = KVA + (size_t)t * (kKvLora + kDR) + kKvLora;
    float x1 = kr[tid], x2 = kr[32 + tid];
    float y1 = x1 * cs[tid] - x2 * sn[tid];
    float y2 = x2 * cs[tid] + x1 * sn[tid];
    unsigned short h1 = f32_to_bf16(y1);
    Krh[(size_t)t * 64 + tid] = h1;
    Krl[(size_t)t * 64 + tid] = f32_to_bf16(y1 - bf16_to_f32(h1));
    unsigned short h2 = f32_to_bf16(y2);
    Krh[(size_t)t * 64 + 32 + tid] = h2;
    Krl[(size_t)t * 64 + 32 + tid] = f32_to_bf16(y2 - bf16_to_f32(h2));
  }
  for (int it = tid; it < kH * 32; it += 64) {
    int h = it >> 5, i = it & 31;
    size_t base = ((size_t)((b * 16 + h) * 2048 + s)) * 192 + 128;
    float x1 = bf16_to_f32(Qh[base + i]) + bf16_to_f32(Ql[base + i]);
    float x2 = bf16_to_f32(Qh[base + 32 + i]) + bf16_to_f32(Ql[base + 32 + i]);
    float y1 = x1 * cs[i] - x2 * sn[i];
    float y2 = x2 * cs[i] + x1 * sn[i];
    unsigned short h1 = f32_to_bf16(y1);
    Qh[base + i] = h1;
    Ql[base + i] = f32_to_bf16(y1 - bf16_to_f32(h1));
    unsigned short h2 = f32_to_bf16(y2);
    Qh[base + 32 + i] = h2;
    Ql[base + 32 + i] = f32_to_bf16(y2 - bf16_to_f32(h2));
  }
}

// ---------------- MFMA indexer scores: one 64x64 tile per block (rows q>=1024 only) ----------------
__global__ __launch_bounds__(256) void isc_mfma_kernel(const unsigned short* __restrict__ QIKH,
                                                       const unsigned short* __restrict__ QIKL,
                                                       const float* __restrict__ WGT,
                                                       float* __restrict__ ISC) {
  const int qt = blockIdx.y + 16;
  const int kt = blockIdx.x;
  if (kt > qt) return;
  const int b = blockIdx.z;
  const int q0 = qt * 64, k0 = kt * 64;
  const int tid = threadIdx.x, wave = tid >> 6, lane = tid & 63;
  const int fr = lane & 15, fg = lane >> 4;

  __shared__ unsigned short KiH[4 * 64 * 40], KiL[4 * 64 * 40];
  __shared__ float wgs[64 * 8];

  {
    int key = tid >> 2, sub = (tid & 3) * 8;
    size_t rb = (size_t)(b * kS + k0 + key) * 1152 + 1024;
#pragma unroll
    for (int kc = 0; kc < 4; ++kc) {
      *(bf16x8*)&KiH[kc * 2560 + key * 40 + sub] = *(const bf16x8*)&QIKH[rb + kc * 32 + sub];
      *(bf16x8*)&KiL[kc * 2560 + key * 40 + sub] = *(const bf16x8*)&QIKL[rb + kc * 32 + sub];
    }
#pragma unroll
    for (int t = 0; t < 2; ++t) {
      int i = t * 256 + tid;
      wgs[i] = WGT[(size_t)(b * kS + q0 + (i >> 3)) * kHI + (i & 7)];
    }
  }
  const size_t qrow = (size_t)(b * kS + q0 + wave * 16 + fr) * 1152;
  f32x4 sacc[4];
  const f32x4 vzero = {0.f, 0.f, 0.f, 0.f};
#pragma unroll
  for (int j = 0; j < 4; ++j) sacc[j] = vzero;

  bf16x8 qAh[4], qAl[4], qBh[4], qBl[4];
#define LOADQ(DH_, DL_, H_)                                                     \
  _Pragma("unroll") for (int kc = 0; kc < 4; ++kc) {                            \
    DH_[kc] = *(const bf16x8*)&QIKH[qrow + (H_)*128 + kc * 32 + fg * 8];        \
    DL_[kc] = *(const bf16x8*)&QIKL[qrow + (H_)*128 + kc * 32 + fg * 8];        \
  }
  LOADQ(qAh, qAl, 0)
  __syncthreads();
#define MFMA_HEAD(QH_, QL_, H_)                                                 \
  {                                                                             \
    f32x4 acc[4];                                                               \
    _Pragma("unroll") for (int j = 0; j < 4; ++j) acc[j] = vzero;               \
    _Pragma("unroll") for (int kc = 0; kc < 4; ++kc) {                          \
      _Pragma("unroll") for (int j = 0; j < 4; ++j) {                           \
        bf16x8 kh = *(const bf16x8*)&KiH[kc * 2560 + (j * 16 + fr) * 40 + fg * 8]; \
        bf16x8 kl = *(const bf16x8*)&KiL[kc * 2560 + (j * 16 + fr) * 40 + fg * 8]; \
        acc[j] = __builtin_amdgcn_mfma_f32_16x16x32_bf16(QH_[kc], kh, acc[j], 0, 0, 0); \
        acc[j] = __builtin_amdgcn_mfma_f32_16x16x32_bf16(QH_[kc], kl, acc[j], 0, 0, 0); \
        acc[j] = __builtin_amdgcn_mfma_f32_16x16x32_bf16(QL_[kc], kh, acc[j], 0, 0, 0); \
      }                                                                         \
    }                                                                           \
    float wv[4];                                                                \
    _Pragma("unroll") for (int r = 0; r < 4; ++r)                               \
        wv[r] = wgs[(wave * 16 + fg * 4 + r) * 8 + (H_)];                       \
    _Pragma("unroll") for (int j = 0; j < 4; ++j)                               \
      _Pragma("unroll") for (int r = 0; r < 4; ++r)                             \
        sacc[j][r] += fmaxf(acc[j][r], 0.0f) * wv[r];                           \
  }
#pragma unroll
  for (int hp = 0; hp < 4; ++hp) {
    int h0 = hp * 2;
    LOADQ(qBh, qBl, h0 + 1)
    MFMA_HEAD(qAh, qAl, h0)
    if (hp < 3) LOADQ(qAh, qAl, h0 + 2)
    MFMA_HEAD(qBh, qBl, h0 + 1)
  }
#undef LOADQ
#undef MFMA_HEAD
#pragma unroll
  for (int r = 0; r < 4; ++r) {
    size_t ob = (size_t)(b * kS + q0 + wave * 16 + fg * 4 + r) * kS + k0;
#pragma unroll
    for (int j = 0; j < 4; ++j) ISC[ob + j * 16 + fr] = sacc[j][r];
  }
}

// ---------------- exact stable top-k from precomputed scores ----------------
__global__ __launch_bounds__(256) void topk_kernel(const float* __restrict__ ISC,
                                                   unsigned* __restrict__ SEL) {
  int row = blockIdx.x;
  int q = row & (kS - 1);
  int L = q + 1;
  unsigned* selrow = SEL + (size_t)row * (kS / 32);
  int tid = threadIdx.x;
  if (L <= kTopK) {
    if (tid < kS / 32) {
      int base = tid * 32;
      unsigned w;
      if (base + 32 <= L) w = 0xFFFFFFFFu;
      else if (base >= L) w = 0u;
      else w = (1u << (L - base)) - 1u;
      selrow[tid] = w;
    }
    return;
  }
  __shared__ unsigned keys[kS];
  __shared__ unsigned hist[256];
  __shared__ unsigned msk[kS / 32];
  __shared__ unsigned pick[2];
  if (tid < kS / 32) msk[tid] = 0u;
  const float* x = ISC + (size_t)row * kS;
  for (int k = tid; k < L; k += 256) {
    unsigned u = __float_as_uint(x[k]);
    keys[k] = (u & 0x80000000u) ? ~u : (u | 0x80000000u);
  }
  __syncthreads();
  unsigned prefix = 0u;
  int r = kTopK;
  for (int shift = 24; shift >= 0; shift -= 8) {
    hist[tid] = 0u;
    __syncthreads();
    unsigned hm = (shift == 24) ? 0u : (0xFFFFFFFFu << (shift + 8));
    for (int k = tid; k < L; k += 256) {
      unsigned key = keys[k];
      if ((key & hm) == (prefix & hm)) atomicAdd(&hist[(key >> shift) & 255u], 1u);
    }
    __syncthreads();
    if (tid == 0) {
      int rr = r, bsel = 0;
      for (int bb = 255; bb >= 0; --bb) {
        int c = (int)hist[bb];
        if (rr <= c) { bsel = bb; break; }
        rr -= c;
      }
      pick[0] = (unsigned)bsel;
      pick[1] = (unsigned)rr;
    }
    __syncthreads();
    prefix |= pick[0] << shift;
    r = (int)pick[1];
    __syncthreads();
  }
  unsigned T = prefix;
  int ties_take = r;
  int base = tid * 8;
  int cnt = 0;
#pragma unroll
  for (int j = 0; j < 8; ++j) {
    int k = base + j;
    if (k < L && keys[k] == T) ++cnt;
  }
  hist[tid] = (unsigned)cnt;
  __syncthreads();
  if (tid == 0) {
    unsigned run = 0;
    for (int t = 0; t < 256; ++t) { unsigned c = hist[t]; hist[t] = run; run += c; }
  }
  __syncthreads();
  int trank = (int)hist[tid];
  unsigned bits = 0u;
#pragma unroll
  for (int j = 0; j < 8; ++j) {
    int k = base + j;
    if (k < L) {
      unsigned key = keys[k];
      bool s;
      if (key > T) s = true;
      else if (key == T) { s = trank < ties_take; ++trank; }
      else s = false;
      if (s) bits |= (1u << j);
    }
  }
  atomicOr(&msk[tid >> 2], bits << ((tid & 3) * 8));
  __syncthreads();
  if (tid < kS / 32) selrow[tid] = msk[tid];
}

// ---------------- MFMA flash attention (round-10 structure; __expf softmax) ----------------
// grid.x = flattened (qt,h), global longest-first: qt = 31 - (x>>4), h = x&15; b = grid.y.
// QK^T: 3-pass hi/lo; K chunks LDS double-buffered (1 barrier/chunk) with reg prefetch.
// PV: (Ph+Pl)*Vh then Ph*Vl; V prefetched into regs early. Pads 40/72 (16B-aligned rows).
__global__ __launch_bounds__(256) void attn_mfma_kernel(const unsigned short* __restrict__ Qh,
                                                        const unsigned short* __restrict__ Ql,
                                                        const unsigned short* __restrict__ Knh,
                                                        const unsigned short* __restrict__ Knl,
                                                        const unsigned short* __restrict__ Krh,
                                                        const unsigned short* __restrict__ Krl,
                                                        const unsigned short* __restrict__ Vth,
                                                        const unsigned short* __restrict__ Vtl,
                                                        const unsigned* __restrict__ SEL,
                                                        unsigned short* __restrict__ CTXB) {
  const int flat = blockIdx.x;
  const int qt = 31 - (flat >> 4);        // longest blocks dispatch first
  const int h = flat & 15;
  const int b = blockIdx.y;
  const int q0 = qt * 64;
  const int tid = threadIdx.x, wave = tid >> 6, lane = tid & 63;
  const int fr = lane & 15, fg = lane >> 4;
  const float scale = 0.07216878364870323f;  // 1/sqrt(192)

  __shared__ unsigned short KsH[2 * 64 * 40], KsL[2 * 64 * 40];  // double-buffered K chunk
  __shared__ unsigned short Ph[64 * 72], Pl[64 * 72];
  __shared__ unsigned short Vs[128 * 72];
  __shared__ unsigned selw[64][2];

  bf16x8 qh[6], ql[6];
  {
    const size_t qbase = ((size_t)((b * 16 + h) * 2048 + q0 + wave * 16 + fr)) * 192;
#pragma unroll
    for (int kc = 0; kc < 6; ++kc) {
      qh[kc] = *(const bf16x8*)&Qh[qbase + kc * 32 + fg * 8];
      ql[kc] = *(const bf16x8*)&Ql[qbase + kc * 32 + fg * 8];
    }
  }
  float m_run[4], l_run[4];
#pragma unroll
  for (int r = 0; r < 4; ++r) { m_run[r] = kNeg; l_run[r] = 0.0f; }
  f32x4 O[8];
  const f32x4 vzero = {0.f, 0.f, 0.f, 0.f};
#pragma unroll
  for (int j = 0; j < 8; ++j) O[j] = vzero;

  const int key = tid >> 2, sub = (tid & 3) * 8;
  const size_t knbase = (size_t)((b * 16 + h) * 2048) * 128;
  const size_t krbase = (size_t)(b * 2048) * 64;
  const size_t vbase0 = ((size_t)((b * 16 + h) * 128)) * 2048;

  const int nkt = qt + 1;
  for (int kt = 0; kt < nkt; ++kt) {
    const int k0 = kt * 64;
    const size_t vbase = vbase0 + k0;
    unsigned selreg = 0;
    if (tid < 128)
      selreg = SEL[(size_t)(b * kS + q0 + (tid >> 1)) * (kS / 32) + (k0 >> 5) + (tid & 1)];
    bf16x8 kh_pre[2], kl_pre[2];
    {
      size_t src = knbase + (size_t)(k0 + key) * 128 + sub;   // chunk 0
      kh_pre[0] = *(const bf16x8*)&Knh[src];
      kl_pre[0] = *(const bf16x8*)&Knl[src];
    }
    bf16x8 vpre[4];
#pragma unroll
    for (int it = 0; it < 4; ++it) {
      int idx = it * 256 + tid;
      int dv = idx >> 3, ks8 = (idx & 7) * 8;
      vpre[it] = *(const bf16x8*)&Vth[vbase + (size_t)dv * 2048 + ks8];
    }
    __syncthreads();  // B1: prev tile's Ks(last chunk)/Vs/selw reads done
    if (tid < 128) selw[tid >> 1][tid & 1] = selreg;
    f32x4 acc[4];
#pragma unroll
    for (int j = 0; j < 4; ++j) acc[j] = vzero;
#pragma unroll
    for (int kc = 0; kc < 6; ++kc) {
      const int buf = (kc & 1) * 2560;
      *(bf16x8*)&KsH[buf + key * 40 + sub] = kh_pre[kc & 1];
      *(bf16x8*)&KsL[buf + key * 40 + sub] = kl_pre[kc & 1];
      if (kc < 5) {   // prefetch next chunk (hidden under barrier+MFMA)
        if (kc + 1 < 4) {
          size_t src = knbase + (size_t)(k0 + key) * 128 + (kc + 1) * 32 + sub;
          kh_pre[(kc + 1) & 1] = *(const bf16x8*)&Knh[src];
          kl_pre[(kc + 1) & 1] = *(const bf16x8*)&Knl[src];
        } else {
          size_t src = krbase + (size_t)(k0 + key) * 64 + (kc - 3) * 32 + sub;
          kh_pre[(kc + 1) & 1] = *(const bf16x8*)&Krh[src];
          kl_pre[(kc + 1) & 1] = *(const bf16x8*)&Krl[src];
        }
      }
      __syncthreads();  // single barrier per chunk (double-buffered Ks)
#pragma unroll
      for (int j = 0; j < 4; ++j) {
        bf16x8 kh = *(const bf16x8*)&KsH[buf + (j * 16 + fr) * 40 + fg * 8];
        bf16x8 kl = *(const bf16x8*)&KsL[buf + (j * 16 + fr) * 40 + fg * 8];
        acc[j] = __builtin_amdgcn_mfma_f32_16x16x32_bf16(qh[kc], kh, acc[j], 0, 0, 0);
        acc[j] = __builtin_amdgcn_mfma_f32_16x16x32_bf16(qh[kc], kl, acc[j], 0, 0, 0);
        acc[j] = __builtin_amdgcn_mfma_f32_16x16x32_bf16(ql[kc], kh, acc[j], 0, 0, 0);
      }
    }
    float p[4][4];
    float fsc[4];
#pragma unroll
    for (int r = 0; r < 4; ++r) {
      int row = wave * 16 + fg * 4 + r;
      float sv[4];
      float vmax = kNeg;
#pragma unroll
      for (int j = 0; j < 4; ++j) {
        int col = j * 16 + fr;
        bool bit = (selw[row][col >> 5] >> (col & 31)) & 1u;
        float s = bit ? acc[j][r] * scale : kNeg;
        sv[j] = s;
        vmax = fmaxf(vmax, s);
      }
#pragma unroll
      for (int m = 1; m <= 8; m <<= 1) vmax = fmaxf(vmax, __shfl_xor(vmax, m, 64));
      float newm = fmaxf(m_run[r], vmax);
      float sum = 0.0f;
#pragma unroll
      for (int j = 0; j < 4; ++j) {
        float pp = (sv[j] < -1e29f) ? 0.0f : __expf(sv[j] - newm);
        p[j][r] = pp;
        sum += pp;
      }
#pragma unroll
      for (int m = 1; m <= 8; m <<= 1) sum += __shfl_xor(sum, m, 64);
      fsc[r] = __expf(m_run[r] - newm);
      l_run[r] = l_run[r] * fsc[r] + sum;
      m_run[r] = newm;
    }
#pragma unroll
    for (int j = 0; j < 8; ++j)
#pragma unroll
      for (int r = 0; r < 4; ++r) O[j][r] *= fsc[r];
#pragma unroll
    for (int r = 0; r < 4; ++r) {
      int row = wave * 16 + fg * 4 + r;
#pragma unroll
      for (int j = 0; j < 4; ++j) {
        int col = j * 16 + fr;
        float pp = p[j][r];
        unsigned short hi = f32_to_bf16(pp);
        Ph[row * 72 + col] = hi;
        Pl[row * 72 + col] = f32_to_bf16(pp - bf16_to_f32(hi));
      }
    }
#pragma unroll
    for (int it = 0; it < 4; ++it) {
      int idx = it * 256 + tid;
      int dv = idx >> 3, ks8 = (idx & 7) * 8;
      *(bf16x8*)&Vs[dv * 72 + ks8] = vpre[it];
    }
#pragma unroll
    for (int it = 0; it < 4; ++it) {
      int idx = it * 256 + tid;
      int dv = idx >> 3, ks8 = (idx & 7) * 8;
      vpre[it] = *(const bf16x8*)&Vtl[vbase + (size_t)dv * 2048 + ks8];
    }
    __syncthreads();  // B3: Vs (hi) ready
#pragma unroll
    for (int kk = 0; kk < 2; ++kk) {
      bf16x8 pah = *(const bf16x8*)&Ph[(wave * 16 + fr) * 72 + kk * 32 + fg * 8];
      bf16x8 pal = *(const bf16x8*)&Pl[(wave * 16 + fr) * 72 + kk * 32 + fg * 8];
#pragma unroll
      for (int j = 0; j < 8; ++j) {
        bf16x8 vb = *(const bf16x8*)&Vs[(j * 16 + fr) * 72 + kk * 32 + fg * 8];
        O[j] = __builtin_amdgcn_mfma_f32_16x16x32_bf16(pah, vb, O[j], 0, 0, 0);
        O[j] = __builtin_amdgcn_mfma_f32_16x16x32_bf16(pal, vb, O[j], 0, 0, 0);
      }
    }
    __syncthreads();  // B4: PV1 Vs reads done
#pragma unroll
    for (int it = 0; it < 4; ++it) {
      int idx = it * 256 + tid;
      int dv = idx >> 3, ks8 = (idx & 7) * 8;
      *(bf16x8*)&Vs[dv * 72 + ks8] = vpre[it];
    }
    __syncthreads();  // B5: Vs (lo) ready
#pragma unroll
    for (int kk = 0; kk < 2; ++kk) {
      bf16x8 pah = *(const bf16x8*)&Ph[(wave * 16 + fr) * 72 + kk * 32 + fg * 8];
#pragma unroll
      for (int j = 0; j < 8; ++j) {
        bf16x8 vb = *(const bf16x8*)&Vs[(j * 16 + fr) * 72 + kk * 32 + fg * 8];
        O[j] = __builtin_amdgcn_mfma_f32_16x16x32_bf16(pah, vb, O[j], 0, 0, 0);
      }
    }
  }
#pragma unroll
  for (int r = 0; r < 4; ++r) {
    float inv = 1.0f / l_run[r];
    float vals[8];
    float am = 0.0f;
#pragma unroll
    for (int j = 0; j < 8; ++j) {
      vals[j] = O[j][r] * inv;
      am = fmaxf(am, fabsf(vals[j]));
    }
#pragma unroll
    for (int m = 1; m <= 8; m <<= 1) am = fmaxf(am, __shfl_xor(am, m, 64));
    am = fmaxf(am, 1e-4f);
    float s = act_scale_from_amax(am);
    size_t obase = (size_t)(b * kS + q0 + wave * 16 + fg * 4 + r) * 2048 + h * 128;
#pragma unroll
    for (int j = 0; j < 8; ++j)
      CTXB[obase + j * 16 + fr] = f32_to_bf16(fp8_e4m3_qdq(clamp448(vals[j] / s)) * s);
  }
}

extern "C" void kernel_launch(void* const* d_in, const int* in_sizes, int n_in,
                              void* d_out, int out_size, void* d_ws, size_t ws_size,
                              hipStream_t stream) {
  (void)in_sizes; (void)n_in;

  const float* hidden = (const float*)d_in[0];
  const float* Wqa    = (const float*)d_in[1];
  const float* qnw    = (const float*)d_in[2];
  const float* Wqb    = (const float*)d_in[3];
  const float* Wkva   = (const float*)d_in[4];
  const float* kvnw   = (const float*)d_in[5];
  const float* Wkvb   = (const float*)d_in[6];
  const float* Wiq    = (const float*)d_in[7];
  const float* Wik    = (const float*)d_in[8];
  const float* Wig    = (const float*)d_in[9];
  const float* Wo     = (const float*)d_in[10];
  const int*   pos    = (const int*)d_in[11];
  char* ws = (char*)d_ws;
  float* out = (float*)d_out;

  if (ws_size < WS_NEED) {
    fill_kernel<<<dim3((out_size + 255) / 256), dim3(256), 0, stream>>>(out, out_size, 54321.0f);
    return;
  }

  float* scWqa  = (float*)(ws + OFF_SC) + 0;
  float* scWqb  = (float*)(ws + OFF_SC) + 128;
  float* scWkva = (float*)(ws + OFF_SC) + 320;
  float* scWkvb = (float*)(ws + OFF_SC) + 400;
  float* scWo   = (float*)(ws + OFF_SC) + 528;
  unsigned* sel = (unsigned*)(ws + OFF_SEL_B);
  float* wgt    = (float*)(ws + OFF_WGT_B);
  unsigned short* krh = (unsigned short*)(ws + OFF_KRH_B);
  unsigned short* krl = (unsigned short*)(ws + OFF_KRL_B);
  unsigned short* wo_b = (unsigned short*)(ws + OFF_WOB_B);

  unsigned short* h_hi  = (unsigned short*)(ws + A_HHI);
  unsigned short* h_lo  = (unsigned short*)(ws + A_HLO);
  unsigned short* wqk_h = (unsigned short*)(ws + A_WQKH);
  unsigned short* wqk_l = (unsigned short*)(ws + A_WQKL);
  unsigned short* qik_h = (unsigned short*)(ws + A_QIKH);
  unsigned short* qik_l = (unsigned short*)(ws + A_QIKL);
  float* isc = (float*)(ws + A_ISC);

  unsigned short* hidq_b = (unsigned short*)(ws + B_HIDQ);
  unsigned short* wqa_b  = (unsigned short*)(ws + B_WQA);
  unsigned short* wqb_b  = (unsigned short*)(ws + B_WQB);
  unsigned short* wkva_b = (unsigned short*)(ws + B_WKVA);
  unsigned short* wkvb_b = (unsigned short*)(ws + B_WKVB);
  float* qa_f   = (float*)(ws + B_QAF);
  unsigned short* qa_b  = (unsigned short*)(ws + B_QAB);
  float* kva    = (float*)(ws + B_KVA);
  unsigned short* ckv_b = (unsigned short*)(ws + B_CKV);
  unsigned short* q_h   = (unsigned short*)(ws + B_QH);
  unsigned short* q_l   = (unsigned short*)(ws + B_QL);
  unsigned short* kn_h  = (unsigned short*)(ws + B_KNH);
  unsigned short* kn_l  = (unsigned short*)(ws + B_KNL);
  unsigned short* v_th  = (unsigned short*)(ws + B_VTH);
  unsigned short* v_tl  = (unsigned short*)(ws + B_VTL);
  unsigned short* ctx_b = (unsigned short*)(ws + B_CTXB);

  // ---------- Phase A: indexer + top-k ----------
  hidden_prep_kernel<<<dim3(16384), dim3(256), 0, stream>>>(hidden, h_hi, h_lo, hidq_b);
  split_bf16x2_kernel<<<dim3(8192),  dim3(256), 0, stream>>>(Wiq, wqk_h, wqk_l, (size_t)kHI * kDI * kDH);
  split_bf16x2_kernel<<<dim3(1024),  dim3(256), 0, stream>>>(Wik, wqk_h + (size_t)1024 * kDH, wqk_l + (size_t)1024 * kDH, (size_t)kDI * kDH);
  gemm_f32_kernel<<<dim3(1, 64), dim3(256), 0, stream>>>(hidden, Wig, wgt, kHI, kDH, 0.35355339059327373f, 16);
  mfma_gemm3_kernel<<<dim3(9, 32), dim3(256), 0, stream>>>(h_hi, h_lo, wqk_h, wqk_l, qik_h, qik_l, kDH, 1152);
  isc_mfma_kernel<<<dim3(32, 16, kB), dim3(256), 0, stream>>>(qik_h, qik_l, wgt, isc);
  topk_kernel<<<dim3(kNTok), dim3(256), 0, stream>>>(isc, sel);

  // ---------- Phase B: fp8-path linears on MFMA ----------
  fused_weight_kernel<<<dim3(16, 8),  dim3(256), 0, stream>>>(Wqa,  scWqa,  wqa_b,  kQLora, kDH);
  fused_weight_kernel<<<dim3(8, 24),  dim3(256), 0, stream>>>(Wqb,  scWqb,  wqb_b,  kH * (kDN + kDR), kQLora);
  fused_weight_kernel<<<dim3(16, 5),  dim3(256), 0, stream>>>(Wkva, scWkva, wkva_b, kKvLora + kDR, kDH);
  fused_weight_kernel<<<dim3(4, 32),  dim3(256), 0, stream>>>(Wkvb, scWkvb, wkvb_b, kH * (kDN + kDV), kKvLora);
  fused_weight_kernel<<<dim3(16, 16), dim3(256), 0, stream>>>(Wo,   scWo,   wo_b,   kDH, kH * kDV);

  // q_a -> rms -> q (bf16 hi/lo, [b,h,s,192])
  mfma_gemm_kernel<0, true><<<dim3(8, 32), dim3(256), 0, stream>>>(hidq_b, wqa_b, scWqa, qa_f, nullptr, nullptr, nullptr, nullptr, 1024, kDH, 1024);
  rms_qdq_kernel<<<dim3(kNTok), dim3(256), 0, stream>>>(qa_f, qnw, qa_b, kQLora, kQLora, kQLora);
  mfma_gemm_kernel<1, true><<<dim3(24, 32), dim3(256), 0, stream>>>(qa_b, wqb_b, scWqb, nullptr, q_h, q_l, nullptr, nullptr, 3072, kQLora, 3072);
  // kv_a -> rms -> kv (split to Kn hi/lo [b,h,s,128] + V^T hi/lo [b,h,dv,s])
  mfma_gemm_kernel<0, true><<<dim3(5, 32), dim3(256), 0, stream>>>(hidq_b, wkva_b, scWkva, kva, nullptr, nullptr, nullptr, nullptr, 576, kDH, 576);
  rms_qdq_kernel<<<dim3(kNTok), dim3(256), 0, stream>>>(kva, kvnw, ckv_b, kKvLora, kKvLora + kDR, kKvLora);
  rope_split_kernel<<<dim3(kNTok), dim3(64), 0, stream>>>(q_h, q_l, kva, krh, krl, pos);
  mfma_gemm_kernel<2, true><<<dim3(32, 32), dim3(256), 0, stream>>>(ckv_b, wkvb_b, scWkvb, nullptr, kn_h, kn_l, v_th, v_tl, 4096, kKvLora, 4096);

  // ---------- attention (fused ctx fp8-qdq) + output ----------
  attn_mfma_kernel<<<dim3(512, kB), dim3(256), 0, stream>>>(q_h, q_l, kn_h, kn_l, krh, krl, v_th, v_tl, sel, ctx_b);
  mfma_gemm_kernel<0, true><<<dim3(16, 32), dim3(256), 0, stream>>>(ctx_b, wo_b, scWo, out, nullptr, nullptr, nullptr, nullptr, kDH, kH * kDV, 2048);
}

// Round 17
// 951.095 us; speedup vs baseline: 1.3389x; 1.2235x over previous
//
#include <hip/hip_runtime.h>
#include <math.h>

namespace {
constexpr int kB = 2, kS = 2048, kDH = 2048, kH = 16, kDN = 128, kDR = 64, kDV = 128;
constexpr int kKvLora = 512, kQLora = 1024, kHI = 8, kDI = 128, kTopK = 1024;
constexpr int kNTok = kB * kS;             // 4096
constexpr float kNeg = -1e30f;

// ---- fixed region (bytes) ----
constexpr size_t OFF_SC    = 0;                          // 784 f32 scales
constexpr size_t OFF_SEL_B = 4096;                       // 1 MB
constexpr size_t OFF_WGT_B = OFF_SEL_B + 1048576;        // 128 KB
constexpr size_t OFF_KRH_B = OFF_WGT_B + 131072;         // 512 KB
constexpr size_t OFF_KRL_B = OFF_KRH_B + 524288;         // 512 KB
constexpr size_t OFF_WOB_B = OFF_KRL_B + 524288;         // 8 MB  (Wo bf16)
constexpr size_t POOL      = OFF_WOB_B + 8388608;        // 10,620,928
// ---- phase B core ----
constexpr size_t B_HIDQ = POOL;                 // 16 MB bf16
constexpr size_t B_WQA  = POOL + 16777216;      // 4 MB
constexpr size_t B_WQB  = POOL + 20971520;      // 6 MB
constexpr size_t B_WKVA = POOL + 27262976;      // 2.5 MB
constexpr size_t B_WKVB = POOL + 29884416;      // 4 MB
constexpr size_t B_QAF  = POOL + 34078720;      // 16 MB f32
constexpr size_t B_QAB  = POOL + 50855936;      // 8 MB bf16
constexpr size_t B_KVA  = POOL + 59244544;      // 9.4 MB f32
constexpr size_t B_CKV  = POOL + 68681728;      // 4 MB bf16
constexpr size_t B_QH   = POOL + 72876032;      // 24 MB bf16
constexpr size_t B_QL   = POOL + 98041856;      // 24 MB bf16
constexpr size_t B_KNH  = POOL + 123207680;     // 16 MB
constexpr size_t B_KNL  = POOL + 139984896;     // 16 MB
constexpr size_t B_VTH  = POOL;                 // 16 MB (over dead hidq)
constexpr size_t B_VTL  = POOL + 34078720;      // 16 MB (over dead qa_f)
constexpr size_t B_CTXB = POOL + 50855936;      // 16 MB (over dead qa_b + kva)
// ---- phase A (indexer) ----
constexpr size_t A_HHI  = POOL + 16777216;      // 16 MB bf16
constexpr size_t A_HLO  = POOL + 33554432;      // 16 MB bf16
constexpr size_t A_WQKH = POOL + 50331648;      // 4,718,592
constexpr size_t A_WQKL = POOL + 55050240;      // 4,718,592
constexpr size_t A_QIKH = POOL + 59768832;      // 9,437,184 bf16 [4096][1152]
constexpr size_t A_QIKL = POOL + 69206016;      // 9,437,184
constexpr size_t A_ISC  = POOL + 78643200;      // 33,554,432 f32 [4096][2048]
constexpr size_t WS_NEED = POOL + 156762112;    // 167,383,040 B (known-good)
} // namespace

typedef __attribute__((ext_vector_type(4))) float f32x4;
typedef __attribute__((ext_vector_type(8))) short bf16x8;
typedef __attribute__((address_space(1))) const void gvoid;
typedef __attribute__((address_space(3))) void lvoid;

// Exact e4m3fn round-to-nearest-even quant-dequant for |x| <= 448 (incl. subnormals).
__device__ __forceinline__ float fp8_e4m3_qdq(float x) {
  float ax = fabsf(x);
  int e;
  (void)frexpf(ax, &e);
  int ee = e - 1;
  if (ee < -6) ee = -6;
  float q = ldexpf(1.0f, ee - 3);
  float y = rintf(ax / q) * q;
  return (x < 0.0f) ? -y : y;
}

__device__ __forceinline__ float act_scale_from_amax(float amax) {
  float t = amax / 448.0f;
  unsigned u = __float_as_uint(t);
  int e = (int)((u >> 23) & 255u) - 127;
  if (u & 0x7fffffu) e += 1;
  return __uint_as_float((unsigned)(e + 127) << 23);
}

__device__ __forceinline__ float clamp448(float v) {
  return fminf(fmaxf(v, -448.0f), 448.0f);
}

__device__ __forceinline__ unsigned short f32_to_bf16(float f) {
  unsigned u = __float_as_uint(f);
  unsigned r = (u + 0x7FFFu + ((u >> 16) & 1u)) >> 16;
  return (unsigned short)r;
}
__device__ __forceinline__ float bf16_to_f32(unsigned short h) {
  return __uint_as_float((unsigned)h << 16);
}

__global__ __launch_bounds__(256) void fill_kernel(float* p, int n, float v) {
  int i = blockIdx.x * 256 + threadIdx.x;
  if (i < n) p[i] = v;
}

// ---------------- fused hidden prep: hi/lo split + fp8-qdq -> bf16 (one read) ----------------
__global__ __launch_bounds__(256) void hidden_prep_kernel(const float* __restrict__ X,
                                                          unsigned short* __restrict__ HI,
                                                          unsigned short* __restrict__ LO,
                                                          unsigned short* __restrict__ QB) {
  int wid = blockIdx.x * 4 + (threadIdx.x >> 6);
  int lane = threadIdx.x & 63;
  const float* x = X + (size_t)wid * 128;
  float v0 = x[lane], v1 = x[lane + 64];
  size_t o0 = (size_t)wid * 128 + lane, o1 = o0 + 64;
  unsigned short h0 = f32_to_bf16(v0);
  HI[o0] = h0; LO[o0] = f32_to_bf16(v0 - bf16_to_f32(h0));
  unsigned short h1 = f32_to_bf16(v1);
  HI[o1] = h1; LO[o1] = f32_to_bf16(v1 - bf16_to_f32(h1));
  float am = fmaxf(fabsf(v0), fabsf(v1));
#pragma unroll
  for (int m = 32; m >= 1; m >>= 1) am = fmaxf(am, __shfl_xor(am, m, 64));
  am = fmaxf(am, 1e-4f);
  float s = act_scale_from_amax(am);
  QB[o0] = f32_to_bf16(fp8_e4m3_qdq(clamp448(v0 / s)) * s);
  QB[o1] = f32_to_bf16(fp8_e4m3_qdq(clamp448(v1 / s)) * s);
}

// ---------------- merged weight prep: 5 weights, one launch (per-block math identical) ----------------
__global__ __launch_bounds__(256) void fused_weight5_kernel(const float* __restrict__ W0,
                                                            const float* __restrict__ W1,
                                                            const float* __restrict__ W2,
                                                            const float* __restrict__ W3,
                                                            const float* __restrict__ W4,
                                                            float* __restrict__ SCB,
                                                            unsigned short* __restrict__ B0,
                                                            unsigned short* __restrict__ B1,
                                                            unsigned short* __restrict__ B2,
                                                            unsigned short* __restrict__ B3,
                                                            unsigned short* __restrict__ B4) {
  int bid = blockIdx.x;
  const float* W; unsigned short* WB; float* SC; int O, I, KBX, loc;
  if (bid < 128)      { W = W0; WB = B0; SC = SCB + 0;   O = 1024; I = 2048; KBX = 16; loc = bid; }
  else if (bid < 320) { W = W1; WB = B1; SC = SCB + 128; O = 3072; I = 1024; KBX = 8;  loc = bid - 128; }
  else if (bid < 400) { W = W2; WB = B2; SC = SCB + 320; O = 576;  I = 2048; KBX = 16; loc = bid - 320; }
  else if (bid < 528) { W = W3; WB = B3; SC = SCB + 400; O = 4096; I = 512;  KBX = 4;  loc = bid - 400; }
  else                { W = W4; WB = B4; SC = SCB + 528; O = 2048; I = 2048; KBX = 16; loc = bid - 528; }
  int kb = loc % KBX, ob = loc / KBX;
  int bo = ob * 128, bi = kb * 128;
  int tid = threadIdx.x;
  __shared__ float red[256];
  __shared__ float s_scale;
  float am = 0.0f;
  for (int idx = tid; idx < 128 * 128; idx += 256) {
    int r = bo + (idx >> 7), c = bi + (idx & 127);
    if (r < O) am = fmaxf(am, fabsf(W[(size_t)r * I + c]));
  }
  red[tid] = am; __syncthreads();
  for (int s = 128; s >= 1; s >>= 1) {
    if (tid < s) red[tid] = fmaxf(red[tid], red[tid + s]);
    __syncthreads();
  }
  if (tid == 0) {
    float sc = fmaxf(red[0], 1e-4f) / 448.0f;
    SC[(size_t)ob * KBX + kb] = sc;
    s_scale = sc;
  }
  __syncthreads();
  float sc = s_scale;
  for (int idx = tid; idx < 128 * 128; idx += 256) {
    int r = bo + (idx >> 7), c = bi + (idx & 127);
    unsigned short v = 0;
    if (r < O) v = f32_to_bf16(fp8_e4m3_qdq(clamp448(W[(size_t)r * I + c] / sc)));
    WB[(size_t)r * I + c] = v;
  }
}

// ---------------- f32 -> bf16 hi/lo split ----------------
__global__ __launch_bounds__(256) void split_bf16x2_kernel(const float* __restrict__ X,
                                                           unsigned short* __restrict__ HI,
                                                           unsigned short* __restrict__ LO,
                                                           size_t n) {
  size_t i = (size_t)blockIdx.x * 256 + threadIdx.x;
  if (i >= n) return;
  float x = X[i];
  unsigned short h = f32_to_bf16(x);
  HI[i] = h;
  LO[i] = f32_to_bf16(x - bf16_to_f32(h));
}

// ---------------- fused RMSNorm + activation qdq -> bf16 (per row) ----------------
__global__ __launch_bounds__(256) void rms_qdq_kernel(const float* __restrict__ X,
                                                      const float* __restrict__ G,
                                                      unsigned short* __restrict__ Y,
                                                      int C, int xs, int ys) {
  int row = blockIdx.x, tid = threadIdx.x;
  __shared__ float xr[1024];
  __shared__ float red[256];
  const float* x = X + (size_t)row * xs;
  float ssq = 0.0f;
  for (int i = tid; i < C; i += 256) { float v = x[i]; xr[i] = v; ssq += v * v; }
  red[tid] = ssq; __syncthreads();
  for (int s = 128; s >= 1; s >>= 1) { if (tid < s) red[tid] += red[tid + s]; __syncthreads(); }
  float inv = 1.0f / sqrtf(red[0] / (float)C + 1e-6f);
  __syncthreads();
  int wv = tid >> 6, lane = tid & 63;
  for (int blk = wv; blk < C / 128; blk += 4) {
    int i0 = blk * 128 + lane, i1 = i0 + 64;
    float y0 = xr[i0] * inv * G[i0];
    float y1 = xr[i1] * inv * G[i1];
    float am = fmaxf(fabsf(y0), fabsf(y1));
#pragma unroll
    for (int m = 32; m >= 1; m >>= 1) am = fmaxf(am, __shfl_xor(am, m, 64));
    am = fmaxf(am, 1e-4f);
    float s = act_scale_from_amax(am);
    Y[(size_t)row * ys + i0] = f32_to_bf16(fp8_e4m3_qdq(clamp448(y0 / s)) * s);
    Y[(size_t)row * ys + i1] = f32_to_bf16(fp8_e4m3_qdq(clamp448(y1 / s)) * s);
  }
}

// ---------------- bf16 MFMA GEMM, templated epilogue ----------------
template <int OMODE, bool SCALED>
__global__ __launch_bounds__(256) void mfma_gemm_kernel(const unsigned short* __restrict__ A,
                                                        const unsigned short* __restrict__ B,
                                                        const float* __restrict__ Bsc,
                                                        float* __restrict__ C,
                                                        unsigned short* __restrict__ O1,
                                                        unsigned short* __restrict__ O2,
                                                        unsigned short* __restrict__ O3,
                                                        unsigned short* __restrict__ O4,
                                                        int N, int K, int ldc) {
  __shared__ unsigned short lA[128 * 64];
  __shared__ unsigned short lB[128 * 64];
  const int tid = threadIdx.x;
  const int wave = tid >> 6, lane = tid & 63;
  const int wr = (wave >> 1) * 64, wc = (wave & 1) * 64;
  const int m0 = blockIdx.y * 128, n0 = blockIdx.x * 128;
  const int KB = K >> 7;
  const int frow = lane & 15, fk = (lane >> 4) * 8;

  f32x4 mainAcc[4][4];
  f32x4 part[4][4];
  const f32x4 vzero = {0.f, 0.f, 0.f, 0.f};
#pragma unroll
  for (int i = 0; i < 4; ++i)
#pragma unroll
    for (int j = 0; j < 4; ++j) { mainAcc[i][j] = vzero; part[i][j] = vzero; }

  const int nkt = K >> 6;
  for (int kt = 0; kt < nkt; ++kt) {
    const int k0 = kt << 6;
    __syncthreads();
#pragma unroll
    for (int it = 0; it < 4; ++it) {
      int o = it * 4096 + wave * 1024 + lane * 16;
      int row = o >> 7;
      int kb = o & 127;
      const char* ga = (const char*)(A + (size_t)(m0 + row) * K + k0) + kb;
      const char* gb = (const char*)(B + (size_t)(n0 + row) * K + k0) + kb;
      __builtin_amdgcn_global_load_lds((gvoid*)ga, (lvoid*)((char*)lA + o), 16, 0, 0);
      __builtin_amdgcn_global_load_lds((gvoid*)gb, (lvoid*)((char*)lB + o), 16, 0, 0);
    }
    __syncthreads();
#pragma unroll
    for (int ks = 0; ks < 2; ++ks) {
      bf16x8 af[4], bfr[4];
#pragma unroll
      for (int i = 0; i < 4; ++i)
        af[i] = *(const bf16x8*)&lA[(wr + i * 16 + frow) * 64 + ks * 32 + fk];
#pragma unroll
      for (int j = 0; j < 4; ++j)
        bfr[j] = *(const bf16x8*)&lB[(wc + j * 16 + frow) * 64 + ks * 32 + fk];
#pragma unroll
      for (int i = 0; i < 4; ++i)
#pragma unroll
        for (int j = 0; j < 4; ++j)
          part[i][j] = __builtin_amdgcn_mfma_f32_16x16x32_bf16(af[i], bfr[j], part[i][j], 0, 0, 0);
    }
    if (SCALED) {
      float bs = Bsc[(size_t)(n0 >> 7) * KB + (k0 >> 7)];
#pragma unroll
      for (int i = 0; i < 4; ++i)
#pragma unroll
        for (int j = 0; j < 4; ++j) {
          mainAcc[i][j] += part[i][j] * bs;
          part[i][j] = vzero;
        }
    }
  }
  const int crow0 = (lane >> 4) * 4;
  const int ccol = lane & 15;
#pragma unroll
  for (int i = 0; i < 4; ++i) {
#pragma unroll
    for (int j = 0; j < 4; ++j) {
      f32x4 v = SCALED ? mainAcc[i][j] : part[i][j];
      int col = n0 + wc + j * 16 + ccol;
      if (col < N) {
#pragma unroll
        for (int r = 0; r < 4; ++r) {
          int m = m0 + wr + i * 16 + crow0 + r;
          float val = v[r];
          if (OMODE == 0) {
            C[(size_t)m * ldc + col] = val;
          } else if (OMODE == 1) {
            int hh = col / 192, d = col - hh * 192;
            int bb = m >> 11, s = m & 2047;
            size_t off = ((size_t)((bb * 16 + hh) * 2048 + s)) * 192 + d;
            unsigned short hi = f32_to_bf16(val);
            O1[off] = hi;
            O2[off] = f32_to_bf16(val - bf16_to_f32(hi));
          } else {
            int hh = col >> 8, d = col & 255;
            int bb = m >> 11, s = m & 2047;
            if (d < 128) {
              size_t off = ((size_t)((bb * 16 + hh) * 2048 + s)) * 128 + d;
              unsigned short hi = f32_to_bf16(val);
              O1[off] = hi;
              O2[off] = f32_to_bf16(val - bf16_to_f32(hi));
            } else {
              size_t off = ((size_t)((bb * 16 + hh) * 128 + (d - 128))) * 2048 + s;
              unsigned short hi = f32_to_bf16(val);
              O3[off] = hi;
              O4[off] = f32_to_bf16(val - bf16_to_f32(hi));
            }
          }
        }
      }
    }
  }
}

// ---------------- 3-product split GEMM -> bf16 hi/lo output [4096][1152] ----------------
__global__ __launch_bounds__(256) void mfma_gemm3_kernel(const unsigned short* __restrict__ Ah,
                                                         const unsigned short* __restrict__ Al,
                                                         const unsigned short* __restrict__ Bh,
                                                         const unsigned short* __restrict__ Bl,
                                                         unsigned short* __restrict__ OH,
                                                         unsigned short* __restrict__ OL,
                                                         int K, int ldc) {
  if (blockIdx.x < 8 && !(blockIdx.y & 8)) return;   // qi rows q<1024 never used
  __shared__ unsigned short lAh[128 * 64], lAl[128 * 64];
  __shared__ unsigned short lBh[128 * 64], lBl[128 * 64];
  const int tid = threadIdx.x;
  const int wave = tid >> 6, lane = tid & 63;
  const int wr = (wave >> 1) * 64, wc = (wave & 1) * 64;
  const int m0 = blockIdx.y * 128, n0 = blockIdx.x * 128;
  const int frow = lane & 15, fk = (lane >> 4) * 8;

  f32x4 part[4][4];
  const f32x4 vzero = {0.f, 0.f, 0.f, 0.f};
#pragma unroll
  for (int i = 0; i < 4; ++i)
#pragma unroll
    for (int j = 0; j < 4; ++j) part[i][j] = vzero;

  const int nkt = K >> 6;
  for (int kt = 0; kt < nkt; ++kt) {
    const int k0 = kt << 6;
    __syncthreads();
#pragma unroll
    for (int it = 0; it < 4; ++it) {
      int o = it * 4096 + wave * 1024 + lane * 16;
      int row = o >> 7;
      int kb = o & 127;
      size_t ga = (size_t)(m0 + row) * K + k0;
      size_t gb = (size_t)(n0 + row) * K + k0;
      __builtin_amdgcn_global_load_lds((gvoid*)((const char*)(Ah + ga) + kb), (lvoid*)((char*)lAh + o), 16, 0, 0);
      __builtin_amdgcn_global_load_lds((gvoid*)((const char*)(Al + ga) + kb), (lvoid*)((char*)lAl + o), 16, 0, 0);
      __builtin_amdgcn_global_load_lds((gvoid*)((const char*)(Bh + gb) + kb), (lvoid*)((char*)lBh + o), 16, 0, 0);
      __builtin_amdgcn_global_load_lds((gvoid*)((const char*)(Bl + gb) + kb), (lvoid*)((char*)lBl + o), 16, 0, 0);
    }
    __syncthreads();
#pragma unroll
    for (int ks = 0; ks < 2; ++ks) {
      bf16x8 ah[4], al[4], bh[4], bl[4];
#pragma unroll
      for (int i = 0; i < 4; ++i) {
        ah[i] = *(const bf16x8*)&lAh[(wr + i * 16 + frow) * 64 + ks * 32 + fk];
        al[i] = *(const bf16x8*)&lAl[(wr + i * 16 + frow) * 64 + ks * 32 + fk];
      }
#pragma unroll
      for (int j = 0; j < 4; ++j) {
        bh[j] = *(const bf16x8*)&lBh[(wc + j * 16 + frow) * 64 + ks * 32 + fk];
        bl[j] = *(const bf16x8*)&lBl[(wc + j * 16 + frow) * 64 + ks * 32 + fk];
      }
#pragma unroll
      for (int i = 0; i < 4; ++i)
#pragma unroll
        for (int j = 0; j < 4; ++j) {
          part[i][j] = __builtin_amdgcn_mfma_f32_16x16x32_bf16(ah[i], bh[j], part[i][j], 0, 0, 0);
          part[i][j] = __builtin_amdgcn_mfma_f32_16x16x32_bf16(ah[i], bl[j], part[i][j], 0, 0, 0);
          part[i][j] = __builtin_amdgcn_mfma_f32_16x16x32_bf16(al[i], bh[j], part[i][j], 0, 0, 0);
        }
    }
  }
  const int crow0 = (lane >> 4) * 4;
  const int ccol = lane & 15;
#pragma unroll
  for (int i = 0; i < 4; ++i)
#pragma unroll
    for (int j = 0; j < 4; ++j) {
      int col = n0 + wc + j * 16 + ccol;
#pragma unroll
      for (int r = 0; r < 4; ++r) {
        float val = part[i][j][r];
        size_t off = (size_t)(m0 + wr + i * 16 + crow0 + r) * ldc + col;
        unsigned short hi = f32_to_bf16(val);
        OH[off] = hi;
        OL[off] = f32_to_bf16(val - bf16_to_f32(hi));
      }
    }
}

// ---------------- f32 GEMM (tiny Wig only); rowskip: skip tiles with (y & rowskip)==0 ----------------
__global__ __launch_bounds__(256) void gemm_f32_kernel(const float* __restrict__ A,
                                                       const float* __restrict__ Bw,
                                                       float* __restrict__ C,
                                                       int N, int K, float alpha, int rowskip) {
  if (rowskip && !(blockIdx.y & rowskip)) return;
  __shared__ __align__(16) float As[16][68];
  __shared__ __align__(16) float Bs[16][68];
  int n0 = blockIdx.x * 64;
  int m0 = blockIdx.y * 64;
  int tid = threadIdx.x;
  int tx = tid & 15, ty = tid >> 4;
  float acc[4][4] = {};
  for (int k0 = 0; k0 < K; k0 += 16) {
#pragma unroll
    for (int t = 0; t < 4; ++t) {
      int idx = tid + t * 256;
      int rr = idx >> 4;
      int kk = idx & 15;
      As[kk][rr] = A[(size_t)(m0 + rr) * K + (k0 + kk)];
      Bs[kk][rr] = (n0 + rr < N) ? Bw[(size_t)(n0 + rr) * K + (k0 + kk)] : 0.0f;
    }
    __syncthreads();
#pragma unroll
    for (int kk = 0; kk < 16; ++kk) {
      float4 a = *(const float4*)&As[kk][ty * 4];
      float4 b = *(const float4*)&Bs[kk][tx * 4];
      float av[4] = {a.x, a.y, a.z, a.w};
      float bv[4] = {b.x, b.y, b.z, b.w};
#pragma unroll
      for (int i = 0; i < 4; ++i)
#pragma unroll
        for (int j = 0; j < 4; ++j) acc[i][j] += av[i] * bv[j];
    }
    __syncthreads();
  }
#pragma unroll
  for (int i = 0; i < 4; ++i) {
    int m = m0 + ty * 4 + i;
#pragma unroll
    for (int j = 0; j < 4; ++j) {
      int n = n0 + tx * 4 + j;
      if (n < N) C[(size_t)m * N + n] = alpha * acc[i][j];
    }
  }
}

// ---------------- RoPE on split Q (in place, [b,h,s,192]) + k_rope -> Krh/Krl ----------------
__global__ __launch_bounds__(64) void rope_split_kernel(unsigned short* __restrict__ Qh,
                                                        unsigned short* __restrict__ Ql,
                                                        const float* __restrict__ KVA,
                                                        unsigned short* __restrict__ Krh,
                                                        unsigned short* __restrict__ Krl,
                                                        const int* __restrict__ POS) {
  int t = blockIdx.x;  // b*S + s
  int tid = threadIdx.x;
  int b = t >> 11, s = t & 2047;
  __shared__ float cs[32], sn[32];
  if (tid < 32) {
    int pos = POS[t];
    double inv = pow(10000.0, -((double)(2 * tid) / 64.0));
    float ang = (float)pos * (float)inv;
    cs[tid] = cosf(ang);
    sn[tid] = sinf(ang);
  }
  __syncthreads();
  if (tid < 32) {
    const float* kr = KVA + (size_t)t * (kKvLora + kDR) + kKvLora;
    float x1 = kr[tid], x2 = kr[32 + tid];
    float y1 = x1 * cs[tid] - x2 * sn[tid];
    float y2 = x2 * cs[tid] + x1 * sn[tid];
    unsigned short h1 = f32_to_bf16(y1);
    Krh[(size_t)t * 64 + tid] = h1;
    Krl[(size_t)t * 64 + tid] = f32_to_bf16(y1 - bf16_to_f32(h1));
    unsigned short h2 = f32_to_bf16(y2);
    Krh[(size_t)t * 64 + 32 + tid] = h2;
    Krl[(size_t)t * 64 + 32 + tid] = f32_to_bf16(y2 - bf16_to_f32(h2));
  }
  for (int it = tid; it < kH * 32; it += 64) {
    int h = it >> 5, i = it & 31;
    size_t base = ((size_t)((b * 16 + h) * 2048 + s)) * 192 + 128;
    float x1 = bf16_to_f32(Qh[base + i]) + bf16_to_f32(Ql[base + i]);
    float x2 = bf16_to_f32(Qh[base + 32 + i]) + bf16_to_f32(Ql[base + 32 + i]);
    float y1 = x1 * cs[i] - x2 * sn[i];
    float y2 = x2 * cs[i] + x1 * sn[i];
    unsigned short h1 = f32_to_bf16(y1);
    Qh[base + i] = h1;
    Ql[base + i] = f32_to_bf16(y1 - bf16_to_f32(h1));
    unsigned short h2 = f32_to_bf16(y2);
    Qh[base + 32 + i] = h2;
    Ql[base + 32 + i] = f32_to_bf16(y2 - bf16_to_f32(h2));
  }
}

// ---------------- MFMA indexer scores: one 64x64 tile per block (rows q>=1024 only) ----------------
__global__ __launch_bounds__(256) void isc_mfma_kernel(const unsigned short* __restrict__ QIKH,
                                                       const unsigned short* __restrict__ QIKL,
                                                       const float* __restrict__ WGT,
                                                       float* __restrict__ ISC) {
  const int qt = blockIdx.y + 16;
  const int kt = blockIdx.x;
  if (kt > qt) return;
  const int b = blockIdx.z;
  const int q0 = qt * 64, k0 = kt * 64;
  const int tid = threadIdx.x, wave = tid >> 6, lane = tid & 63;
  const int fr = lane & 15, fg = lane >> 4;

  __shared__ unsigned short KiH[4 * 64 * 40], KiL[4 * 64 * 40];
  __shared__ float wgs[64 * 8];

  {
    int key = tid >> 2, sub = (tid & 3) * 8;
    size_t rb = (size_t)(b * kS + k0 + key) * 1152 + 1024;
#pragma unroll
    for (int kc = 0; kc < 4; ++kc) {
      *(bf16x8*)&KiH[kc * 2560 + key * 40 + sub] = *(const bf16x8*)&QIKH[rb + kc * 32 + sub];
      *(bf16x8*)&KiL[kc * 2560 + key * 40 + sub] = *(const bf16x8*)&QIKL[rb + kc * 32 + sub];
    }
#pragma unroll
    for (int t = 0; t < 2; ++t) {
      int i = t * 256 + tid;
      wgs[i] = WGT[(size_t)(b * kS + q0 + (i >> 3)) * kHI + (i & 7)];
    }
  }
  const size_t qrow = (size_t)(b * kS + q0 + wave * 16 + fr) * 1152;
  f32x4 sacc[4];
  const f32x4 vzero = {0.f, 0.f, 0.f, 0.f};
#pragma unroll
  for (int j = 0; j < 4; ++j) sacc[j] = vzero;

  bf16x8 qAh[4], qAl[4], qBh[4], qBl[4];
#define LOADQ(DH_, DL_, H_)                                                     \
  _Pragma("unroll") for (int kc = 0; kc < 4; ++kc) {                            \
    DH_[kc] = *(const bf16x8*)&QIKH[qrow + (H_)*128 + kc * 32 + fg * 8];        \
    DL_[kc] = *(const bf16x8*)&QIKL[qrow + (H_)*128 + kc * 32 + fg * 8];        \
  }
  LOADQ(qAh, qAl, 0)
  __syncthreads();
#define MFMA_HEAD(QH_, QL_, H_)                                                 \
  {                                                                             \
    f32x4 acc[4];                                                               \
    _Pragma("unroll") for (int j = 0; j < 4; ++j) acc[j] = vzero;               \
    _Pragma("unroll") for (int kc = 0; kc < 4; ++kc) {                          \
      _Pragma("unroll") for (int j = 0; j < 4; ++j) {                           \
        bf16x8 kh = *(const bf16x8*)&KiH[kc * 2560 + (j * 16 + fr) * 40 + fg * 8]; \
        bf16x8 kl = *(const bf16x8*)&KiL[kc * 2560 + (j * 16 + fr) * 40 + fg * 8]; \
        acc[j] = __builtin_amdgcn_mfma_f32_16x16x32_bf16(QH_[kc], kh, acc[j], 0, 0, 0); \
        acc[j] = __builtin_amdgcn_mfma_f32_16x16x32_bf16(QH_[kc], kl, acc[j], 0, 0, 0); \
        acc[j] = __builtin_amdgcn_mfma_f32_16x16x32_bf16(QL_[kc], kh, acc[j], 0, 0, 0); \
      }                                                                         \
    }                                                                           \
    float wv[4];                                                                \
    _Pragma("unroll") for (int r = 0; r < 4; ++r)                               \
        wv[r] = wgs[(wave * 16 + fg * 4 + r) * 8 + (H_)];                       \
    _Pragma("unroll") for (int j = 0; j < 4; ++j)                               \
      _Pragma("unroll") for (int r = 0; r < 4; ++r)                             \
        sacc[j][r] += fmaxf(acc[j][r], 0.0f) * wv[r];                           \
  }
#pragma unroll
  for (int hp = 0; hp < 4; ++hp) {
    int h0 = hp * 2;
    LOADQ(qBh, qBl, h0 + 1)
    MFMA_HEAD(qAh, qAl, h0)
    if (hp < 3) LOADQ(qAh, qAl, h0 + 2)
    MFMA_HEAD(qBh, qBl, h0 + 1)
  }
#undef LOADQ
#undef MFMA_HEAD
#pragma unroll
  for (int r = 0; r < 4; ++r) {
    size_t ob = (size_t)(b * kS + q0 + wave * 16 + fg * 4 + r) * kS + k0;
#pragma unroll
    for (int j = 0; j < 4; ++j) ISC[ob + j * 16 + fr] = sacc[j][r];
  }
}

// ---------------- exact stable top-k (parallel scans; integer-exact) ----------------
__global__ __launch_bounds__(256) void topk_kernel(const float* __restrict__ ISC,
                                                   unsigned* __restrict__ SEL) {
  int row = blockIdx.x;
  int q = row & (kS - 1);
  int L = q + 1;
  unsigned* selrow = SEL + (size_t)row * (kS / 32);
  int tid = threadIdx.x;
  if (L <= kTopK) {
    if (tid < kS / 32) {
      int base = tid * 32;
      unsigned w;
      if (base + 32 <= L) w = 0xFFFFFFFFu;
      else if (base >= L) w = 0u;
      else w = (1u << (L - base)) - 1u;
      selrow[tid] = w;
    }
    return;
  }
  __shared__ unsigned keys[kS];
  __shared__ unsigned hist[256];
  __shared__ unsigned sfx[256];
  __shared__ unsigned msk[kS / 32];
  __shared__ unsigned pick[2];
  if (tid < kS / 32) msk[tid] = 0u;
  const float* x = ISC + (size_t)row * kS;
  for (int k = tid; k < L; k += 256) {
    unsigned u = __float_as_uint(x[k]);
    keys[k] = (u & 0x80000000u) ? ~u : (u | 0x80000000u);
  }
  __syncthreads();
  unsigned prefix = 0u;
  int r = kTopK;
  for (int shift = 24; shift >= 0; shift -= 8) {
    hist[tid] = 0u;
    __syncthreads();
    unsigned hm = (shift == 24) ? 0u : (0xFFFFFFFFu << (shift + 8));
    for (int k = tid; k < L; k += 256) {
      unsigned key = keys[k];
      if ((key & hm) == (prefix & hm)) atomicAdd(&hist[(key >> shift) & 255u], 1u);
    }
    __syncthreads();
    // parallel suffix-sum bucket select: T(b) = sum_{b'>=b} hist[b'];
    // pick b with T(b+1) < r <= T(b); new rank = r - T(b+1). (== serial walk)
    sfx[tid] = hist[tid];
    __syncthreads();
#pragma unroll
    for (int step = 1; step < 256; step <<= 1) {
      unsigned add = (tid + step < 256) ? sfx[tid + step] : 0u;
      __syncthreads();
      sfx[tid] += add;
      __syncthreads();
    }
    {
      unsigned Tb = sfx[tid];
      unsigned Tb1 = (tid < 255) ? sfx[tid + 1] : 0u;
      if (Tb1 < (unsigned)r && (unsigned)r <= Tb) {
        pick[0] = (unsigned)tid;
        pick[1] = (unsigned)r - Tb1;
      }
    }
    __syncthreads();
    prefix |= pick[0] << shift;
    r = (int)pick[1];
    __syncthreads();
  }
  unsigned T = prefix;
  int ties_take = r;
  int base = tid * 8;
  int cnt = 0;
#pragma unroll
  for (int j = 0; j < 8; ++j) {
    int k = base + j;
    if (k < L && keys[k] == T) ++cnt;
  }
  hist[tid] = (unsigned)cnt;
  __syncthreads();
  // parallel exclusive prefix sum of hist (integer-exact)
  sfx[tid] = hist[tid];
  __syncthreads();
#pragma unroll
  for (int step = 1; step < 256; step <<= 1) {
    unsigned add = (tid >= step) ? sfx[tid - step] : 0u;
    __syncthreads();
    sfx[tid] += add;
    __syncthreads();
  }
  int trank = (tid == 0) ? 0 : (int)sfx[tid - 1];
  unsigned bits = 0u;
#pragma unroll
  for (int j = 0; j < 8; ++j) {
    int k = base + j;
    if (k < L) {
      unsigned key = keys[k];
      bool s;
      if (key > T) s = true;
      else if (key == T) { s = trank < ties_take; ++trank; }
      else s = false;
      if (s) bits |= (1u << j);
    }
  }
  atomicOr(&msk[tid >> 2], bits << ((tid & 3) * 8));
  __syncthreads();
  if (tid < kS / 32) selrow[tid] = msk[tid];
}

// ---------------- MFMA flash attention (round-10 structure; __expf softmax) ----------------
__global__ __launch_bounds__(256) void attn_mfma_kernel(const unsigned short* __restrict__ Qh,
                                                        const unsigned short* __restrict__ Ql,
                                                        const unsigned short* __restrict__ Knh,
                                                        const unsigned short* __restrict__ Knl,
                                                        const unsigned short* __restrict__ Krh,
                                                        const unsigned short* __restrict__ Krl,
                                                        const unsigned short* __restrict__ Vth,
                                                        const unsigned short* __restrict__ Vtl,
                                                        const unsigned* __restrict__ SEL,
                                                        unsigned short* __restrict__ CTXB) {
  const int flat = blockIdx.x;
  const int qt = 31 - (flat >> 4);        // longest blocks dispatch first
  const int h = flat & 15;
  const int b = blockIdx.y;
  const int q0 = qt * 64;
  const int tid = threadIdx.x, wave = tid >> 6, lane = tid & 63;
  const int fr = lane & 15, fg = lane >> 4;
  const float scale = 0.07216878364870323f;  // 1/sqrt(192)

  __shared__ unsigned short KsH[2 * 64 * 40], KsL[2 * 64 * 40];  // double-buffered K chunk
  __shared__ unsigned short Ph[64 * 72], Pl[64 * 72];
  __shared__ unsigned short Vs[128 * 72];
  __shared__ unsigned selw[64][2];

  bf16x8 qh[6], ql[6];
  {
    const size_t qbase = ((size_t)((b * 16 + h) * 2048 + q0 + wave * 16 + fr)) * 192;
#pragma unroll
    for (int kc = 0; kc < 6; ++kc) {
      qh[kc] = *(const bf16x8*)&Qh[qbase + kc * 32 + fg * 8];
      ql[kc] = *(const bf16x8*)&Ql[qbase + kc * 32 + fg * 8];
    }
  }
  float m_run[4], l_run[4];
#pragma unroll
  for (int r = 0; r < 4; ++r) { m_run[r] = kNeg; l_run[r] = 0.0f; }
  f32x4 O[8];
  const f32x4 vzero = {0.f, 0.f, 0.f, 0.f};
#pragma unroll
  for (int j = 0; j < 8; ++j) O[j] = vzero;

  const int key = tid >> 2, sub = (tid & 3) * 8;
  const size_t knbase = (size_t)((b * 16 + h) * 2048) * 128;
  const size_t krbase = (size_t)(b * 2048) * 64;
  const size_t vbase0 = ((size_t)((b * 16 + h) * 128)) * 2048;

  const int nkt = qt + 1;
  for (int kt = 0; kt < nkt; ++kt) {
    const int k0 = kt * 64;
    const size_t vbase = vbase0 + k0;
    unsigned selreg = 0;
    if (tid < 128)
      selreg = SEL[(size_t)(b * kS + q0 + (tid >> 1)) * (kS / 32) + (k0 >> 5) + (tid & 1)];
    bf16x8 kh_pre[2], kl_pre[2];
    {
      size_t src = knbase + (size_t)(k0 + key) * 128 + sub;   // chunk 0
      kh_pre[0] = *(const bf16x8*)&Knh[src];
      kl_pre[0] = *(const bf16x8*)&Knl[src];
    }
    bf16x8 vpre[4];
#pragma unroll
    for (int it = 0; it < 4; ++it) {
      int idx = it * 256 + tid;
      int dv = idx >> 3, ks8 = (idx & 7) * 8;
      vpre[it] = *(const bf16x8*)&Vth[vbase + (size_t)dv * 2048 + ks8];
    }
    __syncthreads();  // B1: prev tile's Ks(last chunk)/Vs/selw reads done
    if (tid < 128) selw[tid >> 1][tid & 1] = selreg;
    f32x4 acc[4];
#pragma unroll
    for (int j = 0; j < 4; ++j) acc[j] = vzero;
#pragma unroll
    for (int kc = 0; kc < 6; ++kc) {
      const int buf = (kc & 1) * 2560;
      *(bf16x8*)&KsH[buf + key * 40 + sub] = kh_pre[kc & 1];
      *(bf16x8*)&KsL[buf + key * 40 + sub] = kl_pre[kc & 1];
      if (kc < 5) {   // prefetch next chunk (hidden under barrier+MFMA)
        if (kc + 1 < 4) {
          size_t src = knbase + (size_t)(k0 + key) * 128 + (kc + 1) * 32 + sub;
          kh_pre[(kc + 1) & 1] = *(const bf16x8*)&Knh[src];
          kl_pre[(kc + 1) & 1] = *(const bf16x8*)&Knl[src];
        } else {
          size_t src = krbase + (size_t)(k0 + key) * 64 + (kc - 3) * 32 + sub;
          kh_pre[(kc + 1) & 1] = *(const bf16x8*)&Krh[src];
          kl_pre[(kc + 1) & 1] = *(const bf16x8*)&Krl[src];
        }
      }
      __syncthreads();  // single barrier per chunk (double-buffered Ks)
#pragma unroll
      for (int j = 0; j < 4; ++j) {
        bf16x8 kh = *(const bf16x8*)&KsH[buf + (j * 16 + fr) * 40 + fg * 8];
        bf16x8 kl = *(const bf16x8*)&KsL[buf + (j * 16 + fr) * 40 + fg * 8];
        acc[j] = __builtin_amdgcn_mfma_f32_16x16x32_bf16(qh[kc], kh, acc[j], 0, 0, 0);
        acc[j] = __builtin_amdgcn_mfma_f32_16x16x32_bf16(qh[kc], kl, acc[j], 0, 0, 0);
        acc[j] = __builtin_amdgcn_mfma_f32_16x16x32_bf16(ql[kc], kh, acc[j], 0, 0, 0);
      }
    }
    float p[4][4];
    float fsc[4];
#pragma unroll
    for (int r = 0; r < 4; ++r) {
      int row = wave * 16 + fg * 4 + r;
      float sv[4];
      float vmax = kNeg;
#pragma unroll
      for (int j = 0; j < 4; ++j) {
        int col = j * 16 + fr;
        bool bit = (selw[row][col >> 5] >> (col & 31)) & 1u;
        float s = bit ? acc[j][r] * scale : kNeg;
        sv[j] = s;
        vmax = fmaxf(vmax, s);
      }
#pragma unroll
      for (int m = 1; m <= 8; m <<= 1) vmax = fmaxf(vmax, __shfl_xor(vmax, m, 64));
      float newm = fmaxf(m_run[r], vmax);
      float sum = 0.0f;
#pragma unroll
      for (int j = 0; j < 4; ++j) {
        float pp = (sv[j] < -1e29f) ? 0.0f : __expf(sv[j] - newm);
        p[j][r] = pp;
        sum += pp;
      }
#pragma unroll
      for (int m = 1; m <= 8; m <<= 1) sum += __shfl_xor(sum, m, 64);
      fsc[r] = __expf(m_run[r] - newm);
      l_run[r] = l_run[r] * fsc[r] + sum;
      m_run[r] = newm;
    }
#pragma unroll
    for (int j = 0; j < 8; ++j)
#pragma unroll
      for (int r = 0; r < 4; ++r) O[j][r] *= fsc[r];
#pragma unroll
    for (int r = 0; r < 4; ++r) {
      int row = wave * 16 + fg * 4 + r;
#pragma unroll
      for (int j = 0; j < 4; ++j) {
        int col = j * 16 + fr;
        float pp = p[j][r];
        unsigned short hi = f32_to_bf16(pp);
        Ph[row * 72 + col] = hi;
        Pl[row * 72 + col] = f32_to_bf16(pp - bf16_to_f32(hi));
      }
    }
#pragma unroll
    for (int it = 0; it < 4; ++it) {
      int idx = it * 256 + tid;
      int dv = idx >> 3, ks8 = (idx & 7) * 8;
      *(bf16x8*)&Vs[dv * 72 + ks8] = vpre[it];
    }
#pragma unroll
    for (int it = 0; it < 4; ++it) {
      int idx = it * 256 + tid;
      int dv = idx >> 3, ks8 = (idx & 7) * 8;
      vpre[it] = *(const bf16x8*)&Vtl[vbase + (size_t)dv * 2048 + ks8];
    }
    __syncthreads();  // B3: Vs (hi) ready
#pragma unroll
    for (int kk = 0; kk < 2; ++kk) {
      bf16x8 pah = *(const bf16x8*)&Ph[(wave * 16 + fr) * 72 + kk * 32 + fg * 8];
      bf16x8 pal = *(const bf16x8*)&Pl[(wave * 16 + fr) * 72 + kk * 32 + fg * 8];
#pragma unroll
      for (int j = 0; j < 8; ++j) {
        bf16x8 vb = *(const bf16x8*)&Vs[(j * 16 + fr) * 72 + kk * 32 + fg * 8];
        O[j] = __builtin_amdgcn_mfma_f32_16x16x32_bf16(pah, vb, O[j], 0, 0, 0);
        O[j] = __builtin_amdgcn_mfma_f32_16x16x32_bf16(pal, vb, O[j], 0, 0, 0);
      }
    }
    __syncthreads();  // B4: PV1 Vs reads done
#pragma unroll
    for (int it = 0; it < 4; ++it) {
      int idx = it * 256 + tid;
      int dv = idx >> 3, ks8 = (idx & 7) * 8;
      *(bf16x8*)&Vs[dv * 72 + ks8] = vpre[it];
    }
    __syncthreads();  // B5: Vs (lo) ready
#pragma unroll
    for (int kk = 0; kk < 2; ++kk) {
      bf16x8 pah = *(const bf16x8*)&Ph[(wave * 16 + fr) * 72 + kk * 32 + fg * 8];
#pragma unroll
      for (int j = 0; j < 8; ++j) {
        bf16x8 vb = *(const bf16x8*)&Vs[(j * 16 + fr) * 72 + kk * 32 + fg * 8];
        O[j] = __builtin_amdgcn_mfma_f32_16x16x32_bf16(pah, vb, O[j], 0, 0, 0);
      }
    }
  }
#pragma unroll
  for (int r = 0; r < 4; ++r) {
    float inv = 1.0f / l_run[r];
    float vals[8];
    float am = 0.0f;
#pragma unroll
    for (int j = 0; j < 8; ++j) {
      vals[j] = O[j][r] * inv;
      am = fmaxf(am, fabsf(vals[j]));
    }
#pragma unroll
    for (int m = 1; m <= 8; m <<= 1) am = fmaxf(am, __shfl_xor(am, m, 64));
    am = fmaxf(am, 1e-4f);
    float s = act_scale_from_amax(am);
    size_t obase = (size_t)(b * kS + q0 + wave * 16 + fg * 4 + r) * 2048 + h * 128;
#pragma unroll
    for (int j = 0; j < 8; ++j)
      CTXB[obase + j * 16 + fr] = f32_to_bf16(fp8_e4m3_qdq(clamp448(vals[j] / s)) * s);
  }
}

extern "C" void kernel_launch(void* const* d_in, const int* in_sizes, int n_in,
                              void* d_out, int out_size, void* d_ws, size_t ws_size,
                              hipStream_t stream) {
  (void)in_sizes; (void)n_in;

  const float* hidden = (const float*)d_in[0];
  const float* Wqa    = (const float*)d_in[1];
  const float* qnw    = (const float*)d_in[2];
  const float* Wqb    = (const float*)d_in[3];
  const float* Wkva   = (const float*)d_in[4];
  const float* kvnw   = (const float*)d_in[5];
  const float* Wkvb   = (const float*)d_in[6];
  const float* Wiq    = (const float*)d_in[7];
  const float* Wik    = (const float*)d_in[8];
  const float* Wig    = (const float*)d_in[9];
  const float* Wo     = (const float*)d_in[10];
  const int*   pos    = (const int*)d_in[11];
  char* ws = (char*)d_ws;
  float* out = (float*)d_out;

  if (ws_size < WS_NEED) {
    fill_kernel<<<dim3((out_size + 255) / 256), dim3(256), 0, stream>>>(out, out_size, 54321.0f);
    return;
  }

  float* scbase = (float*)(ws + OFF_SC);
  float* scWqa  = scbase + 0;
  float* scWqb  = scbase + 128;
  float* scWkva = scbase + 320;
  float* scWkvb = scbase + 400;
  float* scWo   = scbase + 528;
  unsigned* sel = (unsigned*)(ws + OFF_SEL_B);
  float* wgt    = (float*)(ws + OFF_WGT_B);
  unsigned short* krh = (unsigned short*)(ws + OFF_KRH_B);
  unsigned short* krl = (unsigned short*)(ws + OFF_KRL_B);
  unsigned short* wo_b = (unsigned short*)(ws + OFF_WOB_B);

  unsigned short* h_hi  = (unsigned short*)(ws + A_HHI);
  unsigned short* h_lo  = (unsigned short*)(ws + A_HLO);
  unsigned short* wqk_h = (unsigned short*)(ws + A_WQKH);
  unsigned short* wqk_l = (unsigned short*)(ws + A_WQKL);
  unsigned short* qik_h = (unsigned short*)(ws + A_QIKH);
  unsigned short* qik_l = (unsigned short*)(ws + A_QIKL);
  float* isc = (float*)(ws + A_ISC);

  unsigned short* hidq_b = (unsigned short*)(ws + B_HIDQ);
  unsigned short* wqa_b  = (unsigned short*)(ws + B_WQA);
  unsigned short* wqb_b  = (unsigned short*)(ws + B_WQB);
  unsigned short* wkva_b = (unsigned short*)(ws + B_WKVA);
  unsigned short* wkvb_b = (unsigned short*)(ws + B_WKVB);
  float* qa_f   = (float*)(ws + B_QAF);
  unsigned short* qa_b  = (unsigned short*)(ws + B_QAB);
  float* kva    = (float*)(ws + B_KVA);
  unsigned short* ckv_b = (unsigned short*)(ws + B_CKV);
  unsigned short* q_h   = (unsigned short*)(ws + B_QH);
  unsigned short* q_l   = (unsigned short*)(ws + B_QL);
  unsigned short* kn_h  = (unsigned short*)(ws + B_KNH);
  unsigned short* kn_l  = (unsigned short*)(ws + B_KNL);
  unsigned short* v_th  = (unsigned short*)(ws + B_VTH);
  unsigned short* v_tl  = (unsigned short*)(ws + B_VTL);
  unsigned short* ctx_b = (unsigned short*)(ws + B_CTXB);

  // ---------- Phase A: indexer + top-k ----------
  hidden_prep_kernel<<<dim3(16384), dim3(256), 0, stream>>>(hidden, h_hi, h_lo, hidq_b);
  split_bf16x2_kernel<<<dim3(8192),  dim3(256), 0, stream>>>(Wiq, wqk_h, wqk_l, (size_t)kHI * kDI * kDH);
  split_bf16x2_kernel<<<dim3(1024),  dim3(256), 0, stream>>>(Wik, wqk_h + (size_t)1024 * kDH, wqk_l + (size_t)1024 * kDH, (size_t)kDI * kDH);
  gemm_f32_kernel<<<dim3(1, 64), dim3(256), 0, stream>>>(hidden, Wig, wgt, kHI, kDH, 0.35355339059327373f, 16);
  mfma_gemm3_kernel<<<dim3(9, 32), dim3(256), 0, stream>>>(h_hi, h_lo, wqk_h, wqk_l, qik_h, qik_l, kDH, 1152);
  isc_mfma_kernel<<<dim3(32, 16, kB), dim3(256), 0, stream>>>(qik_h, qik_l, wgt, isc);
  topk_kernel<<<dim3(kNTok), dim3(256), 0, stream>>>(isc, sel);

  // ---------- Phase B: fp8-path linears on MFMA ----------
  fused_weight5_kernel<<<dim3(784), dim3(256), 0, stream>>>(Wqa, Wqb, Wkva, Wkvb, Wo, scbase,
                                                            wqa_b, wqb_b, wkva_b, wkvb_b, wo_b);

  // q_a -> rms -> q (bf16 hi/lo, [b,h,s,192])
  mfma_gemm_kernel<0, true><<<dim3(8, 32), dim3(256), 0, stream>>>(hidq_b, wqa_b, scWqa, qa_f, nullptr, nullptr, nullptr, nullptr, 1024, kDH, 1024);
  rms_qdq_kernel<<<dim3(kNTok), dim3(256), 0, stream>>>(qa_f, qnw, qa_b, kQLora, kQLora, kQLora);
  mfma_gemm_kernel<1, true><<<dim3(24, 32), dim3(256), 0, stream>>>(qa_b, wqb_b, scWqb, nullptr, q_h, q_l, nullptr, nullptr, 3072, kQLora, 3072);
  // kv_a -> rms -> kv (split to Kn hi/lo [b,h,s,128] + V^T hi/lo [b,h,dv,s])
  mfma_gemm_kernel<0, true><<<dim3(5, 32), dim3(256), 0, stream>>>(hidq_b, wkva_b, scWkva, kva, nullptr, nullptr, nullptr, nullptr, 576, kDH, 576);
  rms_qdq_kernel<<<dim3(kNTok), dim3(256), 0, stream>>>(kva, kvnw, ckv_b, kKvLora, kKvLora + kDR, kKvLora);
  rope_split_kernel<<<dim3(kNTok), dim3(64), 0, stream>>>(q_h, q_l, kva, krh, krl, pos);
  mfma_gemm_kernel<2, true><<<dim3(32, 32), dim3(256), 0, stream>>>(ckv_b, wkvb_b, scWkvb, nullptr, kn_h, kn_l, v_th, v_tl, 4096, kKvLora, 4096);

  // ---------- attention (fused ctx fp8-qdq) + output ----------
  attn_mfma_kernel<<<dim3(512, kB), dim3(256), 0, stream>>>(q_h, q_l, kn_h, kn_l, krh, krl, v_th, v_tl, sel, ctx_b);
  mfma_gemm_kernel<0, true><<<dim3(16, 32), dim3(256), 0, stream>>>(ctx_b, wo_b, scWo, out, nullptr, nullptr, nullptr, nullptr, kDH, kH * kDV, 2048);
}

// Round 18
// 950.226 us; speedup vs baseline: 1.3401x; 1.0009x over previous
//
#include <hip/hip_runtime.h>
#include <math.h>

namespace {
constexpr int kB = 2, kS = 2048, kDH = 2048, kH = 16, kDN = 128, kDR = 64, kDV = 128;
constexpr int kKvLora = 512, kQLora = 1024, kHI = 8, kDI = 128, kTopK = 1024;
constexpr int kNTok = kB * kS;             // 4096
constexpr float kNeg = -1e30f;

// ---- fixed region (bytes) ----
constexpr size_t OFF_SC    = 0;                          // 784 f32 scales
constexpr size_t OFF_SEL_B = 4096;                       // 1 MB
constexpr size_t OFF_WGT_B = OFF_SEL_B + 1048576;        // 128 KB
constexpr size_t OFF_KRH_B = OFF_WGT_B + 131072;         // 512 KB
constexpr size_t OFF_KRL_B = OFF_KRH_B + 524288;         // 512 KB
constexpr size_t OFF_WOB_B = OFF_KRL_B + 524288;         // 8 MB  (Wo bf16)
constexpr size_t POOL      = OFF_WOB_B + 8388608;        // 10,620,928
// ---- phase B core ----
constexpr size_t B_HIDQ = POOL;                 // 16 MB bf16
constexpr size_t B_WQA  = POOL + 16777216;      // 4 MB
constexpr size_t B_WQB  = POOL + 20971520;      // 6 MB
constexpr size_t B_WKVA = POOL + 27262976;      // 2.5 MB
constexpr size_t B_WKVB = POOL + 29884416;      // 4 MB
constexpr size_t B_QAF  = POOL + 34078720;      // 16 MB f32
constexpr size_t B_QAB  = POOL + 50855936;      // 8 MB bf16
constexpr size_t B_KVA  = POOL + 59244544;      // 9.4 MB f32
constexpr size_t B_CKV  = POOL + 68681728;      // 4 MB bf16
constexpr size_t B_QH   = POOL + 72876032;      // 24 MB bf16
constexpr size_t B_QL   = POOL + 98041856;      // 24 MB bf16
constexpr size_t B_KNH  = POOL + 123207680;     // 16 MB
constexpr size_t B_KNL  = POOL + 139984896;     // 16 MB
constexpr size_t B_VTH  = POOL;                 // 16 MB (over dead hidq)
constexpr size_t B_VTL  = POOL + 34078720;      // 16 MB (over dead qa_f)
constexpr size_t B_CTXB = POOL + 50855936;      // 16 MB (over dead qa_b + kva)
// ---- phase A (indexer) ----
constexpr size_t A_HHI  = POOL + 16777216;      // 16 MB bf16
constexpr size_t A_HLO  = POOL + 33554432;      // 16 MB bf16
constexpr size_t A_WQKH = POOL + 50331648;      // 4,718,592
constexpr size_t A_WQKL = POOL + 55050240;      // 4,718,592
constexpr size_t A_QIKH = POOL + 59768832;      // 9,437,184 bf16 [4096][1152]
constexpr size_t A_QIKL = POOL + 69206016;      // 9,437,184
constexpr size_t A_ISC  = POOL + 78643200;      // 33,554,432 f32 [4096][2048]
constexpr size_t WS_NEED = POOL + 156762112;    // 167,383,040 B (known-good)
} // namespace

typedef __attribute__((ext_vector_type(4))) float f32x4;
typedef __attribute__((ext_vector_type(8))) short bf16x8;
typedef __attribute__((address_space(1))) const void gvoid;
typedef __attribute__((address_space(3))) void lvoid;

// Exact e4m3fn round-to-nearest-even quant-dequant for |x| <= 448 (incl. subnormals).
__device__ __forceinline__ float fp8_e4m3_qdq(float x) {
  float ax = fabsf(x);
  int e;
  (void)frexpf(ax, &e);
  int ee = e - 1;
  if (ee < -6) ee = -6;
  float q = ldexpf(1.0f, ee - 3);
  float y = rintf(ax / q) * q;
  return (x < 0.0f) ? -y : y;
}

__device__ __forceinline__ float act_scale_from_amax(float amax) {
  float t = amax / 448.0f;
  unsigned u = __float_as_uint(t);
  int e = (int)((u >> 23) & 255u) - 127;
  if (u & 0x7fffffu) e += 1;
  return __uint_as_float((unsigned)(e + 127) << 23);
}

__device__ __forceinline__ float clamp448(float v) {
  return fminf(fmaxf(v, -448.0f), 448.0f);
}

__device__ __forceinline__ unsigned short f32_to_bf16(float f) {
  unsigned u = __float_as_uint(f);
  unsigned r = (u + 0x7FFFu + ((u >> 16) & 1u)) >> 16;
  return (unsigned short)r;
}
__device__ __forceinline__ float bf16_to_f32(unsigned short h) {
  return __uint_as_float((unsigned)h << 16);
}

__global__ __launch_bounds__(256) void fill_kernel(float* p, int n, float v) {
  int i = blockIdx.x * 256 + threadIdx.x;
  if (i < n) p[i] = v;
}

// ---------------- fused hidden prep: hi/lo split + fp8-qdq -> bf16 (one read) ----------------
__global__ __launch_bounds__(256) void hidden_prep_kernel(const float* __restrict__ X,
                                                          unsigned short* __restrict__ HI,
                                                          unsigned short* __restrict__ LO,
                                                          unsigned short* __restrict__ QB) {
  int wid = blockIdx.x * 4 + (threadIdx.x >> 6);
  int lane = threadIdx.x & 63;
  const float* x = X + (size_t)wid * 128;
  float v0 = x[lane], v1 = x[lane + 64];
  size_t o0 = (size_t)wid * 128 + lane, o1 = o0 + 64;
  unsigned short h0 = f32_to_bf16(v0);
  HI[o0] = h0; LO[o0] = f32_to_bf16(v0 - bf16_to_f32(h0));
  unsigned short h1 = f32_to_bf16(v1);
  HI[o1] = h1; LO[o1] = f32_to_bf16(v1 - bf16_to_f32(h1));
  float am = fmaxf(fabsf(v0), fabsf(v1));
#pragma unroll
  for (int m = 32; m >= 1; m >>= 1) am = fmaxf(am, __shfl_xor(am, m, 64));
  am = fmaxf(am, 1e-4f);
  float s = act_scale_from_amax(am);
  QB[o0] = f32_to_bf16(fp8_e4m3_qdq(clamp448(v0 / s)) * s);
  QB[o1] = f32_to_bf16(fp8_e4m3_qdq(clamp448(v1 / s)) * s);
}

// ---------------- merged weight prep: 5 weights, one launch (per-block math identical) ----------------
__global__ __launch_bounds__(256) void fused_weight5_kernel(const float* __restrict__ W0,
                                                            const float* __restrict__ W1,
                                                            const float* __restrict__ W2,
                                                            const float* __restrict__ W3,
                                                            const float* __restrict__ W4,
                                                            float* __restrict__ SCB,
                                                            unsigned short* __restrict__ B0,
                                                            unsigned short* __restrict__ B1,
                                                            unsigned short* __restrict__ B2,
                                                            unsigned short* __restrict__ B3,
                                                            unsigned short* __restrict__ B4) {
  int bid = blockIdx.x;
  const float* W; unsigned short* WB; float* SC; int O, I, KBX, loc;
  if (bid < 128)      { W = W0; WB = B0; SC = SCB + 0;   O = 1024; I = 2048; KBX = 16; loc = bid; }
  else if (bid < 320) { W = W1; WB = B1; SC = SCB + 128; O = 3072; I = 1024; KBX = 8;  loc = bid - 128; }
  else if (bid < 400) { W = W2; WB = B2; SC = SCB + 320; O = 576;  I = 2048; KBX = 16; loc = bid - 320; }
  else if (bid < 528) { W = W3; WB = B3; SC = SCB + 400; O = 4096; I = 512;  KBX = 4;  loc = bid - 400; }
  else                { W = W4; WB = B4; SC = SCB + 528; O = 2048; I = 2048; KBX = 16; loc = bid - 528; }
  int kb = loc % KBX, ob = loc / KBX;
  int bo = ob * 128, bi = kb * 128;
  int tid = threadIdx.x;
  __shared__ float red[256];
  __shared__ float s_scale;
  float am = 0.0f;
  for (int idx = tid; idx < 128 * 128; idx += 256) {
    int r = bo + (idx >> 7), c = bi + (idx & 127);
    if (r < O) am = fmaxf(am, fabsf(W[(size_t)r * I + c]));
  }
  red[tid] = am; __syncthreads();
  for (int s = 128; s >= 1; s >>= 1) {
    if (tid < s) red[tid] = fmaxf(red[tid], red[tid + s]);
    __syncthreads();
  }
  if (tid == 0) {
    float sc = fmaxf(red[0], 1e-4f) / 448.0f;
    SC[(size_t)ob * KBX + kb] = sc;
    s_scale = sc;
  }
  __syncthreads();
  float sc = s_scale;
  for (int idx = tid; idx < 128 * 128; idx += 256) {
    int r = bo + (idx >> 7), c = bi + (idx & 127);
    unsigned short v = 0;
    if (r < O) v = f32_to_bf16(fp8_e4m3_qdq(clamp448(W[(size_t)r * I + c] / sc)));
    WB[(size_t)r * I + c] = v;
  }
}

// ---------------- f32 -> bf16 hi/lo split ----------------
__global__ __launch_bounds__(256) void split_bf16x2_kernel(const float* __restrict__ X,
                                                           unsigned short* __restrict__ HI,
                                                           unsigned short* __restrict__ LO,
                                                           size_t n) {
  size_t i = (size_t)blockIdx.x * 256 + threadIdx.x;
  if (i >= n) return;
  float x = X[i];
  unsigned short h = f32_to_bf16(x);
  HI[i] = h;
  LO[i] = f32_to_bf16(x - bf16_to_f32(h));
}

// ---------------- fused RMSNorm + activation qdq -> bf16 (per row) ----------------
__global__ __launch_bounds__(256) void rms_qdq_kernel(const float* __restrict__ X,
                                                      const float* __restrict__ G,
                                                      unsigned short* __restrict__ Y,
                                                      int C, int xs, int ys) {
  int row = blockIdx.x, tid = threadIdx.x;
  __shared__ float xr[1024];
  __shared__ float red[256];
  const float* x = X + (size_t)row * xs;
  float ssq = 0.0f;
  for (int i = tid; i < C; i += 256) { float v = x[i]; xr[i] = v; ssq += v * v; }
  red[tid] = ssq; __syncthreads();
  for (int s = 128; s >= 1; s >>= 1) { if (tid < s) red[tid] += red[tid + s]; __syncthreads(); }
  float inv = 1.0f / sqrtf(red[0] / (float)C + 1e-6f);
  __syncthreads();
  int wv = tid >> 6, lane = tid & 63;
  for (int blk = wv; blk < C / 128; blk += 4) {
    int i0 = blk * 128 + lane, i1 = i0 + 64;
    float y0 = xr[i0] * inv * G[i0];
    float y1 = xr[i1] * inv * G[i1];
    float am = fmaxf(fabsf(y0), fabsf(y1));
#pragma unroll
    for (int m = 32; m >= 1; m >>= 1) am = fmaxf(am, __shfl_xor(am, m, 64));
    am = fmaxf(am, 1e-4f);
    float s = act_scale_from_amax(am);
    Y[(size_t)row * ys + i0] = f32_to_bf16(fp8_e4m3_qdq(clamp448(y0 / s)) * s);
    Y[(size_t)row * ys + i1] = f32_to_bf16(fp8_e4m3_qdq(clamp448(y1 / s)) * s);
  }
}

// ---------------- bf16 MFMA GEMM, templated epilogue ----------------
template <int OMODE, bool SCALED>
__global__ __launch_bounds__(256) void mfma_gemm_kernel(const unsigned short* __restrict__ A,
                                                        const unsigned short* __restrict__ B,
                                                        const float* __restrict__ Bsc,
                                                        float* __restrict__ C,
                                                        unsigned short* __restrict__ O1,
                                                        unsigned short* __restrict__ O2,
                                                        unsigned short* __restrict__ O3,
                                                        unsigned short* __restrict__ O4,
                                                        int N, int K, int ldc) {
  __shared__ unsigned short lA[128 * 64];
  __shared__ unsigned short lB[128 * 64];
  const int tid = threadIdx.x;
  const int wave = tid >> 6, lane = tid & 63;
  const int wr = (wave >> 1) * 64, wc = (wave & 1) * 64;
  const int m0 = blockIdx.y * 128, n0 = blockIdx.x * 128;
  const int KB = K >> 7;
  const int frow = lane & 15, fk = (lane >> 4) * 8;

  f32x4 mainAcc[4][4];
  f32x4 part[4][4];
  const f32x4 vzero = {0.f, 0.f, 0.f, 0.f};
#pragma unroll
  for (int i = 0; i < 4; ++i)
#pragma unroll
    for (int j = 0; j < 4; ++j) { mainAcc[i][j] = vzero; part[i][j] = vzero; }

  const int nkt = K >> 6;
  for (int kt = 0; kt < nkt; ++kt) {
    const int k0 = kt << 6;
    __syncthreads();
#pragma unroll
    for (int it = 0; it < 4; ++it) {
      int o = it * 4096 + wave * 1024 + lane * 16;
      int row = o >> 7;
      int kb = o & 127;
      const char* ga = (const char*)(A + (size_t)(m0 + row) * K + k0) + kb;
      const char* gb = (const char*)(B + (size_t)(n0 + row) * K + k0) + kb;
      __builtin_amdgcn_global_load_lds((gvoid*)ga, (lvoid*)((char*)lA + o), 16, 0, 0);
      __builtin_amdgcn_global_load_lds((gvoid*)gb, (lvoid*)((char*)lB + o), 16, 0, 0);
    }
    __syncthreads();
#pragma unroll
    for (int ks = 0; ks < 2; ++ks) {
      bf16x8 af[4], bfr[4];
#pragma unroll
      for (int i = 0; i < 4; ++i)
        af[i] = *(const bf16x8*)&lA[(wr + i * 16 + frow) * 64 + ks * 32 + fk];
#pragma unroll
      for (int j = 0; j < 4; ++j)
        bfr[j] = *(const bf16x8*)&lB[(wc + j * 16 + frow) * 64 + ks * 32 + fk];
#pragma unroll
      for (int i = 0; i < 4; ++i)
#pragma unroll
        for (int j = 0; j < 4; ++j)
          part[i][j] = __builtin_amdgcn_mfma_f32_16x16x32_bf16(af[i], bfr[j], part[i][j], 0, 0, 0);
    }
    if (SCALED) {
      float bs = Bsc[(size_t)(n0 >> 7) * KB + (k0 >> 7)];
#pragma unroll
      for (int i = 0; i < 4; ++i)
#pragma unroll
        for (int j = 0; j < 4; ++j) {
          mainAcc[i][j] += part[i][j] * bs;
          part[i][j] = vzero;
        }
    }
  }
  const int crow0 = (lane >> 4) * 4;
  const int ccol = lane & 15;
#pragma unroll
  for (int i = 0; i < 4; ++i) {
#pragma unroll
    for (int j = 0; j < 4; ++j) {
      f32x4 v = SCALED ? mainAcc[i][j] : part[i][j];
      int col = n0 + wc + j * 16 + ccol;
      if (col < N) {
#pragma unroll
        for (int r = 0; r < 4; ++r) {
          int m = m0 + wr + i * 16 + crow0 + r;
          float val = v[r];
          if (OMODE == 0) {
            C[(size_t)m * ldc + col] = val;
          } else if (OMODE == 1) {
            int hh = col / 192, d = col - hh * 192;
            int bb = m >> 11, s = m & 2047;
            size_t off = ((size_t)((bb * 16 + hh) * 2048 + s)) * 192 + d;
            unsigned short hi = f32_to_bf16(val);
            O1[off] = hi;
            O2[off] = f32_to_bf16(val - bf16_to_f32(hi));
          } else {
            int hh = col >> 8, d = col & 255;
            int bb = m >> 11, s = m & 2047;
            if (d < 128) {
              size_t off = ((size_t)((bb * 16 + hh) * 2048 + s)) * 128 + d;
              unsigned short hi = f32_to_bf16(val);
              O1[off] = hi;
              O2[off] = f32_to_bf16(val - bf16_to_f32(hi));
            } else {
              size_t off = ((size_t)((bb * 16 + hh) * 128 + (d - 128))) * 2048 + s;
              unsigned short hi = f32_to_bf16(val);
              O3[off] = hi;
              O4[off] = f32_to_bf16(val - bf16_to_f32(hi));
            }
          }
        }
      }
    }
  }
}

// ---------------- 3-product split GEMM -> bf16 hi/lo output [4096][1152] ----------------
__global__ __launch_bounds__(256) void mfma_gemm3_kernel(const unsigned short* __restrict__ Ah,
                                                         const unsigned short* __restrict__ Al,
                                                         const unsigned short* __restrict__ Bh,
                                                         const unsigned short* __restrict__ Bl,
                                                         unsigned short* __restrict__ OH,
                                                         unsigned short* __restrict__ OL,
                                                         int K, int ldc) {
  if (blockIdx.x < 8 && !(blockIdx.y & 8)) return;   // qi rows q<1024 never used
  __shared__ unsigned short lAh[128 * 64], lAl[128 * 64];
  __shared__ unsigned short lBh[128 * 64], lBl[128 * 64];
  const int tid = threadIdx.x;
  const int wave = tid >> 6, lane = tid & 63;
  const int wr = (wave >> 1) * 64, wc = (wave & 1) * 64;
  const int m0 = blockIdx.y * 128, n0 = blockIdx.x * 128;
  const int frow = lane & 15, fk = (lane >> 4) * 8;

  f32x4 part[4][4];
  const f32x4 vzero = {0.f, 0.f, 0.f, 0.f};
#pragma unroll
  for (int i = 0; i < 4; ++i)
#pragma unroll
    for (int j = 0; j < 4; ++j) part[i][j] = vzero;

  const int nkt = K >> 6;
  for (int kt = 0; kt < nkt; ++kt) {
    const int k0 = kt << 6;
    __syncthreads();
#pragma unroll
    for (int it = 0; it < 4; ++it) {
      int o = it * 4096 + wave * 1024 + lane * 16;
      int row = o >> 7;
      int kb = o & 127;
      size_t ga = (size_t)(m0 + row) * K + k0;
      size_t gb = (size_t)(n0 + row) * K + k0;
      __builtin_amdgcn_global_load_lds((gvoid*)((const char*)(Ah + ga) + kb), (lvoid*)((char*)lAh + o), 16, 0, 0);
      __builtin_amdgcn_global_load_lds((gvoid*)((const char*)(Al + ga) + kb), (lvoid*)((char*)lAl + o), 16, 0, 0);
      __builtin_amdgcn_global_load_lds((gvoid*)((const char*)(Bh + gb) + kb), (lvoid*)((char*)lBh + o), 16, 0, 0);
      __builtin_amdgcn_global_load_lds((gvoid*)((const char*)(Bl + gb) + kb), (lvoid*)((char*)lBl + o), 16, 0, 0);
    }
    __syncthreads();
#pragma unroll
    for (int ks = 0; ks < 2; ++ks) {
      bf16x8 ah[4], al[4], bh[4], bl[4];
#pragma unroll
      for (int i = 0; i < 4; ++i) {
        ah[i] = *(const bf16x8*)&lAh[(wr + i * 16 + frow) * 64 + ks * 32 + fk];
        al[i] = *(const bf16x8*)&lAl[(wr + i * 16 + frow) * 64 + ks * 32 + fk];
      }
#pragma unroll
      for (int j = 0; j < 4; ++j) {
        bh[j] = *(const bf16x8*)&lBh[(wc + j * 16 + frow) * 64 + ks * 32 + fk];
        bl[j] = *(const bf16x8*)&lBl[(wc + j * 16 + frow) * 64 + ks * 32 + fk];
      }
#pragma unroll
      for (int i = 0; i < 4; ++i)
#pragma unroll
        for (int j = 0; j < 4; ++j) {
          part[i][j] = __builtin_amdgcn_mfma_f32_16x16x32_bf16(ah[i], bh[j], part[i][j], 0, 0, 0);
          part[i][j] = __builtin_amdgcn_mfma_f32_16x16x32_bf16(ah[i], bl[j], part[i][j], 0, 0, 0);
          part[i][j] = __builtin_amdgcn_mfma_f32_16x16x32_bf16(al[i], bh[j], part[i][j], 0, 0, 0);
        }
    }
  }
  const int crow0 = (lane >> 4) * 4;
  const int ccol = lane & 15;
#pragma unroll
  for (int i = 0; i < 4; ++i)
#pragma unroll
    for (int j = 0; j < 4; ++j) {
      int col = n0 + wc + j * 16 + ccol;
#pragma unroll
      for (int r = 0; r < 4; ++r) {
        float val = part[i][j][r];
        size_t off = (size_t)(m0 + wr + i * 16 + crow0 + r) * ldc + col;
        unsigned short hi = f32_to_bf16(val);
        OH[off] = hi;
        OL[off] = f32_to_bf16(val - bf16_to_f32(hi));
      }
    }
}

// ---------------- f32 GEMM (tiny Wig only); rowskip: skip tiles with (y & rowskip)==0 ----------------
__global__ __launch_bounds__(256) void gemm_f32_kernel(const float* __restrict__ A,
                                                       const float* __restrict__ Bw,
                                                       float* __restrict__ C,
                                                       int N, int K, float alpha, int rowskip) {
  if (rowskip && !(blockIdx.y & rowskip)) return;
  __shared__ __align__(16) float As[16][68];
  __shared__ __align__(16) float Bs[16][68];
  int n0 = blockIdx.x * 64;
  int m0 = blockIdx.y * 64;
  int tid = threadIdx.x;
  int tx = tid & 15, ty = tid >> 4;
  float acc[4][4] = {};
  for (int k0 = 0; k0 < K; k0 += 16) {
#pragma unroll
    for (int t = 0; t < 4; ++t) {
      int idx = tid + t * 256;
      int rr = idx >> 4;
      int kk = idx & 15;
      As[kk][rr] = A[(size_t)(m0 + rr) * K + (k0 + kk)];
      Bs[kk][rr] = (n0 + rr < N) ? Bw[(size_t)(n0 + rr) * K + (k0 + kk)] : 0.0f;
    }
    __syncthreads();
#pragma unroll
    for (int kk = 0; kk < 16; ++kk) {
      float4 a = *(const float4*)&As[kk][ty * 4];
      float4 b = *(const float4*)&Bs[kk][tx * 4];
      float av[4] = {a.x, a.y, a.z, a.w};
      float bv[4] = {b.x, b.y, b.z, b.w};
#pragma unroll
      for (int i = 0; i < 4; ++i)
#pragma unroll
        for (int j = 0; j < 4; ++j) acc[i][j] += av[i] * bv[j];
    }
    __syncthreads();
  }
#pragma unroll
  for (int i = 0; i < 4; ++i) {
    int m = m0 + ty * 4 + i;
#pragma unroll
    for (int j = 0; j < 4; ++j) {
      int n = n0 + tx * 4 + j;
      if (n < N) C[(size_t)m * N + n] = alpha * acc[i][j];
    }
  }
}

// ---------------- RoPE on split Q (in place, [b,h,s,192]) + k_rope -> Krh/Krl ----------------
__global__ __launch_bounds__(64) void rope_split_kernel(unsigned short* __restrict__ Qh,
                                                        unsigned short* __restrict__ Ql,
                                                        const float* __restrict__ KVA,
                                                        unsigned short* __restrict__ Krh,
                                                        unsigned short* __restrict__ Krl,
                                                        const int* __restrict__ POS) {
  int t = blockIdx.x;  // b*S + s
  int tid = threadIdx.x;
  int b = t >> 11, s = t & 2047;
  __shared__ float cs[32], sn[32];
  if (tid < 32) {
    int pos = POS[t];
    double inv = pow(10000.0, -((double)(2 * tid) / 64.0));
    float ang = (float)pos * (float)inv;
    cs[tid] = cosf(ang);
    sn[tid] = sinf(ang);
  }
  __syncthreads();
  if (tid < 32) {
    const float* kr = KVA + (size_t)t * (kKvLora + kDR) + kKvLora;
    float x1 = kr[tid], x2 = kr[32 + tid];
    float y1 = x1 * cs[tid] - x2 * sn[tid];
    float y2 = x2 * cs[tid] + x1 * sn[tid];
    unsigned short h1 = f32_to_bf16(y1);
    Krh[(size_t)t * 64 + tid] = h1;
    Krl[(size_t)t * 64 + tid] = f32_to_bf16(y1 - bf16_to_f32(h1));
    unsigned short h2 = f32_to_bf16(y2);
    Krh[(size_t)t * 64 + 32 + tid] = h2;
    Krl[(size_t)t * 64 + 32 + tid] = f32_to_bf16(y2 - bf16_to_f32(h2));
  }
  for (int it = tid; it < kH * 32; it += 64) {
    int h = it >> 5, i = it & 31;
    size_t base = ((size_t)((b * 16 + h) * 2048 + s)) * 192 + 128;
    float x1 = bf16_to_f32(Qh[base + i]) + bf16_to_f32(Ql[base + i]);
    float x2 = bf16_to_f32(Qh[base + 32 + i]) + bf16_to_f32(Ql[base + 32 + i]);
    float y1 = x1 * cs[i] - x2 * sn[i];
    float y2 = x2 * cs[i] + x1 * sn[i];
    unsigned short h1 = f32_to_bf16(y1);
    Qh[base + i] = h1;
    Ql[base + i] = f32_to_bf16(y1 - bf16_to_f32(h1));
    unsigned short h2 = f32_to_bf16(y2);
    Qh[base + 32 + i] = h2;
    Ql[base + 32 + i] = f32_to_bf16(y2 - bf16_to_f32(h2));
  }
}

// ---------------- MFMA indexer scores: one 64x64 tile per block (rows q>=1024 only) ----------------
__global__ __launch_bounds__(256) void isc_mfma_kernel(const unsigned short* __restrict__ QIKH,
                                                       const unsigned short* __restrict__ QIKL,
                                                       const float* __restrict__ WGT,
                                                       float* __restrict__ ISC) {
  const int qt = blockIdx.y + 16;
  const int kt = blockIdx.x;
  if (kt > qt) return;
  const int b = blockIdx.z;
  const int q0 = qt * 64, k0 = kt * 64;
  const int tid = threadIdx.x, wave = tid >> 6, lane = tid & 63;
  const int fr = lane & 15, fg = lane >> 4;

  __shared__ unsigned short KiH[4 * 64 * 40], KiL[4 * 64 * 40];
  __shared__ float wgs[64 * 8];

  {
    int key = tid >> 2, sub = (tid & 3) * 8;
    size_t rb = (size_t)(b * kS + k0 + key) * 1152 + 1024;
#pragma unroll
    for (int kc = 0; kc < 4; ++kc) {
      *(bf16x8*)&KiH[kc * 2560 + key * 40 + sub] = *(const bf16x8*)&QIKH[rb + kc * 32 + sub];
      *(bf16x8*)&KiL[kc * 2560 + key * 40 + sub] = *(const bf16x8*)&QIKL[rb + kc * 32 + sub];
    }
#pragma unroll
    for (int t = 0; t < 2; ++t) {
      int i = t * 256 + tid;
      wgs[i] = WGT[(size_t)(b * kS + q0 + (i >> 3)) * kHI + (i & 7)];
    }
  }
  const size_t qrow = (size_t)(b * kS + q0 + wave * 16 + fr) * 1152;
  f32x4 sacc[4];
  const f32x4 vzero = {0.f, 0.f, 0.f, 0.f};
#pragma unroll
  for (int j = 0; j < 4; ++j) sacc[j] = vzero;

  bf16x8 qAh[4], qAl[4], qBh[4], qBl[4];
#define LOADQ(DH_, DL_, H_)                                                     \
  _Pragma("unroll") for (int kc = 0; kc < 4; ++kc) {                            \
    DH_[kc] = *(const bf16x8*)&QIKH[qrow + (H_)*128 + kc * 32 + fg * 8];        \
    DL_[kc] = *(const bf16x8*)&QIKL[qrow + (H_)*128 + kc * 32 + fg * 8];        \
  }
  LOADQ(qAh, qAl, 0)
  __syncthreads();
#define MFMA_HEAD(QH_, QL_, H_)                                                 \
  {                                                                             \
    f32x4 acc[4];                                                               \
    _Pragma("unroll") for (int j = 0; j < 4; ++j) acc[j] = vzero;               \
    _Pragma("unroll") for (int kc = 0; kc < 4; ++kc) {                          \
      _Pragma("unroll") for (int j = 0; j < 4; ++j) {                           \
        bf16x8 kh = *(const bf16x8*)&KiH[kc * 2560 + (j * 16 + fr) * 40 + fg * 8]; \
        bf16x8 kl = *(const bf16x8*)&KiL[kc * 2560 + (j * 16 + fr) * 40 + fg * 8]; \
        acc[j] = __builtin_amdgcn_mfma_f32_16x16x32_bf16(QH_[kc], kh, acc[j], 0, 0, 0); \
        acc[j] = __builtin_amdgcn_mfma_f32_16x16x32_bf16(QH_[kc], kl, acc[j], 0, 0, 0); \
        acc[j] = __builtin_amdgcn_mfma_f32_16x16x32_bf16(QL_[kc], kh, acc[j], 0, 0, 0); \
      }                                                                         \
    }                                                                           \
    float wv[4];                                                                \
    _Pragma("unroll") for (int r = 0; r < 4; ++r)                               \
        wv[r] = wgs[(wave * 16 + fg * 4 + r) * 8 + (H_)];                       \
    _Pragma("unroll") for (int j = 0; j < 4; ++j)                               \
      _Pragma("unroll") for (int r = 0; r < 4; ++r)                             \
        sacc[j][r] += fmaxf(acc[j][r], 0.0f) * wv[r];                           \
  }
#pragma unroll
  for (int hp = 0; hp < 4; ++hp) {
    int h0 = hp * 2;
    LOADQ(qBh, qBl, h0 + 1)
    MFMA_HEAD(qAh, qAl, h0)
    if (hp < 3) LOADQ(qAh, qAl, h0 + 2)
    MFMA_HEAD(qBh, qBl, h0 + 1)
  }
#undef LOADQ
#undef MFMA_HEAD
#pragma unroll
  for (int r = 0; r < 4; ++r) {
    size_t ob = (size_t)(b * kS + q0 + wave * 16 + fg * 4 + r) * kS + k0;
#pragma unroll
    for (int j = 0; j < 4; ++j) ISC[ob + j * 16 + fr] = sacc[j][r];
  }
}

// ---------------- exact stable top-k (parallel scans; integer-exact) ----------------
__global__ __launch_bounds__(256) void topk_kernel(const float* __restrict__ ISC,
                                                   unsigned* __restrict__ SEL) {
  int row = blockIdx.x;
  int q = row & (kS - 1);
  int L = q + 1;
  unsigned* selrow = SEL + (size_t)row * (kS / 32);
  int tid = threadIdx.x;
  if (L <= kTopK) {
    if (tid < kS / 32) {
      int base = tid * 32;
      unsigned w;
      if (base + 32 <= L) w = 0xFFFFFFFFu;
      else if (base >= L) w = 0u;
      else w = (1u << (L - base)) - 1u;
      selrow[tid] = w;
    }
    return;
  }
  __shared__ unsigned keys[kS];
  __shared__ unsigned hist[256];
  __shared__ unsigned sfx[256];
  __shared__ unsigned msk[kS / 32];
  __shared__ unsigned pick[2];
  if (tid < kS / 32) msk[tid] = 0u;
  const float* x = ISC + (size_t)row * kS;
  for (int k = tid; k < L; k += 256) {
    unsigned u = __float_as_uint(x[k]);
    keys[k] = (u & 0x80000000u) ? ~u : (u | 0x80000000u);
  }
  __syncthreads();
  unsigned prefix = 0u;
  int r = kTopK;
  for (int shift = 24; shift >= 0; shift -= 8) {
    hist[tid] = 0u;
    __syncthreads();
    unsigned hm = (shift == 24) ? 0u : (0xFFFFFFFFu << (shift + 8));
    for (int k = tid; k < L; k += 256) {
      unsigned key = keys[k];
      if ((key & hm) == (prefix & hm)) atomicAdd(&hist[(key >> shift) & 255u], 1u);
    }
    __syncthreads();
    sfx[tid] = hist[tid];
    __syncthreads();
#pragma unroll
    for (int step = 1; step < 256; step <<= 1) {
      unsigned add = (tid + step < 256) ? sfx[tid + step] : 0u;
      __syncthreads();
      sfx[tid] += add;
      __syncthreads();
    }
    {
      unsigned Tb = sfx[tid];
      unsigned Tb1 = (tid < 255) ? sfx[tid + 1] : 0u;
      if (Tb1 < (unsigned)r && (unsigned)r <= Tb) {
        pick[0] = (unsigned)tid;
        pick[1] = (unsigned)r - Tb1;
      }
    }
    __syncthreads();
    prefix |= pick[0] << shift;
    r = (int)pick[1];
    __syncthreads();
  }
  unsigned T = prefix;
  int ties_take = r;
  int base = tid * 8;
  int cnt = 0;
#pragma unroll
  for (int j = 0; j < 8; ++j) {
    int k = base + j;
    if (k < L && keys[k] == T) ++cnt;
  }
  hist[tid] = (unsigned)cnt;
  __syncthreads();
  sfx[tid] = hist[tid];
  __syncthreads();
#pragma unroll
  for (int step = 1; step < 256; step <<= 1) {
    unsigned add = (tid >= step) ? sfx[tid - step] : 0u;
    __syncthreads();
    sfx[tid] += add;
    __syncthreads();
  }
  int trank = (tid == 0) ? 0 : (int)sfx[tid - 1];
  unsigned bits = 0u;
#pragma unroll
  for (int j = 0; j < 8; ++j) {
    int k = base + j;
    if (k < L) {
      unsigned key = keys[k];
      bool s;
      if (key > T) s = true;
      else if (key == T) { s = trank < ties_take; ++trank; }
      else s = false;
      if (s) bits |= (1u << j);
    }
  }
  atomicOr(&msk[tid >> 2], bits << ((tid & 3) * 8));
  __syncthreads();
  if (tid < kS / 32) selrow[tid] = msk[tid];
}

// ---------------- MFMA flash attention (Ph/Pl alias Ks double-buffers -> 4 blocks/CU) ----------------
// grid.x = flattened (qt,h), global longest-first: qt = 31 - (x>>4), h = x&15; b = grid.y.
// QK^T: 3-pass hi/lo; K chunks LDS double-buffered with reg prefetch; one barrier after QK
// lets Ph/Pl reuse the (now dead) Ks region. PV: (Ph+Pl)*Vh then Ph*Vl; V reg-prefetched.
__global__ __launch_bounds__(256) void attn_mfma_kernel(const unsigned short* __restrict__ Qh,
                                                        const unsigned short* __restrict__ Ql,
                                                        const unsigned short* __restrict__ Knh,
                                                        const unsigned short* __restrict__ Knl,
                                                        const unsigned short* __restrict__ Krh,
                                                        const unsigned short* __restrict__ Krl,
                                                        const unsigned short* __restrict__ Vth,
                                                        const unsigned short* __restrict__ Vtl,
                                                        const unsigned* __restrict__ SEL,
                                                        unsigned short* __restrict__ CTXB) {
  const int flat = blockIdx.x;
  const int qt = 31 - (flat >> 4);        // longest blocks dispatch first
  const int h = flat & 15;
  const int b = blockIdx.y;
  const int q0 = qt * 64;
  const int tid = threadIdx.x, wave = tid >> 6, lane = tid & 63;
  const int fr = lane & 15, fg = lane >> 4;
  const float scale = 0.07216878364870323f;  // 1/sqrt(192)

  __shared__ unsigned short KsH[2 * 64 * 40], KsL[2 * 64 * 40];  // double-buffered K chunk
  __shared__ unsigned short Vs[128 * 72];
  __shared__ unsigned selw[64][2];
  // Ph/Pl alias Ks (dead after QK barrier): 64*72 <= 2*64*40; row pads stay 72 (16B-aligned)
  unsigned short* Ph = KsH;
  unsigned short* Pl = KsL;
  // LDS total: 10240*2 + 18432 + 512 = 39424 B -> 4 blocks/CU (VGPR-capped 4 waves/SIMD)

  bf16x8 qh[6], ql[6];
  {
    const size_t qbase = ((size_t)((b * 16 + h) * 2048 + q0 + wave * 16 + fr)) * 192;
#pragma unroll
    for (int kc = 0; kc < 6; ++kc) {
      qh[kc] = *(const bf16x8*)&Qh[qbase + kc * 32 + fg * 8];
      ql[kc] = *(const bf16x8*)&Ql[qbase + kc * 32 + fg * 8];
    }
  }
  float m_run[4], l_run[4];
#pragma unroll
  for (int r = 0; r < 4; ++r) { m_run[r] = kNeg; l_run[r] = 0.0f; }
  f32x4 O[8];
  const f32x4 vzero = {0.f, 0.f, 0.f, 0.f};
#pragma unroll
  for (int j = 0; j < 8; ++j) O[j] = vzero;

  const int key = tid >> 2, sub = (tid & 3) * 8;
  const size_t knbase = (size_t)((b * 16 + h) * 2048) * 128;
  const size_t krbase = (size_t)(b * 2048) * 64;
  const size_t vbase0 = ((size_t)((b * 16 + h) * 128)) * 2048;

  const int nkt = qt + 1;
  for (int kt = 0; kt < nkt; ++kt) {
    const int k0 = kt * 64;
    const size_t vbase = vbase0 + k0;
    unsigned selreg = 0;
    if (tid < 128)
      selreg = SEL[(size_t)(b * kS + q0 + (tid >> 1)) * (kS / 32) + (k0 >> 5) + (tid & 1)];
    bf16x8 kh_pre[2], kl_pre[2];
    {
      size_t src = knbase + (size_t)(k0 + key) * 128 + sub;   // chunk 0
      kh_pre[0] = *(const bf16x8*)&Knh[src];
      kl_pre[0] = *(const bf16x8*)&Knl[src];
    }
    bf16x8 vpre[4];
#pragma unroll
    for (int it = 0; it < 4; ++it) {
      int idx = it * 256 + tid;
      int dv = idx >> 3, ks8 = (idx & 7) * 8;
      vpre[it] = *(const bf16x8*)&Vth[vbase + (size_t)dv * 2048 + ks8];
    }
    __syncthreads();  // B1: prev tile's Ph(=Ks)/Vs/selw reads done
    if (tid < 128) selw[tid >> 1][tid & 1] = selreg;
    f32x4 acc[4];
#pragma unroll
    for (int j = 0; j < 4; ++j) acc[j] = vzero;
#pragma unroll
    for (int kc = 0; kc < 6; ++kc) {
      const int buf = (kc & 1) * 2560;
      *(bf16x8*)&KsH[buf + key * 40 + sub] = kh_pre[kc & 1];
      *(bf16x8*)&KsL[buf + key * 40 + sub] = kl_pre[kc & 1];
      if (kc < 5) {   // prefetch next chunk (hidden under barrier+MFMA)
        if (kc + 1 < 4) {
          size_t src = knbase + (size_t)(k0 + key) * 128 + (kc + 1) * 32 + sub;
          kh_pre[(kc + 1) & 1] = *(const bf16x8*)&Knh[src];
          kl_pre[(kc + 1) & 1] = *(const bf16x8*)&Knl[src];
        } else {
          size_t src = krbase + (size_t)(k0 + key) * 64 + (kc - 3) * 32 + sub;
          kh_pre[(kc + 1) & 1] = *(const bf16x8*)&Krh[src];
          kl_pre[(kc + 1) & 1] = *(const bf16x8*)&Krl[src];
        }
      }
      __syncthreads();  // single barrier per chunk (double-buffered Ks)
#pragma unroll
      for (int j = 0; j < 4; ++j) {
        bf16x8 kh = *(const bf16x8*)&KsH[buf + (j * 16 + fr) * 40 + fg * 8];
        bf16x8 kl = *(const bf16x8*)&KsL[buf + (j * 16 + fr) * 40 + fg * 8];
        acc[j] = __builtin_amdgcn_mfma_f32_16x16x32_bf16(qh[kc], kh, acc[j], 0, 0, 0);
        acc[j] = __builtin_amdgcn_mfma_f32_16x16x32_bf16(qh[kc], kl, acc[j], 0, 0, 0);
        acc[j] = __builtin_amdgcn_mfma_f32_16x16x32_bf16(ql[kc], kh, acc[j], 0, 0, 0);
      }
    }
    float p[4][4];
    float fsc[4];
#pragma unroll
    for (int r = 0; r < 4; ++r) {
      int row = wave * 16 + fg * 4 + r;
      float sv[4];
      float vmax = kNeg;
#pragma unroll
      for (int j = 0; j < 4; ++j) {
        int col = j * 16 + fr;
        bool bit = (selw[row][col >> 5] >> (col & 31)) & 1u;
        float s = bit ? acc[j][r] * scale : kNeg;
        sv[j] = s;
        vmax = fmaxf(vmax, s);
      }
#pragma unroll
      for (int m = 1; m <= 8; m <<= 1) vmax = fmaxf(vmax, __shfl_xor(vmax, m, 64));
      float newm = fmaxf(m_run[r], vmax);
      float sum = 0.0f;
#pragma unroll
      for (int j = 0; j < 4; ++j) {
        float pp = (sv[j] < -1e29f) ? 0.0f : __expf(sv[j] - newm);
        p[j][r] = pp;
        sum += pp;
      }
#pragma unroll
      for (int m = 1; m <= 8; m <<= 1) sum += __shfl_xor(sum, m, 64);
      fsc[r] = __expf(m_run[r] - newm);
      l_run[r] = l_run[r] * fsc[r] + sum;
      m_run[r] = newm;
    }
#pragma unroll
    for (int j = 0; j < 8; ++j)
#pragma unroll
      for (int r = 0; r < 4; ++r) O[j][r] *= fsc[r];
    __syncthreads();  // B2: all waves' Ks reads complete before Ph/Pl overwrite (alias)
#pragma unroll
    for (int r = 0; r < 4; ++r) {
      int row = wave * 16 + fg * 4 + r;
#pragma unroll
      for (int j = 0; j < 4; ++j) {
        int col = j * 16 + fr;
        float pp = p[j][r];
        unsigned short hi = f32_to_bf16(pp);
        Ph[row * 72 + col] = hi;
        Pl[row * 72 + col] = f32_to_bf16(pp - bf16_to_f32(hi));
      }
    }
#pragma unroll
    for (int it = 0; it < 4; ++it) {
      int idx = it * 256 + tid;
      int dv = idx >> 3, ks8 = (idx & 7) * 8;
      *(bf16x8*)&Vs[dv * 72 + ks8] = vpre[it];
    }
#pragma unroll
    for (int it = 0; it < 4; ++it) {
      int idx = it * 256 + tid;
      int dv = idx >> 3, ks8 = (idx & 7) * 8;
      vpre[it] = *(const bf16x8*)&Vtl[vbase + (size_t)dv * 2048 + ks8];
    }
    __syncthreads();  // B3: Vs (hi) + Ph/Pl ready
#pragma unroll
    for (int kk = 0; kk < 2; ++kk) {
      bf16x8 pah = *(const bf16x8*)&Ph[(wave * 16 + fr) * 72 + kk * 32 + fg * 8];
      bf16x8 pal = *(const bf16x8*)&Pl[(wave * 16 + fr) * 72 + kk * 32 + fg * 8];
#pragma unroll
      for (int j = 0; j < 8; ++j) {
        bf16x8 vb = *(const bf16x8*)&Vs[(j * 16 + fr) * 72 + kk * 32 + fg * 8];
        O[j] = __builtin_amdgcn_mfma_f32_16x16x32_bf16(pah, vb, O[j], 0, 0, 0);
        O[j] = __builtin_amdgcn_mfma_f32_16x16x32_bf16(pal, vb, O[j], 0, 0, 0);
      }
    }
    __syncthreads();  // B4: PV1 Vs reads done
#pragma unroll
    for (int it = 0; it < 4; ++it) {
      int idx = it * 256 + tid;
      int dv = idx >> 3, ks8 = (idx & 7) * 8;
      *(bf16x8*)&Vs[dv * 72 + ks8] = vpre[it];
    }
    __syncthreads();  // B5: Vs (lo) ready
#pragma unroll
    for (int kk = 0; kk < 2; ++kk) {
      bf16x8 pah = *(const bf16x8*)&Ph[(wave * 16 + fr) * 72 + kk * 32 + fg * 8];
#pragma unroll
      for (int j = 0; j < 8; ++j) {
        bf16x8 vb = *(const bf16x8*)&Vs[(j * 16 + fr) * 72 + kk * 32 + fg * 8];
        O[j] = __builtin_amdgcn_mfma_f32_16x16x32_bf16(pah, vb, O[j], 0, 0, 0);
      }
    }
  }
#pragma unroll
  for (int r = 0; r < 4; ++r) {
    float inv = 1.0f / l_run[r];
    float vals[8];
    float am = 0.0f;
#pragma unroll
    for (int j = 0; j < 8; ++j) {
      vals[j] = O[j][r] * inv;
      am = fmaxf(am, fabsf(vals[j]));
    }
#pragma unroll
    for (int m = 1; m <= 8; m <<= 1) am = fmaxf(am, __shfl_xor(am, m, 64));
    am = fmaxf(am, 1e-4f);
    float s = act_scale_from_amax(am);
    size_t obase = (size_t)(b * kS + q0 + wave * 16 + fg * 4 + r) * 2048 + h * 128;
#pragma unroll
    for (int j = 0; j < 8; ++j)
      CTXB[obase + j * 16 + fr] = f32_to_bf16(fp8_e4m3_qdq(clamp448(vals[j] / s)) * s);
  }
}

extern "C" void kernel_launch(void* const* d_in, const int* in_sizes, int n_in,
                              void* d_out, int out_size, void* d_ws, size_t ws_size,
                              hipStream_t stream) {
  (void)in_sizes; (void)n_in;

  const float* hidden = (const float*)d_in[0];
  const float* Wqa    = (const float*)d_in[1];
  const float* qnw    = (const float*)d_in[2];
  const float* Wqb    = (const float*)d_in[3];
  const float* Wkva   = (const float*)d_in[4];
  const float* kvnw   = (const float*)d_in[5];
  const float* Wkvb   = (const float*)d_in[6];
  const float* Wiq    = (const float*)d_in[7];
  const float* Wik    = (const float*)d_in[8];
  const float* Wig    = (const float*)d_in[9];
  const float* Wo     = (const float*)d_in[10];
  const int*   pos    = (const int*)d_in[11];
  char* ws = (char*)d_ws;
  float* out = (float*)d_out;

  if (ws_size < WS_NEED) {
    fill_kernel<<<dim3((out_size + 255) / 256), dim3(256), 0, stream>>>(out, out_size, 54321.0f);
    return;
  }

  float* scbase = (float*)(ws + OFF_SC);
  float* scWqa  = scbase + 0;
  float* scWqb  = scbase + 128;
  float* scWkva = scbase + 320;
  float* scWkvb = scbase + 400;
  float* scWo   = scbase + 528;
  unsigned* sel = (unsigned*)(ws + OFF_SEL_B);
  float* wgt    = (float*)(ws + OFF_WGT_B);
  unsigned short* krh = (unsigned short*)(ws + OFF_KRH_B);
  unsigned short* krl = (unsigned short*)(ws + OFF_KRL_B);
  unsigned short* wo_b = (unsigned short*)(ws + OFF_WOB_B);

  unsigned short* h_hi  = (unsigned short*)(ws + A_HHI);
  unsigned short* h_lo  = (unsigned short*)(ws + A_HLO);
  unsigned short* wqk_h = (unsigned short*)(ws + A_WQKH);
  unsigned short* wqk_l = (unsigned short*)(ws + A_WQKL);
  unsigned short* qik_h = (unsigned short*)(ws + A_QIKH);
  unsigned short* qik_l = (unsigned short*)(ws + A_QIKL);
  float* isc = (float*)(ws + A_ISC);

  unsigned short* hidq_b = (unsigned short*)(ws + B_HIDQ);
  unsigned short* wqa_b  = (unsigned short*)(ws + B_WQA);
  unsigned short* wqb_b  = (unsigned short*)(ws + B_WQB);
  unsigned short* wkva_b = (unsigned short*)(ws + B_WKVA);
  unsigned short* wkvb_b = (unsigned short*)(ws + B_WKVB);
  float* qa_f   = (float*)(ws + B_QAF);
  unsigned short* qa_b  = (unsigned short*)(ws + B_QAB);
  float* kva    = (float*)(ws + B_KVA);
  unsigned short* ckv_b = (unsigned short*)(ws + B_CKV);
  unsigned short* q_h   = (unsigned short*)(ws + B_QH);
  unsigned short* q_l   = (unsigned short*)(ws + B_QL);
  unsigned short* kn_h  = (unsigned short*)(ws + B_KNH);
  unsigned short* kn_l  = (unsigned short*)(ws + B_KNL);
  unsigned short* v_th  = (unsigned short*)(ws + B_VTH);
  unsigned short* v_tl  = (unsigned short*)(ws + B_VTL);
  unsigned short* ctx_b = (unsigned short*)(ws + B_CTXB);

  // ---------- Phase A: indexer + top-k ----------
  hidden_prep_kernel<<<dim3(16384), dim3(256), 0, stream>>>(hidden, h_hi, h_lo, hidq_b);
  split_bf16x2_kernel<<<dim3(8192),  dim3(256), 0, stream>>>(Wiq, wqk_h, wqk_l, (size_t)kHI * kDI * kDH);
  split_bf16x2_kernel<<<dim3(1024),  dim3(256), 0, stream>>>(Wik, wqk_h + (size_t)1024 * kDH, wqk_l + (size_t)1024 * kDH, (size_t)kDI * kDH);
  gemm_f32_kernel<<<dim3(1, 64), dim3(256), 0, stream>>>(hidden, Wig, wgt, kHI, kDH, 0.35355339059327373f, 16);
  mfma_gemm3_kernel<<<dim3(9, 32), dim3(256), 0, stream>>>(h_hi, h_lo, wqk_h, wqk_l, qik_h, qik_l, kDH, 1152);
  isc_mfma_kernel<<<dim3(32, 16, kB), dim3(256), 0, stream>>>(qik_h, qik_l, wgt, isc);
  topk_kernel<<<dim3(kNTok), dim3(256), 0, stream>>>(isc, sel);

  // ---------- Phase B: fp8-path linears on MFMA ----------
  fused_weight5_kernel<<<dim3(784), dim3(256), 0, stream>>>(Wqa, Wqb, Wkva, Wkvb, Wo, scbase,
                                                            wqa_b, wqb_b, wkva_b, wkvb_b, wo_b);

  // q_a -> rms -> q (bf16 hi/lo, [b,h,s,192])
  mfma_gemm_kernel<0, true><<<dim3(8, 32), dim3(256), 0, stream>>>(hidq_b, wqa_b, scWqa, qa_f, nullptr, nullptr, nullptr, nullptr, 1024, kDH, 1024);
  rms_qdq_kernel<<<dim3(kNTok), dim3(256), 0, stream>>>(qa_f, qnw, qa_b, kQLora, kQLora, kQLora);
  mfma_gemm_kernel<1, true><<<dim3(24, 32), dim3(256), 0, stream>>>(qa_b, wqb_b, scWqb, nullptr, q_h, q_l, nullptr, nullptr, 3072, kQLora, 3072);
  // kv_a -> rms -> kv (split to Kn hi/lo [b,h,s,128] + V^T hi/lo [b,h,dv,s])
  mfma_gemm_kernel<0, true><<<dim3(5, 32), dim3(256), 0, stream>>>(hidq_b, wkva_b, scWkva, kva, nullptr, nullptr, nullptr, nullptr, 576, kDH, 576);
  rms_qdq_kernel<<<dim3(kNTok), dim3(256), 0, stream>>>(kva, kvnw, ckv_b, kKvLora, kKvLora + kDR, kKvLora);
  rope_split_kernel<<<dim3(kNTok), dim3(64), 0, stream>>>(q_h, q_l, kva, krh, krl, pos);
  mfma_gemm_kernel<2, true><<<dim3(32, 32), dim3(256), 0, stream>>>(ckv_b, wkvb_b, scWkvb, nullptr, kn_h, kn_l, v_th, v_tl, 4096, kKvLora, 4096);

  // ---------- attention (fused ctx fp8-qdq) + output ----------
  attn_mfma_kernel<<<dim3(512, kB), dim3(256), 0, stream>>>(q_h, q_l, kn_h, kn_l, krh, krl, v_th, v_tl, sel, ctx_b);
  mfma_gemm_kernel<0, true><<<dim3(16, 32), dim3(256), 0, stream>>>(ctx_b, wo_b, scWo, out, nullptr, nullptr, nullptr, nullptr, kDH, kH * kDV, 2048);
}